// Round 4
// baseline (2593.238 us; speedup 1.0000x reference)
//
#include <hip/hip_runtime.h>
#include <hip/hip_bf16.h>
#include <math.h>

#define EPSV 1e-6f
#define INV_SCALE 0.04419417382415922f   // 1/sqrt(512)

typedef __hip_bfloat16 bf16;

__device__ __forceinline__ float ldf(const float* p) { return *p; }
__device__ __forceinline__ float ldf(const bf16* p)  { return __bfloat162float(*p); }
__device__ __forceinline__ void  stf(float* p, float v) { *p = v; }
__device__ __forceinline__ void  stf(bf16* p, float v)  { *p = __float2bfloat16(v); }

// ---------------------------------------------------------------------------
// Generic 64x64-tile fp32-accumulate GEMM.  C = A * B(^T) [+ epilogue]
// MODE: 0 = +bias[n]; 1 = sigmoid(acc*INV_SCALE + r[h]); 2 = acc*INV_SCALE; 3 = plain
// BT  : false -> B is (Kd,N) row-major;  true -> B is (N,Kd) row-major (C=A*B^T)
// ---------------------------------------------------------------------------
template<int MODE, bool BT, typename TA, typename TB, typename TC>
__global__ __launch_bounds__(256)
void gemm64(const TA* __restrict__ A, const TB* __restrict__ B,
            TC* __restrict__ C, int M, int N, int Kd,
            int lda, int ldb, int ldc, int hdiv,
            long long sAb, long long sAh, long long sBb, long long sBh,
            long long sCb, long long sCh,
            const float* __restrict__ bias, const float* __restrict__ rvec)
{
  int z  = blockIdx.z;
  int bz = z / hdiv, hz = z - bz * hdiv;
  A += (size_t)bz * sAb + (size_t)hz * sAh;
  B += (size_t)bz * sBb + (size_t)hz * sBh;
  C += (size_t)bz * sCb + (size_t)hz * sCh;

  __shared__ __align__(16) float As[16][64];
  __shared__ __align__(16) float Bs[16][64];
  int tid = threadIdx.x;
  int tx = tid & 15, ty = tid >> 4;
  int m0 = blockIdx.y * 64, n0 = blockIdx.x * 64;
  float acc[4][4] = {};

  for (int k0 = 0; k0 < Kd; k0 += 16) {
    #pragma unroll
    for (int i = 0; i < 4; i++) {            // A tile: As[k][m]
      int idx = tid + i * 256;
      int rr = idx >> 4, cc = idx & 15;
      int mm = m0 + rr, kk = k0 + cc;
      As[cc][rr] = (mm < M && kk < Kd) ? ldf(&A[(size_t)mm * lda + kk]) : 0.f;
    }
    #pragma unroll
    for (int i = 0; i < 4; i++) {            // B tile: Bs[k][n]
      int idx = tid + i * 256;
      if (BT) {
        int rr = idx >> 4, cc = idx & 15;
        int nn = n0 + rr, kk = k0 + cc;
        Bs[cc][rr] = (nn < N && kk < Kd) ? ldf(&B[(size_t)nn * ldb + kk]) : 0.f;
      } else {
        int rr = idx >> 6, cc = idx & 63;
        int nn = n0 + cc, kk = k0 + rr;
        Bs[rr][cc] = (nn < N && kk < Kd) ? ldf(&B[(size_t)kk * ldb + nn]) : 0.f;
      }
    }
    __syncthreads();
    #pragma unroll
    for (int kk = 0; kk < 16; kk++) {
      float4 av = *(const float4*)&As[kk][ty * 4];
      float4 bv = *(const float4*)&Bs[kk][tx * 4];
      float a_[4] = {av.x, av.y, av.z, av.w};
      float b_[4] = {bv.x, bv.y, bv.z, bv.w};
      #pragma unroll
      for (int i2 = 0; i2 < 4; i2++)
        #pragma unroll
        for (int j2 = 0; j2 < 4; j2++)
          acc[i2][j2] = fmaf(a_[i2], b_[j2], acc[i2][j2]);
    }
    __syncthreads();
  }

  float radd = 0.f;
  if (MODE == 1) radd = rvec[hz];
  #pragma unroll
  for (int i2 = 0; i2 < 4; i2++) {
    int row = m0 + ty * 4 + i2;
    if (row >= M) continue;
    #pragma unroll
    for (int j2 = 0; j2 < 4; j2++) {
      int col = n0 + tx * 4 + j2;
      if (col >= N) continue;
      float v = acc[i2][j2];
      if (MODE == 0)      v += bias[col];
      else if (MODE == 1) v = 1.f / (1.f + expf(-(v * INV_SCALE + radd)));
      else if (MODE == 2) v *= INV_SCALE;
      stf(&C[(size_t)row * ldc + col], v);
    }
  }
}

// ---------------------------------------------------------------------------
// Fused cp + monotonic-alpha scan. One block per (b,h) chain (grid = 32).
// Per q-step: (1) log-space prefix scan of log(clip(1-p)) -> cp_i in fp32
// registers (exclusive cumprod), (2) prefix scan of a_prev/clip(cp) ->
// alpha_i. a_prev carried in fp32 registers; alpha written fp32 to output.
// 1024 threads x 3 elements cover K=3000. Two barriers per step.
// ---------------------------------------------------------------------------
__global__ __launch_bounds__(1024)
void scan_kernel(const float* __restrict__ p_slot, float* __restrict__ alpha_slot)
{
  __shared__ float wsA[16];
  __shared__ float wsB[16];
  int z = blockIdx.x;                 // b*4+h
  int tid = threadIdx.x;
  int lane = tid & 63, wid = tid >> 6;
  int k0 = tid * 3;
  float a_prev[3];
  #pragma unroll
  for (int c = 0; c < 3; c++) a_prev[c] = (k0 + c == 0) ? 1.f : 0.f;
  size_t zbase = (size_t)z * 256 * 3000;

  float pv[3];                        // prefetched p row
  #pragma unroll
  for (int c = 0; c < 3; c++) {
    int k = k0 + c;
    pv[c] = (k < 3000) ? p_slot[zbase + k] : 0.f;
  }

  for (int i = 0; i < 256; i++) {
    float pc[3] = {pv[0], pv[1], pv[2]};
    if (i < 255) {                    // prefetch next row (hides HBM latency)
      size_t nbase = zbase + (size_t)(i + 1) * 3000;
      #pragma unroll
      for (int c = 0; c < 3; c++) {
        int k = k0 + c;
        pv[c] = (k < 3000) ? p_slot[nbase + k] : 0.f;
      }
    }
    // ---- scan 1: exclusive cumsum of log(clip(1-p)) -> cp (fp32) ----
    float l[3]; float s = 0.f;
    #pragma unroll
    for (int c = 0; c < 3; c++) {
      l[c] = s;
      if (k0 + c < 3000) s += logf(fminf(fmaxf(1.f - pc[c], EPSV), 1.f));
    }
    float incl = s;
    #pragma unroll
    for (int d = 1; d < 64; d <<= 1) {
      float o = __shfl_up(incl, d);
      if (lane >= d) incl += o;
    }
    if (lane == 63) wsA[wid] = incl;
    float excl = incl - s;
    __syncthreads();                                  // barrier 1
    float base = excl;
    for (int w = 0; w < wid; w++) base += wsA[w];
    float cpv[3];
    #pragma unroll
    for (int c = 0; c < 3; c++) cpv[c] = expf(base + l[c]);

    // ---- scan 2: inclusive cumsum of a_prev / clip(cp) ----
    float t[3]; float s2 = 0.f;
    #pragma unroll
    for (int c = 0; c < 3; c++) {
      if (k0 + c < 3000) s2 += a_prev[c] / fmaxf(cpv[c], EPSV);
      t[c] = s2;
    }
    float incl2 = s2;
    #pragma unroll
    for (int d = 1; d < 64; d <<= 1) {
      float o = __shfl_up(incl2, d);
      if (lane >= d) incl2 += o;
    }
    if (lane == 63) wsB[wid] = incl2;
    float excl2 = incl2 - s2;
    __syncthreads();                                  // barrier 2
    float off = excl2;
    for (int w = 0; w < wid; w++) off += wsB[w];

    size_t rbase = zbase + (size_t)i * 3000;
    #pragma unroll
    for (int c = 0; c < 3; c++) {
      int k = k0 + c;
      float an = pc[c] * cpv[c] * (off + t[c]);
      a_prev[c] = an;
      if (k < 3000) alpha_slot[rbase + k] = an;
    }
  }
}

// ---------------------------------------------------------------------------
// Chunkwise beta: per (b,q) row (grid = 2048). denom = 16-back moving sum of
// clipped exp(u-max); beta[h][k] = se[k] * sum_{m=k}^{k+15} alpha[h][m]/dn[m].
// ---------------------------------------------------------------------------
__global__ __launch_bounds__(256)
void beta_kernel(const float* __restrict__ ubuf, const float* __restrict__ alpha_slot,
                 float* __restrict__ beta_slot)
{
  __shared__ float se[3008];
  __shared__ float dn[3008];
  __shared__ float tt[3024];
  __shared__ float red[4];
  int bq = blockIdx.x;
  int b = bq >> 8, q = bq & 255;
  int tid = threadIdx.x;
  int lane = tid & 63, wid = tid >> 6;
  const float* urow = ubuf + (size_t)bq * 3000;
  float lmax = -3.0e38f;
  for (int i = tid; i < 3000; i += 256) { float v = urow[i]; se[i] = v; lmax = fmaxf(lmax, v); }
  #pragma unroll
  for (int d = 32; d > 0; d >>= 1) lmax = fmaxf(lmax, __shfl_xor(lmax, d));
  if (lane == 0) red[wid] = lmax;
  __syncthreads();
  float umax = fmaxf(fmaxf(red[0], red[1]), fmaxf(red[2], red[3]));
  for (int i = tid; i < 3000; i += 256) se[i] = fmaxf(expf(se[i] - umax), 1e-5f);
  if (tid < 24) tt[3000 + tid] = 0.f;              // forward-window zero pad
  __syncthreads();
  for (int k = tid; k < 3000; k += 256) {
    int lo = k - 15; if (lo < 0) lo = 0;
    float s = 0.f;
    for (int j = lo; j <= k; j++) s += se[j];
    dn[k] = s;
  }
  __syncthreads();
  for (int h = 0; h < 4; h++) {
    const float* arow = alpha_slot + ((size_t)((b * 4 + h) * 256 + q)) * 3000;
    for (int i = tid; i < 3000; i += 256) tt[i] = arow[i] / dn[i];
    __syncthreads();
    float* brow = beta_slot + ((size_t)((b * 4 + h) * 256 + q)) * 3000;
    for (int k = tid; k < 3000; k += 256) {
      float s = 0.f;
      #pragma unroll
      for (int j = 0; j < 16; j++) s += tt[k + j];
      brow[k] = se[k] * s;
    }
    __syncthreads();
  }
}

// ---------------------------------------------------------------------------
extern "C" void kernel_launch(void* const* d_in, const int* in_sizes, int n_in,
                              void* d_out, int out_size, void* d_ws, size_t ws_size,
                              hipStream_t stream)
{
  const float* key        = (const float*)d_in[0];
  const float* query      = (const float*)d_in[1];
  const float* w_key_ma   = (const float*)d_in[2];
  const float* b_key_ma   = (const float*)d_in[3];
  const float* w_query_ma = (const float*)d_in[4];
  const float* b_query_ma = (const float*)d_in[5];
  const float* rvec       = (const float*)d_in[6];
  const float* w_key_ca   = (const float*)d_in[7];
  const float* b_key_ca   = (const float*)d_in[8];
  const float* w_query_ca = (const float*)d_in[9];
  const float* b_query_ca = (const float*)d_in[10];
  const float* w_value    = (const float*)d_in[11];
  const float* b_value    = (const float*)d_in[12];

  // Outputs are FP32 (reference returns float32): cv | alpha | beta, flat.
  float* out       = (float*)d_out;
  float* cv_out    = out;                                  // (8,256,512)
  float* alpha_out = out + (size_t)1048576;                // (8,4,256,3000)
  float* beta_out  = alpha_out + (size_t)24576000;         // (8,4,256,3000)

  // workspace: kbuf (bf16, reused k_ma -> k_ca -> v) + qbuf (f32, reused
  // q_ma -> q_ca) + u (f32).  Total 53,346,304 bytes (~50.9 MiB).
  bf16*  kbuf  = (bf16*)d_ws;                        // 24000 x 512 bf16
  float* qbuf  = (float*)((char*)d_ws + 24576000);   // 2048 x 512 f32
  float* u_buf = (float*)((char*)d_ws + 24576000 + 4194304);  // 8x256x3000 f32
  if (ws_size < (size_t)24576000 + 4194304 + 24576000) return;  // diagnosable fail, no crash

  dim3 blk(256);

  // --- MA path: projections, then p_choose = sigmoid(qk/sqrt+r) into beta slot (fp32)
  gemm64<0,false,float,float,float><<<dim3(8,32,1),  blk, 0, stream>>>(query, w_query_ma, qbuf, 2048, 512,512, 512,512,512, 1, 0,0,0,0,0,0, b_query_ma, nullptr);
  gemm64<0,false,float,float,bf16 ><<<dim3(8,375,1), blk, 0, stream>>>(key,   w_key_ma,   kbuf, 24000,512,512, 512,512,512, 1, 0,0,0,0,0,0, b_key_ma,   nullptr);
  gemm64<1,true ,float,bf16 ,float><<<dim3(47,4,32), blk, 0, stream>>>(qbuf, kbuf, beta_out, 256,3000,128, 512,512,3000, 4,
      131072,128, 1536000,128, 3072000,768000, nullptr, rvec);

  // --- CA path: projections (reuse buffers), u = qk/sqrt (fp32 ws)
  gemm64<0,false,float,float,float><<<dim3(8,32,1),  blk, 0, stream>>>(query, w_query_ca, qbuf, 2048, 512,512, 512,512,512, 1, 0,0,0,0,0,0, b_query_ca, nullptr);
  gemm64<0,false,float,float,bf16 ><<<dim3(8,375,1), blk, 0, stream>>>(key,   w_key_ca,   kbuf, 24000,512,512, 512,512,512, 1, 0,0,0,0,0,0, b_key_ca,   nullptr);
  gemm64<2,true ,float,bf16 ,float><<<dim3(47,4,8),  blk, 0, stream>>>(qbuf, kbuf, u_buf, 256,3000,512, 512,512,3000, 1,
      131072,0, 1536000,0, 768000,0, nullptr, nullptr);

  // --- v projection (reuse kbuf; k_ca dead after u GEMM; stream-ordered)
  gemm64<0,false,float,float,bf16 ><<<dim3(8,375,1), blk, 0, stream>>>(key, w_value, kbuf, 24000,512,512, 512,512,512, 1, 0,0,0,0,0,0, b_value, nullptr);

  // --- fused cp + sequential alpha scan (reads p fp32, writes alpha fp32)
  scan_kernel<<<dim3(32), dim3(1024), 0, stream>>>(beta_out, alpha_out);

  // --- chunkwise beta (fp32, overwrites p_choose in beta slot)
  beta_kernel<<<dim3(2048), blk, 0, stream>>>(u_buf, alpha_out, beta_out);

  // --- cv = beta @ v  (A fp32, B bf16, C fp32)
  gemm64<3,false,float,bf16,float><<<dim3(2,4,32), blk, 0, stream>>>(beta_out, kbuf, cv_out, 256,128,3000, 3000,512,512, 4,
      3072000,768000, 1536000,128, 131072,128, nullptr, nullptr);
}

// Round 5
// 2139.049 us; speedup vs baseline: 1.2123x; 1.2123x over previous
//
#include <hip/hip_runtime.h>
#include <hip/hip_bf16.h>
#include <math.h>

#define EPSV 1e-6f
#define INV_SCALE 0.04419417382415922f   // 1/sqrt(512)

typedef __hip_bfloat16 bf16;

__device__ __forceinline__ float ldf(const float* p) { return *p; }
__device__ __forceinline__ float ldf(const bf16* p)  { return __bfloat162float(*p); }
__device__ __forceinline__ void  stf(float* p, float v) { *p = v; }
__device__ __forceinline__ void  stf(bf16* p, float v)  { *p = __float2bfloat16(v); }

// ---------------------------------------------------------------------------
// Generic 64x64-tile fp32-accumulate GEMM.  C = A * B(^T) [+ epilogue]
// MODE: 0 = +bias[n]; 1 = sigmoid(acc*INV_SCALE + r[h]); 2 = acc*INV_SCALE; 3 = plain
// BT  : false -> B is (Kd,N) row-major;  true -> B is (N,Kd) row-major (C=A*B^T)
// ATOM: epilogue uses atomicAdd (for K-split partial sums)
// z decode: ks = z%kdiv (K-chunk), zz = z/kdiv, bz = zz/hdiv, hz = zz%hdiv.
// LDS tiles padded to stride 68: write bank = (4*(t&15)+(t>>4))&31 -> 2-way
// (free), and 272B rows keep float4 reads 16B-aligned.
// ---------------------------------------------------------------------------
template<int MODE, bool BT, bool ATOM, typename TA, typename TB, typename TC>
__global__ __launch_bounds__(256)
void gemm64(const TA* __restrict__ A, const TB* __restrict__ B,
            TC* __restrict__ C, int M, int N, int Kd,
            int lda, int ldb, int ldc, int hdiv, int kdiv, int kc,
            long long sAb, long long sAh, long long sBb, long long sBh,
            long long sCb, long long sCh,
            const float* __restrict__ bias, const float* __restrict__ rvec)
{
  int z  = blockIdx.z;
  int ks = z % kdiv;  int zz = z / kdiv;
  int bz = zz / hdiv, hz = zz - bz * hdiv;
  A += (size_t)bz * sAb + (size_t)hz * sAh;
  B += (size_t)bz * sBb + (size_t)hz * sBh;
  C += (size_t)bz * sCb + (size_t)hz * sCh;
  // K-chunk offset (k is a column of A; row of B if !BT, column if BT)
  A += (size_t)ks * kc;
  B += BT ? (size_t)ks * kc : (size_t)ks * kc * ldb;
  int Ke = Kd - ks * kc; if (Ke > kc) Ke = kc;

  __shared__ __align__(16) float As[16][68];
  __shared__ __align__(16) float Bs[16][68];
  int tid = threadIdx.x;
  int tx = tid & 15, ty = tid >> 4;
  int m0 = blockIdx.y * 64, n0 = blockIdx.x * 64;
  float acc[4][4] = {};

  for (int k0 = 0; k0 < Ke; k0 += 16) {
    #pragma unroll
    for (int i = 0; i < 4; i++) {            // A tile: As[k][m]
      int idx = tid + i * 256;
      int rr = idx >> 4, cc = idx & 15;
      int mm = m0 + rr, kk = k0 + cc;
      As[cc][rr] = (mm < M && kk < Ke) ? ldf(&A[(size_t)mm * lda + kk]) : 0.f;
    }
    #pragma unroll
    for (int i = 0; i < 4; i++) {            // B tile: Bs[k][n]
      int idx = tid + i * 256;
      if (BT) {
        int rr = idx >> 4, cc = idx & 15;
        int nn = n0 + rr, kk = k0 + cc;
        Bs[cc][rr] = (nn < N && kk < Ke) ? ldf(&B[(size_t)nn * ldb + kk]) : 0.f;
      } else {
        int rr = idx >> 6, cc = idx & 63;
        int nn = n0 + cc, kk = k0 + rr;
        Bs[rr][cc] = (nn < N && kk < Ke) ? ldf(&B[(size_t)kk * ldb + nn]) : 0.f;
      }
    }
    __syncthreads();
    #pragma unroll
    for (int kk = 0; kk < 16; kk++) {
      float4 av = *(const float4*)&As[kk][ty * 4];
      float4 bv = *(const float4*)&Bs[kk][tx * 4];
      float a_[4] = {av.x, av.y, av.z, av.w};
      float b_[4] = {bv.x, bv.y, bv.z, bv.w};
      #pragma unroll
      for (int i2 = 0; i2 < 4; i2++)
        #pragma unroll
        for (int j2 = 0; j2 < 4; j2++)
          acc[i2][j2] = fmaf(a_[i2], b_[j2], acc[i2][j2]);
    }
    __syncthreads();
  }

  float radd = 0.f;
  if (MODE == 1) radd = rvec[hz];
  #pragma unroll
  for (int i2 = 0; i2 < 4; i2++) {
    int row = m0 + ty * 4 + i2;
    if (row >= M) continue;
    #pragma unroll
    for (int j2 = 0; j2 < 4; j2++) {
      int col = n0 + tx * 4 + j2;
      if (col >= N) continue;
      float v = acc[i2][j2];
      if (MODE == 0)      v += bias[col];
      else if (MODE == 1) v = 1.f / (1.f + expf(-(v * INV_SCALE + radd)));
      else if (MODE == 2) v *= INV_SCALE;
      if (ATOM) atomicAdd((float*)&C[(size_t)row * ldc + col], v);
      else      stf(&C[(size_t)row * ldc + col], v);
    }
  }
}

// ---------------------------------------------------------------------------
// cp = safe_cumprod(1-p) per (b,h,q) row. Fully parallel: grid = 8192 rows
// (B*H_MA*Q). Reads p (fp32, beta slot), writes cp (fp32, alpha slot).
// ---------------------------------------------------------------------------
__global__ __launch_bounds__(256)
void cp_kernel(const float* __restrict__ p_slot, float* __restrict__ cp_out)
{
  __shared__ float wsum[4];
  int row = blockIdx.x;
  int tid = threadIdx.x;
  int lane = tid & 63, wid = tid >> 6;
  const float* p = p_slot + (size_t)row * 3000;
  float l[12]; float s = 0.f;
  int k0 = tid * 12;
  #pragma unroll
  for (int j = 0; j < 12; j++) {
    int k = k0 + j;
    l[j] = s;                                     // local exclusive prefix
    if (k < 3000)
      s += logf(fminf(fmaxf(1.f - p[k], EPSV), 1.f));
  }
  float incl = s;
  #pragma unroll
  for (int d = 1; d < 64; d <<= 1) {
    float o = __shfl_up(incl, d);
    if (lane >= d) incl += o;
  }
  float excl = incl - s;
  if (lane == 63) wsum[wid] = incl;
  __syncthreads();
  float base = excl;
  for (int w = 0; w < wid; w++) base += wsum[w];
  float* o = cp_out + (size_t)row * 3000;
  #pragma unroll
  for (int j = 0; j < 12; j++) {
    int k = k0 + j;
    if (k < 3000) o[k] = expf(base + l[j]);
  }
}

// ---------------------------------------------------------------------------
// Sequential monotonic-alpha scan, cp precomputed. One block per (b,h).
// Per q-step: ONE prefix scan of a_prev/clip(cp) -> alpha_i. Ping-pong
// wave-sum buffers -> a single barrier per step. p and cp rows prefetched.
// Reads cp from the alpha slot and overwrites the same row with alpha
// (same-thread read-before-write; race-free).
// ---------------------------------------------------------------------------
__global__ __launch_bounds__(1024)
void scan_kernel(const float* __restrict__ p_slot, float* __restrict__ alpha_slot)
{
  __shared__ float ws[2][16];
  int z = blockIdx.x;                 // b*4+h
  int tid = threadIdx.x;
  int lane = tid & 63, wid = tid >> 6;
  int k0 = tid * 3;
  float a_prev[3];
  #pragma unroll
  for (int c = 0; c < 3; c++) a_prev[c] = (k0 + c == 0) ? 1.f : 0.f;
  size_t zbase = (size_t)z * 256 * 3000;

  float pv[3], cv_[3];                // prefetched p / cp rows
  #pragma unroll
  for (int c = 0; c < 3; c++) {
    int k = k0 + c;
    pv[c]  = (k < 3000) ? p_slot[zbase + k]     : 0.f;
    cv_[c] = (k < 3000) ? alpha_slot[zbase + k] : 1.f;
  }

  for (int i = 0; i < 256; i++) {
    float pc[3] = {pv[0], pv[1], pv[2]};
    float cc[3] = {cv_[0], cv_[1], cv_[2]};
    if (i < 255) {                    // prefetch next rows (hide HBM latency)
      size_t nbase = zbase + (size_t)(i + 1) * 3000;
      #pragma unroll
      for (int c = 0; c < 3; c++) {
        int k = k0 + c;
        pv[c]  = (k < 3000) ? p_slot[nbase + k]     : 0.f;
        cv_[c] = (k < 3000) ? alpha_slot[nbase + k] : 1.f;
      }
    }
    // inclusive cumsum of a_prev / clip(cp)
    float t[3]; float s = 0.f;
    #pragma unroll
    for (int c = 0; c < 3; c++) {
      if (k0 + c < 3000) s += a_prev[c] / fmaxf(cc[c], EPSV);
      t[c] = s;
    }
    float incl = s;
    #pragma unroll
    for (int d = 1; d < 64; d <<= 1) {
      float o = __shfl_up(incl, d);
      if (lane >= d) incl += o;
    }
    if (lane == 63) ws[i & 1][wid] = incl;
    float excl = incl - s;
    __syncthreads();                  // single barrier per step (ping-pong)
    float off = excl;
    for (int w = 0; w < wid; w++) off += ws[i & 1][w];

    size_t rbase = zbase + (size_t)i * 3000;
    #pragma unroll
    for (int c = 0; c < 3; c++) {
      int k = k0 + c;
      float an = pc[c] * cc[c] * (off + t[c]);
      a_prev[c] = an;
      if (k < 3000) alpha_slot[rbase + k] = an;
    }
  }
}

// ---------------------------------------------------------------------------
// Chunkwise beta: per (b,q) row (grid = 2048). denom = 16-back moving sum of
// clipped exp(u-max); beta[h][k] = se[k] * sum_{m=k}^{k+15} alpha[h][m]/dn[m].
// ---------------------------------------------------------------------------
__global__ __launch_bounds__(256)
void beta_kernel(const float* __restrict__ ubuf, const float* __restrict__ alpha_slot,
                 float* __restrict__ beta_slot)
{
  __shared__ float se[3008];
  __shared__ float dn[3008];
  __shared__ float tt[3024];
  __shared__ float red[4];
  int bq = blockIdx.x;
  int b = bq >> 8, q = bq & 255;
  int tid = threadIdx.x;
  int lane = tid & 63, wid = tid >> 6;
  const float* urow = ubuf + (size_t)bq * 3000;
  float lmax = -3.0e38f;
  for (int i = tid; i < 3000; i += 256) { float v = urow[i]; se[i] = v; lmax = fmaxf(lmax, v); }
  #pragma unroll
  for (int d = 32; d > 0; d >>= 1) lmax = fmaxf(lmax, __shfl_xor(lmax, d));
  if (lane == 0) red[wid] = lmax;
  __syncthreads();
  float umax = fmaxf(fmaxf(red[0], red[1]), fmaxf(red[2], red[3]));
  for (int i = tid; i < 3000; i += 256) se[i] = fmaxf(expf(se[i] - umax), 1e-5f);
  if (tid < 24) tt[3000 + tid] = 0.f;              // forward-window zero pad
  __syncthreads();
  for (int k = tid; k < 3000; k += 256) {
    int lo = k - 15; if (lo < 0) lo = 0;
    float s = 0.f;
    for (int j = lo; j <= k; j++) s += se[j];
    dn[k] = s;
  }
  __syncthreads();
  for (int h = 0; h < 4; h++) {
    const float* arow = alpha_slot + ((size_t)((b * 4 + h) * 256 + q)) * 3000;
    for (int i = tid; i < 3000; i += 256) tt[i] = arow[i] / dn[i];
    __syncthreads();
    float* brow = beta_slot + ((size_t)((b * 4 + h) * 256 + q)) * 3000;
    for (int k = tid; k < 3000; k += 256) {
      float s = 0.f;
      #pragma unroll
      for (int j = 0; j < 16; j++) s += tt[k + j];
      brow[k] = se[k] * s;
    }
    __syncthreads();
  }
}

// ---------------------------------------------------------------------------
extern "C" void kernel_launch(void* const* d_in, const int* in_sizes, int n_in,
                              void* d_out, int out_size, void* d_ws, size_t ws_size,
                              hipStream_t stream)
{
  const float* key        = (const float*)d_in[0];
  const float* query      = (const float*)d_in[1];
  const float* w_key_ma   = (const float*)d_in[2];
  const float* b_key_ma   = (const float*)d_in[3];
  const float* w_query_ma = (const float*)d_in[4];
  const float* b_query_ma = (const float*)d_in[5];
  const float* rvec       = (const float*)d_in[6];
  const float* w_key_ca   = (const float*)d_in[7];
  const float* b_key_ca   = (const float*)d_in[8];
  const float* w_query_ca = (const float*)d_in[9];
  const float* b_query_ca = (const float*)d_in[10];
  const float* w_value    = (const float*)d_in[11];
  const float* b_value    = (const float*)d_in[12];

  // Outputs are FP32: cv | alpha | beta, flat.
  float* out       = (float*)d_out;
  float* cv_out    = out;                                  // (8,256,512)
  float* alpha_out = out + (size_t)1048576;                // (8,4,256,3000)
  float* beta_out  = alpha_out + (size_t)24576000;         // (8,4,256,3000)

  // workspace: kbuf (bf16, reused k_ma -> k_ca -> v) + qbuf (f32, reused
  // q_ma -> q_ca) + u (f32).  Total 53,346,304 bytes (~50.9 MiB).
  bf16*  kbuf  = (bf16*)d_ws;                        // 24000 x 512 bf16
  float* qbuf  = (float*)((char*)d_ws + 24576000);   // 2048 x 512 f32
  float* u_buf = (float*)((char*)d_ws + 24576000 + 4194304);  // 8x256x3000 f32
  if (ws_size < (size_t)24576000 + 4194304 + 24576000) return;

  dim3 blk(256);

  // zero cv_out for the K-split atomic epilogue (capturable async memset)
  hipMemsetAsync(cv_out, 0, (size_t)1048576 * sizeof(float), stream);

  // --- MA path: projections, then p_choose = sigmoid(qk/sqrt+r) into beta slot (fp32)
  gemm64<0,false,false,float,float,float><<<dim3(8,32,1),  blk, 0, stream>>>(query, w_query_ma, qbuf, 2048, 512,512, 512,512,512, 1,1,512, 0,0,0,0,0,0, b_query_ma, nullptr);
  gemm64<0,false,false,float,float,bf16 ><<<dim3(8,375,1), blk, 0, stream>>>(key,   w_key_ma,   kbuf, 24000,512,512, 512,512,512, 1,1,512, 0,0,0,0,0,0, b_key_ma,   nullptr);
  gemm64<1,true ,false,float,bf16 ,float><<<dim3(47,4,32), blk, 0, stream>>>(qbuf, kbuf, beta_out, 256,3000,128, 512,512,3000, 4,1,128,
      131072,128, 1536000,128, 3072000,768000, nullptr, rvec);

  // --- CA path: projections (reuse buffers), u = qk/sqrt (fp32 ws)
  gemm64<0,false,false,float,float,float><<<dim3(8,32,1),  blk, 0, stream>>>(query, w_query_ca, qbuf, 2048, 512,512, 512,512,512, 1,1,512, 0,0,0,0,0,0, b_query_ca, nullptr);
  gemm64<0,false,false,float,float,bf16 ><<<dim3(8,375,1), blk, 0, stream>>>(key,   w_key_ca,   kbuf, 24000,512,512, 512,512,512, 1,1,512, 0,0,0,0,0,0, b_key_ca,   nullptr);
  gemm64<2,true ,false,float,bf16 ,float><<<dim3(47,4,8),  blk, 0, stream>>>(qbuf, kbuf, u_buf, 256,3000,512, 512,512,3000, 1,1,512,
      131072,0, 1536000,0, 768000,0, nullptr, nullptr);

  // --- v projection (reuse kbuf; k_ca dead after u GEMM; stream-ordered)
  gemm64<0,false,false,float,float,bf16 ><<<dim3(8,375,1), blk, 0, stream>>>(key, w_value, kbuf, 24000,512,512, 512,512,512, 1,1,512, 0,0,0,0,0,0, b_value, nullptr);

  // --- parallel cp (fp32 into alpha slot; 8192 = B*H_MA*Q rows) ---
  cp_kernel<<<dim3(8192), blk, 0, stream>>>(beta_out, alpha_out);

  // --- sequential alpha scan (reads p + cp, overwrites cp rows with alpha)
  scan_kernel<<<dim3(32), dim3(1024), 0, stream>>>(beta_out, alpha_out);

  // --- chunkwise beta (fp32, overwrites p_choose in beta slot)
  beta_kernel<<<dim3(2048), blk, 0, stream>>>(u_buf, alpha_out, beta_out);

  // --- cv = beta @ v, K-split x8 with atomic accumulate ---
  gemm64<3,false,true ,float,bf16,float><<<dim3(2,4,256), blk, 0, stream>>>(beta_out, kbuf, cv_out, 256,128,3000, 3000,512,512, 4,8,384,
      3072000,768000, 1536000,128, 131072,128, nullptr, nullptr);
}

// Round 8
// 1215.338 us; speedup vs baseline: 2.1338x; 1.7600x over previous
//
#include <hip/hip_runtime.h>
#include <hip/hip_bf16.h>
#include <math.h>

#define EPSV 1e-6f
#define INV_SCALE 0.04419417382415922f   // 1/sqrt(512)

typedef _Float16 half_t;
typedef __attribute__((ext_vector_type(8))) _Float16 half8;
typedef __attribute__((ext_vector_type(4))) _Float16 half4v;
typedef __attribute__((ext_vector_type(4))) float    f32x4;

__device__ __forceinline__ float ldf(const float* p)  { return *p; }
__device__ __forceinline__ float ldf(const half_t* p) { return (float)*p; }
__device__ __forceinline__ void  stf(float* p, float v)  { *p = v; }
__device__ __forceinline__ void  stf(half_t* p, float v) { *p = (half_t)v; }

// ---------------------------------------------------------------------------
// Weight transpose + f16 convert: WT[n][k] = (half)W[k][n], 512x512.
// Grid (16,16) of 32x32 tiles, 256 threads.
// ---------------------------------------------------------------------------
__global__ __launch_bounds__(256)
void wtrans(const float* __restrict__ W, half_t* __restrict__ WT)
{
  __shared__ float t[32][33];
  int bx = blockIdx.x, by = blockIdx.y;   // bx: k-tile, by: n-tile
  int tid = threadIdx.x;
  int r = tid >> 3, cq = tid & 7;
  float4 v = *(const float4*)&W[(size_t)(bx * 32 + r) * 512 + by * 32 + cq * 4];
  t[r][cq * 4 + 0] = v.x; t[r][cq * 4 + 1] = v.y;
  t[r][cq * 4 + 2] = v.z; t[r][cq * 4 + 3] = v.w;
  __syncthreads();
  half4v o;
  o[0] = (half_t)t[cq * 4 + 0][r];
  o[1] = (half_t)t[cq * 4 + 1][r];
  o[2] = (half_t)t[cq * 4 + 2][r];
  o[3] = (half_t)t[cq * 4 + 3][r];
  *(half4v*)&WT[(size_t)(by * 32 + r) * 512 + bx * 32 + cq * 4] = o;
}

// ---------------------------------------------------------------------------
// MFMA GEMM: C = A(fp32,[M][lda]) * BT^T (BT: f16 [N][ldb], i.e. C=A*B with
// B[k][n]=BT[n][k]) [+ epilogue].  v_mfma_f32_16x16x32_f16.
// Tile 128x128, BK=32, 4 waves (2x2 of 64x64).  LDS fragment-major:
// As[kb][row][8] so a lane's 8-contig-k fragment is one ds_read_b128;
// 16-lane groups read 256B contiguous (conflict-free).
// C/D layout (m89-verified): col=lane&15, row=(lane>>4)*4+reg.
// MODE: 0=+bias[n]; 1=sigmoid(acc*INV_SCALE+rvec[hz]); 2=acc*INV_SCALE.
// Batch via blockIdx.z: bz=z/hdiv, hz=z%hdiv, per-operand strides.
// ---------------------------------------------------------------------------
template<int MODE, typename TC>
__global__ __launch_bounds__(256)
void mgemm(const float* __restrict__ A, const half_t* __restrict__ BT,
           TC* __restrict__ C, int M, int N, int Kd,
           int lda, int ldb, int ldc, int hdiv,
           long long sAb, long long sAh, long long sBb, long long sBh,
           long long sCb, long long sCh,
           const float* __restrict__ bias, const float* __restrict__ rvec)
{
  int z = blockIdx.z;
  int bz = z / hdiv, hz = z - bz * hdiv;
  A  += (size_t)bz * sAb + (size_t)hz * sAh;
  BT += (size_t)bz * sBb + (size_t)hz * sBh;
  C  += (size_t)bz * sCb + (size_t)hz * sCh;

  __shared__ half_t As[4][128][8];   // [k/8][m][k%8]  8 KB
  __shared__ half_t Bs[4][128][8];   // [k/8][n][k%8]  8 KB
  int tid = threadIdx.x;
  int lane = tid & 63, wid = tid >> 6;
  int wm = wid >> 1, wn = wid & 1;             // wave 64x64 sub-tile
  int m0 = blockIdx.y * 128, n0 = blockIdx.x * 128;

  f32x4 acc[4][4] = {};

  for (int k0 = 0; k0 < Kd; k0 += 32) {
    // stage A: 128x32 fp32 -> f16 (1024 float4 chunks, 4/thread)
    #pragma unroll
    for (int i = 0; i < 4; i++) {
      int ch = tid + i * 256;
      int m = ch >> 3, cq = ch & 7, k = cq * 4;
      float4 v = make_float4(0.f, 0.f, 0.f, 0.f);
      if (m0 + m < M) v = *(const float4*)&A[(size_t)(m0 + m) * lda + k0 + k];
      half4v h;
      h[0] = (half_t)v.x; h[1] = (half_t)v.y; h[2] = (half_t)v.z; h[3] = (half_t)v.w;
      *(half4v*)&As[cq >> 1][m][(cq & 1) * 4] = h;
    }
    // stage B: 128x32 f16 from BT (512 16B chunks, 2/thread)
    #pragma unroll
    for (int i = 0; i < 2; i++) {
      int ch = tid + i * 256;
      int n = ch >> 2, kb = ch & 3;
      half8 v = {(_Float16)0,(_Float16)0,(_Float16)0,(_Float16)0,
                 (_Float16)0,(_Float16)0,(_Float16)0,(_Float16)0};
      if (n0 + n < N) v = *(const half8*)&BT[(size_t)(n0 + n) * ldb + k0 + kb * 8];
      *(half8*)&Bs[kb][n][0] = v;
    }
    __syncthreads();
    int kb = lane >> 4, r = lane & 15;
    half8 af[4], bfv[4];
    #pragma unroll
    for (int mi = 0; mi < 4; mi++) af[mi]  = *(const half8*)&As[kb][wm * 64 + mi * 16 + r][0];
    #pragma unroll
    for (int ni = 0; ni < 4; ni++) bfv[ni] = *(const half8*)&Bs[kb][wn * 64 + ni * 16 + r][0];
    #pragma unroll
    for (int mi = 0; mi < 4; mi++)
      #pragma unroll
      for (int ni = 0; ni < 4; ni++)
        acc[mi][ni] = __builtin_amdgcn_mfma_f32_16x16x32_f16(af[mi], bfv[ni], acc[mi][ni], 0, 0, 0);
    __syncthreads();
  }

  float radd = (MODE == 1) ? rvec[hz] : 0.f;
  int r = lane & 15, g = lane >> 4;
  #pragma unroll
  for (int mi = 0; mi < 4; mi++) {
    #pragma unroll
    for (int ni = 0; ni < 4; ni++) {
      int col = n0 + wn * 64 + ni * 16 + r;
      if (col >= N) continue;
      float bv = (MODE == 0) ? bias[col] : 0.f;
      #pragma unroll
      for (int j = 0; j < 4; j++) {
        int row = m0 + wm * 64 + mi * 16 + g * 4 + j;
        if (row >= M) continue;
        float v = acc[mi][ni][j];
        if (MODE == 0)      v += bv;
        else if (MODE == 1) v = 1.f / (1.f + expf(-(v * INV_SCALE + radd)));
        else if (MODE == 2) v *= INV_SCALE;
        stf(&C[(size_t)row * ldc + col], v);
      }
    }
  }
}

// ---------------------------------------------------------------------------
// fp32-FMA 64x64 GEMM (kept for cv: B is K-major fp16, K-split atomic).
// LDS padded to 68 (write 2-way, reads 16B-aligned).
// ---------------------------------------------------------------------------
template<int MODE, bool BT, bool ATOM, typename TA, typename TB, typename TC>
__global__ __launch_bounds__(256)
void gemm64(const TA* __restrict__ A, const TB* __restrict__ B,
            TC* __restrict__ C, int M, int N, int Kd,
            int lda, int ldb, int ldc, int hdiv, int kdiv, int kc,
            long long sAb, long long sAh, long long sBb, long long sBh,
            long long sCb, long long sCh,
            const float* __restrict__ bias, const float* __restrict__ rvec)
{
  int z  = blockIdx.z;
  int ks = z % kdiv;  int zz = z / kdiv;
  int bz = zz / hdiv, hz = zz - bz * hdiv;
  A += (size_t)bz * sAb + (size_t)hz * sAh;
  B += (size_t)bz * sBb + (size_t)hz * sBh;
  C += (size_t)bz * sCb + (size_t)hz * sCh;
  A += (size_t)ks * kc;
  B += BT ? (size_t)ks * kc : (size_t)ks * kc * ldb;
  int Ke = Kd - ks * kc; if (Ke > kc) Ke = kc;

  __shared__ __align__(16) float As[16][68];
  __shared__ __align__(16) float Bs[16][68];
  int tid = threadIdx.x;
  int tx = tid & 15, ty = tid >> 4;
  int m0 = blockIdx.y * 64, n0 = blockIdx.x * 64;
  float acc[4][4] = {};

  for (int k0 = 0; k0 < Ke; k0 += 16) {
    #pragma unroll
    for (int i = 0; i < 4; i++) {
      int idx = tid + i * 256;
      int rr = idx >> 4, cc = idx & 15;
      int mm = m0 + rr, kk = k0 + cc;
      As[cc][rr] = (mm < M && kk < Ke) ? ldf(&A[(size_t)mm * lda + kk]) : 0.f;
    }
    #pragma unroll
    for (int i = 0; i < 4; i++) {
      int idx = tid + i * 256;
      if (BT) {
        int rr = idx >> 4, cc = idx & 15;
        int nn = n0 + rr, kk = k0 + cc;
        Bs[cc][rr] = (nn < N && kk < Ke) ? ldf(&B[(size_t)nn * ldb + kk]) : 0.f;
      } else {
        int rr = idx >> 6, cc = idx & 63;
        int nn = n0 + cc, kk = k0 + rr;
        Bs[rr][cc] = (nn < N && kk < Ke) ? ldf(&B[(size_t)kk * ldb + nn]) : 0.f;
      }
    }
    __syncthreads();
    #pragma unroll
    for (int kk = 0; kk < 16; kk++) {
      float4 av = *(const float4*)&As[kk][ty * 4];
      float4 bv = *(const float4*)&Bs[kk][tx * 4];
      float a_[4] = {av.x, av.y, av.z, av.w};
      float b_[4] = {bv.x, bv.y, bv.z, bv.w};
      #pragma unroll
      for (int i2 = 0; i2 < 4; i2++)
        #pragma unroll
        for (int j2 = 0; j2 < 4; j2++)
          acc[i2][j2] = fmaf(a_[i2], b_[j2], acc[i2][j2]);
    }
    __syncthreads();
  }

  #pragma unroll
  for (int i2 = 0; i2 < 4; i2++) {
    int row = m0 + ty * 4 + i2;
    if (row >= M) continue;
    #pragma unroll
    for (int j2 = 0; j2 < 4; j2++) {
      int col = n0 + tx * 4 + j2;
      if (col >= N) continue;
      float v = acc[i2][j2];
      if (MODE == 0) v += bias[col];
      if (ATOM) atomicAdd((float*)&C[(size_t)row * ldc + col], v);
      else      stf(&C[(size_t)row * ldc + col], v);
    }
  }
}

// ---------------------------------------------------------------------------
// Fused cp + monotonic-alpha scan, software-pipelined, ONE barrier/step.
// At iter i: scan2 finishes alpha_i (using cpv_i from the pipeline) while
// scan1 computes cp_{i+1} from p row i+1 — both share one __syncthreads.
// cp lives only in registers (no cp memory traffic; cp_kernel deleted).
// 24 KB/step/block HBM traffic (p read + alpha write) vs 36 KB before.
// ---------------------------------------------------------------------------
__global__ __launch_bounds__(1024)
void scan_kernel(const float* __restrict__ p_slot, float* __restrict__ alpha_slot)
{
  __shared__ float wsA[2][16], wsB[2][16];
  int z = blockIdx.x;                 // b*4+h
  int tid = threadIdx.x;
  int lane = tid & 63, wid = tid >> 6;
  int k0 = tid * 3;
  size_t zbase = (size_t)z * 256 * 3000;

  float a_prev[3];
  #pragma unroll
  for (int c = 0; c < 3; c++) a_prev[c] = (k0 + c == 0) ? 1.f : 0.f;

  float pc[3], pv[3];
  #pragma unroll
  for (int c = 0; c < 3; c++) {
    int k = k0 + c;
    pc[c] = (k < 3000) ? p_slot[zbase + k]        : 0.f;   // row 0
    pv[c] = (k < 3000) ? p_slot[zbase + 3000 + k] : 0.f;   // row 1
  }

  // prologue: cp for row 0
  float cpv[3];
  {
    float l[3], s = 0.f;
    #pragma unroll
    for (int c = 0; c < 3; c++) {
      l[c] = s;
      if (k0 + c < 3000) s += logf(fminf(fmaxf(1.f - pc[c], EPSV), 1.f));
    }
    float incl = s;
    #pragma unroll
    for (int d = 1; d < 64; d <<= 1) { float o = __shfl_up(incl, d); if (lane >= d) incl += o; }
    if (lane == 63) wsA[1][wid] = incl;
    float excl = incl - s;
    __syncthreads();
    float base = excl;
    for (int w = 0; w < wid; w++) base += wsA[1][w];
    #pragma unroll
    for (int c = 0; c < 3; c++) cpv[c] = expf(base + l[c]);
  }

  for (int i = 0; i < 256; i++) {
    int par = i & 1;
    // scan2: inclusive cumsum of a_prev / clip(cp_i)
    float t[3], s2 = 0.f;
    #pragma unroll
    for (int c = 0; c < 3; c++) {
      if (k0 + c < 3000) s2 += a_prev[c] / fmaxf(cpv[c], EPSV);
      t[c] = s2;
    }
    float incl2 = s2;
    #pragma unroll
    for (int d = 1; d < 64; d <<= 1) { float o = __shfl_up(incl2, d); if (lane >= d) incl2 += o; }
    if (lane == 63) wsB[par][wid] = incl2;
    float excl2 = incl2 - s2;

    // scan1: cp for row i+1 (recurrence-independent)
    float pn[3] = {pv[0], pv[1], pv[2]};
    float l[3], s1 = 0.f;
    #pragma unroll
    for (int c = 0; c < 3; c++) {
      l[c] = s1;
      if (k0 + c < 3000) s1 += logf(fminf(fmaxf(1.f - pn[c], EPSV), 1.f));
    }
    float incl1 = s1;
    #pragma unroll
    for (int d = 1; d < 64; d <<= 1) { float o = __shfl_up(incl1, d); if (lane >= d) incl1 += o; }
    if (lane == 63) wsA[par][wid] = incl1;
    float excl1 = incl1 - s1;

    __syncthreads();                               // the single barrier

    float off = excl2;
    for (int w = 0; w < wid; w++) off += wsB[par][w];
    size_t rbase = zbase + (size_t)i * 3000;
    #pragma unroll
    for (int c = 0; c < 3; c++) {
      int k = k0 + c;
      float an = pc[c] * cpv[c] * (off + t[c]);
      a_prev[c] = an;
      if (k < 3000) alpha_slot[rbase + k] = an;
    }
    float base1 = excl1;
    for (int w = 0; w < wid; w++) base1 += wsA[par][w];
    #pragma unroll
    for (int c = 0; c < 3; c++) { cpv[c] = expf(base1 + l[c]); pc[c] = pn[c]; }
    if (i < 254) {                                 // prefetch p row i+2
      size_t nb = zbase + (size_t)(i + 2) * 3000;
      #pragma unroll
      for (int c = 0; c < 3; c++) {
        int k = k0 + c;
        pv[c] = (k < 3000) ? p_slot[nb + k] : 0.f;
      }
    }
  }
}

// ---------------------------------------------------------------------------
// Chunkwise beta (unchanged).
// ---------------------------------------------------------------------------
__global__ __launch_bounds__(256)
void beta_kernel(const float* __restrict__ ubuf, const float* __restrict__ alpha_slot,
                 float* __restrict__ beta_slot)
{
  __shared__ float se[3008];
  __shared__ float dn[3008];
  __shared__ float tt[3024];
  __shared__ float red[4];
  int bq = blockIdx.x;
  int b = bq >> 8, q = bq & 255;
  int tid = threadIdx.x;
  int lane = tid & 63, wid = tid >> 6;
  const float* urow = ubuf + (size_t)bq * 3000;
  float lmax = -3.0e38f;
  for (int i = tid; i < 3000; i += 256) { float v = urow[i]; se[i] = v; lmax = fmaxf(lmax, v); }
  #pragma unroll
  for (int d = 32; d > 0; d >>= 1) lmax = fmaxf(lmax, __shfl_xor(lmax, d));
  if (lane == 0) red[wid] = lmax;
  __syncthreads();
  float umax = fmaxf(fmaxf(red[0], red[1]), fmaxf(red[2], red[3]));
  for (int i = tid; i < 3000; i += 256) se[i] = fmaxf(expf(se[i] - umax), 1e-5f);
  if (tid < 24) tt[3000 + tid] = 0.f;
  __syncthreads();
  for (int k = tid; k < 3000; k += 256) {
    int lo = k - 15; if (lo < 0) lo = 0;
    float s = 0.f;
    for (int j = lo; j <= k; j++) s += se[j];
    dn[k] = s;
  }
  __syncthreads();
  for (int h = 0; h < 4; h++) {
    const float* arow = alpha_slot + ((size_t)((b * 4 + h) * 256 + q)) * 3000;
    for (int i = tid; i < 3000; i += 256) tt[i] = arow[i] / dn[i];
    __syncthreads();
    float* brow = beta_slot + ((size_t)((b * 4 + h) * 256 + q)) * 3000;
    for (int k = tid; k < 3000; k += 256) {
      float s = 0.f;
      #pragma unroll
      for (int j = 0; j < 16; j++) s += tt[k + j];
      brow[k] = se[k] * s;
    }
    __syncthreads();
  }
}

// ---------------------------------------------------------------------------
extern "C" void kernel_launch(void* const* d_in, const int* in_sizes, int n_in,
                              void* d_out, int out_size, void* d_ws, size_t ws_size,
                              hipStream_t stream)
{
  const float* key        = (const float*)d_in[0];
  const float* query      = (const float*)d_in[1];
  const float* w_key_ma   = (const float*)d_in[2];
  const float* b_key_ma   = (const float*)d_in[3];
  const float* w_query_ma = (const float*)d_in[4];
  const float* b_query_ma = (const float*)d_in[5];
  const float* rvec       = (const float*)d_in[6];
  const float* w_key_ca   = (const float*)d_in[7];
  const float* b_key_ca   = (const float*)d_in[8];
  const float* w_query_ca = (const float*)d_in[9];
  const float* b_query_ca = (const float*)d_in[10];
  const float* w_value    = (const float*)d_in[11];
  const float* b_value    = (const float*)d_in[12];

  // Outputs FP32: cv | alpha | beta, flat.
  float* out       = (float*)d_out;
  float* cv_out    = out;                                  // (8,256,512)
  float* alpha_out = out + (size_t)1048576;                // (8,4,256,3000)
  float* beta_out  = alpha_out + (size_t)24576000;         // (8,4,256,3000)

  // workspace: kbuf f16 (k_ma -> k_ca -> v) | qbuf f32 (q_ma -> q_ca) |
  // u f32 | 5x W^T f16.  Total 55,967,744 B (~53.4 MiB).
  half_t* kbuf   = (half_t*)d_ws;                              // 24000x512
  float*  qbuf   = (float*)((char*)d_ws + 24576000);           // 2048x512
  float*  u_buf  = (float*)((char*)d_ws + 28770304);           // 8x256x3000
  half_t* wt_qma = (half_t*)((char*)d_ws + 53346304);
  half_t* wt_kma = (half_t*)((char*)d_ws + 53870592);
  half_t* wt_qca = (half_t*)((char*)d_ws + 54394880);
  half_t* wt_kca = (half_t*)((char*)d_ws + 54919168);
  half_t* wt_v   = (half_t*)((char*)d_ws + 55443456);
  if (ws_size < (size_t)55967744) return;

  dim3 blk(256);
  dim3 tgrid(16, 16);

  hipMemsetAsync(cv_out, 0, (size_t)1048576 * sizeof(float), stream);

  // weight transposes (f32 -> f16 [N][K])
  wtrans<<<tgrid, blk, 0, stream>>>(w_query_ma, wt_qma);
  wtrans<<<tgrid, blk, 0, stream>>>(w_key_ma,   wt_kma);
  wtrans<<<tgrid, blk, 0, stream>>>(w_query_ca, wt_qca);
  wtrans<<<tgrid, blk, 0, stream>>>(w_key_ca,   wt_kca);
  wtrans<<<tgrid, blk, 0, stream>>>(w_value,    wt_v);

  // --- MA path ---
  mgemm<0,float ><<<dim3(4,16,1),  blk, 0, stream>>>(query, wt_qma, qbuf, 2048, 512, 512, 512,512,512, 1, 0,0,0,0,0,0, b_query_ma, nullptr);
  mgemm<0,half_t><<<dim3(4,188,1), blk, 0, stream>>>(key,   wt_kma, kbuf, 24000,512, 512, 512,512,512, 1, 0,0,0,0,0,0, b_key_ma,   nullptr);
  mgemm<1,float ><<<dim3(24,2,32), blk, 0, stream>>>(qbuf,  kbuf, beta_out, 256,3000, 128, 512,512,3000, 4,
      131072,128, 1536000,128, 3072000,768000, nullptr, rvec);

  // --- CA path ---
  mgemm<0,float ><<<dim3(4,16,1),  blk, 0, stream>>>(query, wt_qca, qbuf, 2048, 512, 512, 512,512,512, 1, 0,0,0,0,0,0, b_query_ca, nullptr);
  mgemm<0,half_t><<<dim3(4,188,1), blk, 0, stream>>>(key,   wt_kca, kbuf, 24000,512, 512, 512,512,512, 1, 0,0,0,0,0,0, b_key_ca,   nullptr);
  mgemm<2,float ><<<dim3(24,2,8),  blk, 0, stream>>>(qbuf,  kbuf, u_buf, 256,3000, 512, 512,512,3000, 1,
      131072,0, 1536000,0, 768000,0, nullptr, nullptr);

  // --- v projection (reuse kbuf) ---
  mgemm<0,half_t><<<dim3(4,188,1), blk, 0, stream>>>(key, wt_v, kbuf, 24000,512, 512, 512,512,512, 1, 0,0,0,0,0,0, b_value, nullptr);

  // --- fused cp + alpha scan (single barrier/step) ---
  scan_kernel<<<dim3(32), dim3(1024), 0, stream>>>(beta_out, alpha_out);

  // --- chunkwise beta ---
  beta_kernel<<<dim3(2048), blk, 0, stream>>>(u_buf, alpha_out, beta_out);

  // --- cv = beta @ v, K-split x8 atomic ---
  gemm64<3,false,true,float,half_t,float><<<dim3(2,4,256), blk, 0, stream>>>(beta_out, kbuf, cv_out, 256,128,3000, 3000,512,512, 4,8,384,
      3072000,768000, 1536000,128, 131072,128, nullptr, nullptr);
}

// Round 9
// 1160.591 us; speedup vs baseline: 2.2344x; 1.0472x over previous
//
#include <hip/hip_runtime.h>
#include <hip/hip_bf16.h>
#include <math.h>

#define EPSV 1e-6f
#define INV_SCALE 0.04419417382415922f   // 1/sqrt(512)

typedef _Float16 half_t;
typedef __attribute__((ext_vector_type(8))) _Float16 half8;
typedef __attribute__((ext_vector_type(4))) _Float16 half4v;
typedef __attribute__((ext_vector_type(4))) float    f32x4;

__device__ __forceinline__ float ldf(const float* p)  { return *p; }
__device__ __forceinline__ float ldf(const half_t* p) { return (float)*p; }
__device__ __forceinline__ void  stf(float* p, float v)  { *p = v; }
__device__ __forceinline__ void  stf(half_t* p, float v) { *p = (half_t)v; }

// ---------------------------------------------------------------------------
// Weight transpose + f16 convert: WT[n][k] = (half)W[k][n], 512x512.
// ---------------------------------------------------------------------------
__global__ __launch_bounds__(256)
void wtrans(const float* __restrict__ W, half_t* __restrict__ WT)
{
  __shared__ float t[32][33];
  int bx = blockIdx.x, by = blockIdx.y;   // bx: k-tile, by: n-tile
  int tid = threadIdx.x;
  int r = tid >> 3, cq = tid & 7;
  float4 v = *(const float4*)&W[(size_t)(bx * 32 + r) * 512 + by * 32 + cq * 4];
  t[r][cq * 4 + 0] = v.x; t[r][cq * 4 + 1] = v.y;
  t[r][cq * 4 + 2] = v.z; t[r][cq * 4 + 3] = v.w;
  __syncthreads();
  half4v o;
  o[0] = (half_t)t[cq * 4 + 0][r];
  o[1] = (half_t)t[cq * 4 + 1][r];
  o[2] = (half_t)t[cq * 4 + 2][r];
  o[3] = (half_t)t[cq * 4 + 3][r];
  *(half4v*)&WT[(size_t)(by * 32 + r) * 512 + bx * 32 + cq * 4] = o;
}

// ---------------------------------------------------------------------------
// MFMA GEMM: C = A(fp32) * BT^T (BT f16 [N][ldb]).  v_mfma_f32_16x16x32_f16.
// Tile 128x128, BK=32, 4 waves (2x2 of 64x64), fragment-major LDS.
// Staging guarded at chunk granularity (Kd%4==0 / %8==0 in all uses) so
// K tails (cv: Kd=3000) are zero-filled, never OOB.
// MODE: 0=+bias[n]; 1=sigmoid(acc*INV_SCALE+rvec[hz]); 2=acc*INV_SCALE; 3=plain.
// CT: store C transposed (C[col*ldc+row], half4v over 4 consecutive rows) —
// used to produce vT for the cv GEMM.
// ---------------------------------------------------------------------------
template<int MODE, bool CT, typename TC>
__global__ __launch_bounds__(256)
void mgemm(const float* __restrict__ A, const half_t* __restrict__ BT,
           TC* __restrict__ C, int M, int N, int Kd,
           int lda, int ldb, int ldc, int hdiv,
           long long sAb, long long sAh, long long sBb, long long sBh,
           long long sCb, long long sCh,
           const float* __restrict__ bias, const float* __restrict__ rvec)
{
  int z = blockIdx.z;
  int bz = z / hdiv, hz = z - bz * hdiv;
  A  += (size_t)bz * sAb + (size_t)hz * sAh;
  BT += (size_t)bz * sBb + (size_t)hz * sBh;
  C  += (size_t)bz * sCb + (size_t)hz * sCh;

  __shared__ half_t As[4][128][8];   // [k/8][m][k%8]
  __shared__ half_t Bs[4][128][8];   // [k/8][n][k%8]
  int tid = threadIdx.x;
  int lane = tid & 63, wid = tid >> 6;
  int wm = wid >> 1, wn = wid & 1;
  int m0 = blockIdx.y * 128, n0 = blockIdx.x * 128;

  f32x4 acc[4][4] = {};

  for (int k0 = 0; k0 < Kd; k0 += 32) {
    #pragma unroll
    for (int i = 0; i < 4; i++) {            // A: 128x32 f32 -> f16
      int ch = tid + i * 256;
      int m = ch >> 3, cq = ch & 7, k = cq * 4;
      float4 v = make_float4(0.f, 0.f, 0.f, 0.f);
      if (m0 + m < M && k0 + k < Kd) v = *(const float4*)&A[(size_t)(m0 + m) * lda + k0 + k];
      half4v h;
      h[0] = (half_t)v.x; h[1] = (half_t)v.y; h[2] = (half_t)v.z; h[3] = (half_t)v.w;
      *(half4v*)&As[cq >> 1][m][(cq & 1) * 4] = h;
    }
    #pragma unroll
    for (int i = 0; i < 2; i++) {            // B: 128x32 f16
      int ch = tid + i * 256;
      int n = ch >> 2, kb = ch & 3;
      half8 v = {(_Float16)0,(_Float16)0,(_Float16)0,(_Float16)0,
                 (_Float16)0,(_Float16)0,(_Float16)0,(_Float16)0};
      if (n0 + n < N && k0 + kb * 8 < Kd)
        v = *(const half8*)&BT[(size_t)(n0 + n) * ldb + k0 + kb * 8];
      *(half8*)&Bs[kb][n][0] = v;
    }
    __syncthreads();
    int kb = lane >> 4, r = lane & 15;
    half8 af[4], bfv[4];
    #pragma unroll
    for (int mi = 0; mi < 4; mi++) af[mi]  = *(const half8*)&As[kb][wm * 64 + mi * 16 + r][0];
    #pragma unroll
    for (int ni = 0; ni < 4; ni++) bfv[ni] = *(const half8*)&Bs[kb][wn * 64 + ni * 16 + r][0];
    #pragma unroll
    for (int mi = 0; mi < 4; mi++)
      #pragma unroll
      for (int ni = 0; ni < 4; ni++)
        acc[mi][ni] = __builtin_amdgcn_mfma_f32_16x16x32_f16(af[mi], bfv[ni], acc[mi][ni], 0, 0, 0);
    __syncthreads();
  }

  float radd = (MODE == 1) ? rvec[hz] : 0.f;
  int r = lane & 15, g = lane >> 4;
  #pragma unroll
  for (int mi = 0; mi < 4; mi++) {
    #pragma unroll
    for (int ni = 0; ni < 4; ni++) {
      int col = n0 + wn * 64 + ni * 16 + r;
      if (col >= N) continue;
      float bv = (MODE == 0) ? bias[col] : 0.f;
      if (CT) {
        int row0 = m0 + wm * 64 + mi * 16 + g * 4;
        if (row0 + 3 < M) {
          half4v o;
          #pragma unroll
          for (int j = 0; j < 4; j++) o[j] = (half_t)(acc[mi][ni][j] + bv);
          *(half4v*)&((half_t*)C)[(size_t)col * ldc + row0] = o;
        }
      } else {
        #pragma unroll
        for (int j = 0; j < 4; j++) {
          int row = m0 + wm * 64 + mi * 16 + g * 4 + j;
          if (row >= M) continue;
          float v = acc[mi][ni][j];
          if (MODE == 0)      v += bv;
          else if (MODE == 1) v = 1.f / (1.f + expf(-(v * INV_SCALE + radd)));
          else if (MODE == 2) v *= INV_SCALE;
          stf(&C[(size_t)row * ldc + col], v);
        }
      }
    }
  }
}

// ---------------------------------------------------------------------------
// Fused cp + monotonic-alpha scan. 256 threads x 12 elems (3000 = 250x12).
// 4 waves -> cheap barrier, <=3 cross-wave adds; all global I/O float4.
// Pipeline: scan2 finishes alpha_i while scan1 builds cp_{i+1}; ONE barrier.
// Inactive tail threads (k0>=3000) carry zeros: log(1-0)=0, a_prev=0 — no
// per-element guards needed, only memory-op guards.
// ---------------------------------------------------------------------------
__global__ __launch_bounds__(256)
void scan_kernel(const float* __restrict__ p_slot, float* __restrict__ alpha_slot)
{
  __shared__ float wsA[2][4], wsB[2][4];
  int z = blockIdx.x;                 // b*4+h
  int tid = threadIdx.x;
  int lane = tid & 63, wid = tid >> 6;
  int k0 = tid * 12;
  bool act = (k0 < 3000);
  size_t zbase = (size_t)z * 768000;  // 256*3000

  float a_prev[12];
  #pragma unroll
  for (int c = 0; c < 12; c++) a_prev[c] = 0.f;
  if (tid == 0) a_prev[0] = 1.f;

  float pc[12], pv[12];
  if (act) {
    #pragma unroll
    for (int q = 0; q < 3; q++) {
      f32x4 v0 = *(const f32x4*)&p_slot[zbase + k0 + q * 4];
      f32x4 v1 = *(const f32x4*)&p_slot[zbase + 3000 + k0 + q * 4];
      #pragma unroll
      for (int j = 0; j < 4; j++) { pc[q * 4 + j] = v0[j]; pv[q * 4 + j] = v1[j]; }
    }
  } else {
    #pragma unroll
    for (int c = 0; c < 12; c++) { pc[c] = 0.f; pv[c] = 0.f; }
  }

  float cpv[12];
  { // prologue: cp for row 0
    float l[12], s = 0.f;
    #pragma unroll
    for (int c = 0; c < 12; c++) {
      l[c] = s;
      s += logf(fminf(fmaxf(1.f - pc[c], EPSV), 1.f));
    }
    float incl = s;
    #pragma unroll
    for (int d = 1; d < 64; d <<= 1) { float o = __shfl_up(incl, d); if (lane >= d) incl += o; }
    if (lane == 63) wsA[1][wid] = incl;
    float excl = incl - s;
    __syncthreads();
    float base = excl;
    for (int w = 0; w < wid; w++) base += wsA[1][w];
    #pragma unroll
    for (int c = 0; c < 12; c++) cpv[c] = expf(base + l[c]);
  }

  for (int i = 0; i < 256; i++) {
    int par = i & 1;
    // scan2: inclusive cumsum of a_prev / clip(cp_i)
    float t[12], s2 = 0.f;
    #pragma unroll
    for (int c = 0; c < 12; c++) {
      s2 += a_prev[c] / fmaxf(cpv[c], EPSV);
      t[c] = s2;
    }
    float incl2 = s2;
    #pragma unroll
    for (int d = 1; d < 64; d <<= 1) { float o = __shfl_up(incl2, d); if (lane >= d) incl2 += o; }
    if (lane == 63) wsB[par][wid] = incl2;
    float excl2 = incl2 - s2;

    // scan1: cp for row i+1 (recurrence-independent)
    float pn[12], l[12], s1 = 0.f;
    #pragma unroll
    for (int c = 0; c < 12; c++) {
      pn[c] = pv[c];
      l[c] = s1;
      s1 += logf(fminf(fmaxf(1.f - pn[c], EPSV), 1.f));
    }
    float incl1 = s1;
    #pragma unroll
    for (int d = 1; d < 64; d <<= 1) { float o = __shfl_up(incl1, d); if (lane >= d) incl1 += o; }
    if (lane == 63) wsA[par][wid] = incl1;
    float excl1 = incl1 - s1;

    __syncthreads();                               // the single barrier

    float off = excl2;
    for (int w = 0; w < wid; w++) off += wsB[par][w];
    size_t rbase = zbase + (size_t)i * 3000;
    float an[12];
    #pragma unroll
    for (int c = 0; c < 12; c++) {
      an[c] = pc[c] * cpv[c] * (off + t[c]);
      a_prev[c] = an[c];
    }
    if (act) {
      #pragma unroll
      for (int q = 0; q < 3; q++) {
        f32x4 o;
        #pragma unroll
        for (int j = 0; j < 4; j++) o[j] = an[q * 4 + j];
        *(f32x4*)&alpha_slot[rbase + k0 + q * 4] = o;
      }
    }
    float base1 = excl1;
    for (int w = 0; w < wid; w++) base1 += wsA[par][w];
    #pragma unroll
    for (int c = 0; c < 12; c++) { cpv[c] = expf(base1 + l[c]); pc[c] = pn[c]; }
    if (i < 254 && act) {                          // prefetch p row i+2
      size_t nb = zbase + (size_t)(i + 2) * 3000;
      #pragma unroll
      for (int q = 0; q < 3; q++) {
        f32x4 v1 = *(const f32x4*)&p_slot[nb + k0 + q * 4];
        #pragma unroll
        for (int j = 0; j < 4; j++) pv[q * 4 + j] = v1[j];
      }
    }
  }
}

// ---------------------------------------------------------------------------
// Chunkwise beta (unchanged).
// ---------------------------------------------------------------------------
__global__ __launch_bounds__(256)
void beta_kernel(const float* __restrict__ ubuf, const float* __restrict__ alpha_slot,
                 float* __restrict__ beta_slot)
{
  __shared__ float se[3008];
  __shared__ float dn[3008];
  __shared__ float tt[3024];
  __shared__ float red[4];
  int bq = blockIdx.x;
  int b = bq >> 8, q = bq & 255;
  int tid = threadIdx.x;
  int lane = tid & 63, wid = tid >> 6;
  const float* urow = ubuf + (size_t)bq * 3000;
  float lmax = -3.0e38f;
  for (int i = tid; i < 3000; i += 256) { float v = urow[i]; se[i] = v; lmax = fmaxf(lmax, v); }
  #pragma unroll
  for (int d = 32; d > 0; d >>= 1) lmax = fmaxf(lmax, __shfl_xor(lmax, d));
  if (lane == 0) red[wid] = lmax;
  __syncthreads();
  float umax = fmaxf(fmaxf(red[0], red[1]), fmaxf(red[2], red[3]));
  for (int i = tid; i < 3000; i += 256) se[i] = fmaxf(expf(se[i] - umax), 1e-5f);
  if (tid < 24) tt[3000 + tid] = 0.f;
  __syncthreads();
  for (int k = tid; k < 3000; k += 256) {
    int lo = k - 15; if (lo < 0) lo = 0;
    float s = 0.f;
    for (int j = lo; j <= k; j++) s += se[j];
    dn[k] = s;
  }
  __syncthreads();
  for (int h = 0; h < 4; h++) {
    const float* arow = alpha_slot + ((size_t)((b * 4 + h) * 256 + q)) * 3000;
    for (int i = tid; i < 3000; i += 256) tt[i] = arow[i] / dn[i];
    __syncthreads();
    float* brow = beta_slot + ((size_t)((b * 4 + h) * 256 + q)) * 3000;
    for (int k = tid; k < 3000; k += 256) {
      float s = 0.f;
      #pragma unroll
      for (int j = 0; j < 16; j++) s += tt[k + j];
      brow[k] = se[k] * s;
    }
    __syncthreads();
  }
}

// ---------------------------------------------------------------------------
extern "C" void kernel_launch(void* const* d_in, const int* in_sizes, int n_in,
                              void* d_out, int out_size, void* d_ws, size_t ws_size,
                              hipStream_t stream)
{
  const float* key        = (const float*)d_in[0];
  const float* query      = (const float*)d_in[1];
  const float* w_key_ma   = (const float*)d_in[2];
  const float* b_key_ma   = (const float*)d_in[3];
  const float* w_query_ma = (const float*)d_in[4];
  const float* b_query_ma = (const float*)d_in[5];
  const float* rvec       = (const float*)d_in[6];
  const float* w_key_ca   = (const float*)d_in[7];
  const float* b_key_ca   = (const float*)d_in[8];
  const float* w_query_ca = (const float*)d_in[9];
  const float* b_query_ca = (const float*)d_in[10];
  const float* w_value    = (const float*)d_in[11];
  const float* b_value    = (const float*)d_in[12];

  // Outputs FP32: cv | alpha | beta, flat.
  float* out       = (float*)d_out;
  float* cv_out    = out;                                  // (8,256,512)
  float* alpha_out = out + (size_t)1048576;                // (8,4,256,3000)
  float* beta_out  = alpha_out + (size_t)24576000;         // (8,4,256,3000)

  // workspace: kbuf f16 (k_ma -> k_ca -> vT) | qbuf f32 (q_ma -> q_ca) |
  // u f32 | 5x W^T f16.  Total 55,967,744 B (~53.4 MiB).
  half_t* kbuf   = (half_t*)d_ws;                              // 24000x512 (or vT 512x24000)
  float*  qbuf   = (float*)((char*)d_ws + 24576000);           // 2048x512
  float*  u_buf  = (float*)((char*)d_ws + 28770304);           // 8x256x3000
  half_t* wt_qma = (half_t*)((char*)d_ws + 53346304);
  half_t* wt_kma = (half_t*)((char*)d_ws + 53870592);
  half_t* wt_qca = (half_t*)((char*)d_ws + 54394880);
  half_t* wt_kca = (half_t*)((char*)d_ws + 54919168);
  half_t* wt_v   = (half_t*)((char*)d_ws + 55443456);
  if (ws_size < (size_t)55967744) return;

  dim3 blk(256);
  dim3 tgrid(16, 16);

  // weight transposes (f32 -> f16 [N][K])
  wtrans<<<tgrid, blk, 0, stream>>>(w_query_ma, wt_qma);
  wtrans<<<tgrid, blk, 0, stream>>>(w_key_ma,   wt_kma);
  wtrans<<<tgrid, blk, 0, stream>>>(w_query_ca, wt_qca);
  wtrans<<<tgrid, blk, 0, stream>>>(w_key_ca,   wt_kca);
  wtrans<<<tgrid, blk, 0, stream>>>(w_value,    wt_v);

  // --- MA path ---
  mgemm<0,false,float ><<<dim3(4,16,1),  blk, 0, stream>>>(query, wt_qma, qbuf, 2048, 512, 512, 512,512,512, 1, 0,0,0,0,0,0, b_query_ma, nullptr);
  mgemm<0,false,half_t><<<dim3(4,188,1), blk, 0, stream>>>(key,   wt_kma, kbuf, 24000,512, 512, 512,512,512, 1, 0,0,0,0,0,0, b_key_ma,   nullptr);
  mgemm<1,false,float ><<<dim3(24,2,32), blk, 0, stream>>>(qbuf,  kbuf, beta_out, 256,3000, 128, 512,512,3000, 4,
      131072,128, 1536000,128, 3072000,768000, nullptr, rvec);

  // --- CA path ---
  mgemm<0,false,float ><<<dim3(4,16,1),  blk, 0, stream>>>(query, wt_qca, qbuf, 2048, 512, 512, 512,512,512, 1, 0,0,0,0,0,0, b_query_ca, nullptr);
  mgemm<0,false,half_t><<<dim3(4,188,1), blk, 0, stream>>>(key,   wt_kca, kbuf, 24000,512, 512, 512,512,512, 1, 0,0,0,0,0,0, b_key_ca,   nullptr);
  mgemm<2,false,float ><<<dim3(24,2,8),  blk, 0, stream>>>(qbuf,  kbuf, u_buf, 256,3000, 512, 512,512,3000, 1,
      131072,0, 1536000,0, 768000,0, nullptr, nullptr);

  // --- v projection, stored TRANSPOSED: vT[512][24000] f16 (reuses kbuf) ---
  mgemm<0,true,half_t><<<dim3(4,188,1), blk, 0, stream>>>(key, wt_v, kbuf, 24000,512, 512, 512,512,24000, 1, 0,0,0,0,0,0, b_value, nullptr);

  // --- fused cp + alpha scan (256 thr x 12, single barrier/step) ---
  scan_kernel<<<dim3(32), blk, 0, stream>>>(beta_out, alpha_out);

  // --- chunkwise beta ---
  beta_kernel<<<dim3(2048), blk, 0, stream>>>(u_buf, alpha_out, beta_out);

  // --- cv = beta @ v via MFMA (A=beta fp32, BT=vT f16, plain store) ---
  mgemm<3,false,float><<<dim3(1,2,32), blk, 0, stream>>>(beta_out, kbuf, cv_out, 256,128,3000, 3000,24000,512, 4,
      3072000,768000, 3000,3072000, 131072,128, nullptr, nullptr);
}

// Round 10
// 1003.663 us; speedup vs baseline: 2.5838x; 1.1564x over previous
//
#include <hip/hip_runtime.h>
#include <hip/hip_bf16.h>
#include <math.h>

#define EPSV 1e-6f
#define INV_SCALE 0.04419417382415922f   // 1/sqrt(512)

typedef _Float16 half_t;
typedef __attribute__((ext_vector_type(8))) _Float16 half8;
typedef __attribute__((ext_vector_type(4))) _Float16 half4v;
typedef __attribute__((ext_vector_type(4))) float    f32x4;

__device__ __forceinline__ float ldf(const float* p)  { return *p; }
__device__ __forceinline__ float ldf(const half_t* p) { return (float)*p; }
__device__ __forceinline__ void  stf(float* p, float v)  { *p = v; }
__device__ __forceinline__ void  stf(half_t* p, float v) { *p = (half_t)v; }
__device__ __forceinline__ float frcp(float x) { return __builtin_amdgcn_rcpf(x); }

// ---------------------------------------------------------------------------
// Weight transpose + f16 convert: WT[n][k] = (half)W[k][n], 512x512.
// ---------------------------------------------------------------------------
__global__ __launch_bounds__(256)
void wtrans(const float* __restrict__ W, half_t* __restrict__ WT)
{
  __shared__ float t[32][33];
  int bx = blockIdx.x, by = blockIdx.y;   // bx: k-tile, by: n-tile
  int tid = threadIdx.x;
  int r = tid >> 3, cq = tid & 7;
  float4 v = *(const float4*)&W[(size_t)(bx * 32 + r) * 512 + by * 32 + cq * 4];
  t[r][cq * 4 + 0] = v.x; t[r][cq * 4 + 1] = v.y;
  t[r][cq * 4 + 2] = v.z; t[r][cq * 4 + 3] = v.w;
  __syncthreads();
  half4v o;
  o[0] = (half_t)t[cq * 4 + 0][r];
  o[1] = (half_t)t[cq * 4 + 1][r];
  o[2] = (half_t)t[cq * 4 + 2][r];
  o[3] = (half_t)t[cq * 4 + 3][r];
  *(half4v*)&WT[(size_t)(by * 32 + r) * 512 + bx * 32 + cq * 4] = o;
}

// ---------------------------------------------------------------------------
// MFMA GEMM: C = A(fp32) * BT^T (BT f16 [N][ldb]).  v_mfma_f32_16x16x32_f16.
// Tile 128x128, BK=32, 4 waves (2x2 of 64x64), fragment-major LDS.
// MODE: 0=+bias[n]; 1=sigmoid(acc*INV_SCALE+rvec[hz]); 2=acc*INV_SCALE; 3=plain.
// CT: store C transposed (vT for the cv GEMM).
// ---------------------------------------------------------------------------
template<int MODE, bool CT, typename TC>
__global__ __launch_bounds__(256)
void mgemm(const float* __restrict__ A, const half_t* __restrict__ BT,
           TC* __restrict__ C, int M, int N, int Kd,
           int lda, int ldb, int ldc, int hdiv,
           long long sAb, long long sAh, long long sBb, long long sBh,
           long long sCb, long long sCh,
           const float* __restrict__ bias, const float* __restrict__ rvec)
{
  int z = blockIdx.z;
  int bz = z / hdiv, hz = z - bz * hdiv;
  A  += (size_t)bz * sAb + (size_t)hz * sAh;
  BT += (size_t)bz * sBb + (size_t)hz * sBh;
  C  += (size_t)bz * sCb + (size_t)hz * sCh;

  __shared__ half_t As[4][128][8];   // [k/8][m][k%8]
  __shared__ half_t Bs[4][128][8];   // [k/8][n][k%8]
  int tid = threadIdx.x;
  int lane = tid & 63, wid = tid >> 6;
  int wm = wid >> 1, wn = wid & 1;
  int m0 = blockIdx.y * 128, n0 = blockIdx.x * 128;

  f32x4 acc[4][4] = {};

  for (int k0 = 0; k0 < Kd; k0 += 32) {
    #pragma unroll
    for (int i = 0; i < 4; i++) {            // A: 128x32 f32 -> f16
      int ch = tid + i * 256;
      int m = ch >> 3, cq = ch & 7, k = cq * 4;
      float4 v = make_float4(0.f, 0.f, 0.f, 0.f);
      if (m0 + m < M && k0 + k < Kd) v = *(const float4*)&A[(size_t)(m0 + m) * lda + k0 + k];
      half4v h;
      h[0] = (half_t)v.x; h[1] = (half_t)v.y; h[2] = (half_t)v.z; h[3] = (half_t)v.w;
      *(half4v*)&As[cq >> 1][m][(cq & 1) * 4] = h;
    }
    #pragma unroll
    for (int i = 0; i < 2; i++) {            // B: 128x32 f16
      int ch = tid + i * 256;
      int n = ch >> 2, kb = ch & 3;
      half8 v = {(_Float16)0,(_Float16)0,(_Float16)0,(_Float16)0,
                 (_Float16)0,(_Float16)0,(_Float16)0,(_Float16)0};
      if (n0 + n < N && k0 + kb * 8 < Kd)
        v = *(const half8*)&BT[(size_t)(n0 + n) * ldb + k0 + kb * 8];
      *(half8*)&Bs[kb][n][0] = v;
    }
    __syncthreads();
    int kb = lane >> 4, r = lane & 15;
    half8 af[4], bfv[4];
    #pragma unroll
    for (int mi = 0; mi < 4; mi++) af[mi]  = *(const half8*)&As[kb][wm * 64 + mi * 16 + r][0];
    #pragma unroll
    for (int ni = 0; ni < 4; ni++) bfv[ni] = *(const half8*)&Bs[kb][wn * 64 + ni * 16 + r][0];
    #pragma unroll
    for (int mi = 0; mi < 4; mi++)
      #pragma unroll
      for (int ni = 0; ni < 4; ni++)
        acc[mi][ni] = __builtin_amdgcn_mfma_f32_16x16x32_f16(af[mi], bfv[ni], acc[mi][ni], 0, 0, 0);
    __syncthreads();
  }

  float radd = (MODE == 1) ? rvec[hz] : 0.f;
  int r = lane & 15, g = lane >> 4;
  #pragma unroll
  for (int mi = 0; mi < 4; mi++) {
    #pragma unroll
    for (int ni = 0; ni < 4; ni++) {
      int col = n0 + wn * 64 + ni * 16 + r;
      if (col >= N) continue;
      float bv = (MODE == 0) ? bias[col] : 0.f;
      if (CT) {
        int row0 = m0 + wm * 64 + mi * 16 + g * 4;
        if (row0 + 3 < M) {
          half4v o;
          #pragma unroll
          for (int j = 0; j < 4; j++) o[j] = (half_t)(acc[mi][ni][j] + bv);
          *(half4v*)&((half_t*)C)[(size_t)col * ldc + row0] = o;
        }
      } else {
        #pragma unroll
        for (int j = 0; j < 4; j++) {
          int row = m0 + wm * 64 + mi * 16 + g * 4 + j;
          if (row >= M) continue;
          float v = acc[mi][ni][j];
          if (MODE == 0)      v += bv;
          else if (MODE == 1) v = frcp(1.f + expf(-(v * INV_SCALE + radd)));
          else if (MODE == 2) v *= INV_SCALE;
          stf(&C[(size_t)row * ldc + col], v);
        }
      }
    }
  }
}

// ---------------------------------------------------------------------------
// Fused cp + monotonic-alpha scan. 256 threads x 12 elems; 1 barrier/step.
// cp via DIRECT multiplicative prefix scan (== exp(cumsum(log(clip))), no
// transcendentals); divides via v_rcp_f32 (2^-22 rel err, ample headroom).
// Underflow: products that flush to 0 match reference expf(-large)->0; the
// exclusive-prefix recovery incl*rcp(max(m,1e-30)) can't produce NaN.
// ---------------------------------------------------------------------------
__global__ __launch_bounds__(256)
void scan_kernel(const float* __restrict__ p_slot, float* __restrict__ alpha_slot)
{
  __shared__ float wsA[2][4], wsB[2][4];
  int z = blockIdx.x;                 // b*4+h
  int tid = threadIdx.x;
  int lane = tid & 63, wid = tid >> 6;
  int k0 = tid * 12;
  bool act = (k0 < 3000);
  size_t zbase = (size_t)z * 768000;  // 256*3000

  float a_prev[12];
  #pragma unroll
  for (int c = 0; c < 12; c++) a_prev[c] = 0.f;
  if (tid == 0) a_prev[0] = 1.f;

  float pc[12], pv[12];
  if (act) {
    #pragma unroll
    for (int q = 0; q < 3; q++) {
      f32x4 v0 = *(const f32x4*)&p_slot[zbase + k0 + q * 4];
      f32x4 v1 = *(const f32x4*)&p_slot[zbase + 3000 + k0 + q * 4];
      #pragma unroll
      for (int j = 0; j < 4; j++) { pc[q * 4 + j] = v0[j]; pv[q * 4 + j] = v1[j]; }
    }
  } else {
    #pragma unroll
    for (int c = 0; c < 12; c++) { pc[c] = 0.f; pv[c] = 0.f; }
  }

  float cpv[12];
  { // prologue: cp row 0 (multiplicative scan)
    float l[12], m = 1.f;
    #pragma unroll
    for (int c = 0; c < 12; c++) {
      l[c] = m;
      m *= fminf(fmaxf(1.f - pc[c], EPSV), 1.f);
    }
    float incl = m;
    #pragma unroll
    for (int d = 1; d < 64; d <<= 1) { float o = __shfl_up(incl, d); if (lane >= d) incl *= o; }
    if (lane == 63) wsA[1][wid] = incl;
    float excl = incl * frcp(fmaxf(m, 1e-30f));
    __syncthreads();
    float base = excl;
    for (int w = 0; w < wid; w++) base *= wsA[1][w];
    #pragma unroll
    for (int c = 0; c < 12; c++) cpv[c] = base * l[c];
  }

  for (int i = 0; i < 256; i++) {
    int par = i & 1;
    // scan2: inclusive cumsum of a_prev * rcp(clip(cp_i))
    float inv[12];
    #pragma unroll
    for (int c = 0; c < 12; c++) inv[c] = frcp(fmaxf(cpv[c], EPSV));
    float t[12], s2 = 0.f;
    #pragma unroll
    for (int c = 0; c < 12; c++) {
      s2 = fmaf(a_prev[c], inv[c], s2);
      t[c] = s2;
    }
    float incl2 = s2;
    #pragma unroll
    for (int d = 1; d < 64; d <<= 1) { float o = __shfl_up(incl2, d); if (lane >= d) incl2 += o; }
    if (lane == 63) wsB[par][wid] = incl2;
    float excl2 = incl2 - s2;

    // scan1: cp for row i+1 (multiplicative, recurrence-independent)
    float pn[12], l[12], m = 1.f;
    #pragma unroll
    for (int c = 0; c < 12; c++) {
      pn[c] = pv[c];
      l[c] = m;
      m *= fminf(fmaxf(1.f - pn[c], EPSV), 1.f);
    }
    float incl1 = m;
    #pragma unroll
    for (int d = 1; d < 64; d <<= 1) { float o = __shfl_up(incl1, d); if (lane >= d) incl1 *= o; }
    if (lane == 63) wsA[par][wid] = incl1;
    float excl1 = incl1 * frcp(fmaxf(m, 1e-30f));

    __syncthreads();                               // the single barrier

    float off = excl2;
    for (int w = 0; w < wid; w++) off += wsB[par][w];
    size_t rbase = zbase + (size_t)i * 3000;
    float an[12];
    #pragma unroll
    for (int c = 0; c < 12; c++) {
      an[c] = pc[c] * cpv[c] * (off + t[c]);
      a_prev[c] = an[c];
    }
    if (act) {
      #pragma unroll
      for (int q = 0; q < 3; q++) {
        f32x4 o;
        #pragma unroll
        for (int j = 0; j < 4; j++) o[j] = an[q * 4 + j];
        *(f32x4*)&alpha_slot[rbase + k0 + q * 4] = o;
      }
    }
    float base1 = excl1;
    for (int w = 0; w < wid; w++) base1 *= wsA[par][w];
    #pragma unroll
    for (int c = 0; c < 12; c++) { cpv[c] = base1 * l[c]; pc[c] = pn[c]; }
    if (i < 254 && act) {                          // prefetch p row i+2
      size_t nb = zbase + (size_t)(i + 2) * 3000;
      #pragma unroll
      for (int q = 0; q < 3; q++) {
        f32x4 v1 = *(const f32x4*)&p_slot[nb + k0 + q * 4];
        #pragma unroll
        for (int j = 0; j < 4; j++) pv[q * 4 + j] = v1[j];
      }
    }
  }
}

// ---------------------------------------------------------------------------
// Chunkwise beta (divide -> v_rcp).
// ---------------------------------------------------------------------------
__global__ __launch_bounds__(256)
void beta_kernel(const float* __restrict__ ubuf, const float* __restrict__ alpha_slot,
                 float* __restrict__ beta_slot)
{
  __shared__ float se[3008];
  __shared__ float dn[3008];
  __shared__ float tt[3024];
  __shared__ float red[4];
  int bq = blockIdx.x;
  int b = bq >> 8, q = bq & 255;
  int tid = threadIdx.x;
  int lane = tid & 63, wid = tid >> 6;
  const float* urow = ubuf + (size_t)bq * 3000;
  float lmax = -3.0e38f;
  for (int i = tid; i < 3000; i += 256) { float v = urow[i]; se[i] = v; lmax = fmaxf(lmax, v); }
  #pragma unroll
  for (int d = 32; d > 0; d >>= 1) lmax = fmaxf(lmax, __shfl_xor(lmax, d));
  if (lane == 0) red[wid] = lmax;
  __syncthreads();
  float umax = fmaxf(fmaxf(red[0], red[1]), fmaxf(red[2], red[3]));
  for (int i = tid; i < 3000; i += 256) se[i] = fmaxf(expf(se[i] - umax), 1e-5f);
  if (tid < 24) tt[3000 + tid] = 0.f;
  __syncthreads();
  for (int k = tid; k < 3000; k += 256) {
    int lo = k - 15; if (lo < 0) lo = 0;
    float s = 0.f;
    for (int j = lo; j <= k; j++) s += se[j];
    dn[k] = s;
  }
  __syncthreads();
  for (int h = 0; h < 4; h++) {
    const float* arow = alpha_slot + ((size_t)((b * 4 + h) * 256 + q)) * 3000;
    for (int i = tid; i < 3000; i += 256) tt[i] = arow[i] * frcp(dn[i]);
    __syncthreads();
    float* brow = beta_slot + ((size_t)((b * 4 + h) * 256 + q)) * 3000;
    for (int k = tid; k < 3000; k += 256) {
      float s = 0.f;
      #pragma unroll
      for (int j = 0; j < 16; j++) s += tt[k + j];
      brow[k] = se[k] * s;
    }
    __syncthreads();
  }
}

// ---------------------------------------------------------------------------
extern "C" void kernel_launch(void* const* d_in, const int* in_sizes, int n_in,
                              void* d_out, int out_size, void* d_ws, size_t ws_size,
                              hipStream_t stream)
{
  const float* key        = (const float*)d_in[0];
  const float* query      = (const float*)d_in[1];
  const float* w_key_ma   = (const float*)d_in[2];
  const float* b_key_ma   = (const float*)d_in[3];
  const float* w_query_ma = (const float*)d_in[4];
  const float* b_query_ma = (const float*)d_in[5];
  const float* rvec       = (const float*)d_in[6];
  const float* w_key_ca   = (const float*)d_in[7];
  const float* b_key_ca   = (const float*)d_in[8];
  const float* w_query_ca = (const float*)d_in[9];
  const float* b_query_ca = (const float*)d_in[10];
  const float* w_value    = (const float*)d_in[11];
  const float* b_value    = (const float*)d_in[12];

  // Outputs FP32: cv | alpha | beta, flat.
  float* out       = (float*)d_out;
  float* cv_out    = out;                                  // (8,256,512)
  float* alpha_out = out + (size_t)1048576;                // (8,4,256,3000)
  float* beta_out  = alpha_out + (size_t)24576000;         // (8,4,256,3000)

  // workspace: kbuf f16 (k_ma -> k_ca -> vT) | qbuf f32 (q_ma -> q_ca) |
  // u f32 | 5x W^T f16.  Total 55,967,744 B (~53.4 MiB).
  half_t* kbuf   = (half_t*)d_ws;                              // 24000x512 (or vT 512x24000)
  float*  qbuf   = (float*)((char*)d_ws + 24576000);           // 2048x512
  float*  u_buf  = (float*)((char*)d_ws + 28770304);           // 8x256x3000
  half_t* wt_qma = (half_t*)((char*)d_ws + 53346304);
  half_t* wt_kma = (half_t*)((char*)d_ws + 53870592);
  half_t* wt_qca = (half_t*)((char*)d_ws + 54394880);
  half_t* wt_kca = (half_t*)((char*)d_ws + 54919168);
  half_t* wt_v   = (half_t*)((char*)d_ws + 55443456);
  if (ws_size < (size_t)55967744) return;

  dim3 blk(256);
  dim3 tgrid(16, 16);

  // weight transposes (f32 -> f16 [N][K])
  wtrans<<<tgrid, blk, 0, stream>>>(w_query_ma, wt_qma);
  wtrans<<<tgrid, blk, 0, stream>>>(w_key_ma,   wt_kma);
  wtrans<<<tgrid, blk, 0, stream>>>(w_query_ca, wt_qca);
  wtrans<<<tgrid, blk, 0, stream>>>(w_key_ca,   wt_kca);
  wtrans<<<tgrid, blk, 0, stream>>>(w_value,    wt_v);

  // --- MA path ---
  mgemm<0,false,float ><<<dim3(4,16,1),  blk, 0, stream>>>(query, wt_qma, qbuf, 2048, 512, 512, 512,512,512, 1, 0,0,0,0,0,0, b_query_ma, nullptr);
  mgemm<0,false,half_t><<<dim3(4,188,1), blk, 0, stream>>>(key,   wt_kma, kbuf, 24000,512, 512, 512,512,512, 1, 0,0,0,0,0,0, b_key_ma,   nullptr);
  mgemm<1,false,float ><<<dim3(24,2,32), blk, 0, stream>>>(qbuf,  kbuf, beta_out, 256,3000, 128, 512,512,3000, 4,
      131072,128, 1536000,128, 3072000,768000, nullptr, rvec);

  // --- CA path ---
  mgemm<0,false,float ><<<dim3(4,16,1),  blk, 0, stream>>>(query, wt_qca, qbuf, 2048, 512, 512, 512,512,512, 1, 0,0,0,0,0,0, b_query_ca, nullptr);
  mgemm<0,false,half_t><<<dim3(4,188,1), blk, 0, stream>>>(key,   wt_kca, kbuf, 24000,512, 512, 512,512,512, 1, 0,0,0,0,0,0, b_key_ca,   nullptr);
  mgemm<2,false,float ><<<dim3(24,2,8),  blk, 0, stream>>>(qbuf,  kbuf, u_buf, 256,3000, 512, 512,512,3000, 1,
      131072,0, 1536000,0, 768000,0, nullptr, nullptr);

  // --- v projection, stored TRANSPOSED: vT[512][24000] f16 (reuses kbuf) ---
  mgemm<0,true,half_t><<<dim3(4,188,1), blk, 0, stream>>>(key, wt_v, kbuf, 24000,512, 512, 512,512,24000, 1, 0,0,0,0,0,0, b_value, nullptr);

  // --- fused cp + alpha scan ---
  scan_kernel<<<dim3(32), blk, 0, stream>>>(beta_out, alpha_out);

  // --- chunkwise beta ---
  beta_kernel<<<dim3(2048), blk, 0, stream>>>(u_buf, alpha_out, beta_out);

  // --- cv = beta @ v via MFMA (A=beta fp32, BT=vT f16, plain store) ---
  mgemm<3,false,float><<<dim3(1,2,32), blk, 0, stream>>>(beta_out, kbuf, cv_out, 256,128,3000, 3000,24000,512, 4,
      3072000,768000, 3000,3072000, 131072,128, nullptr, nullptr);
}

// Round 11
// 932.966 us; speedup vs baseline: 2.7796x; 1.0758x over previous
//
#include <hip/hip_runtime.h>
#include <hip/hip_bf16.h>
#include <math.h>

#define EPSV 1e-6f
#define INV_SCALE 0.04419417382415922f   // 1/sqrt(512)

typedef _Float16 half_t;
typedef __attribute__((ext_vector_type(8))) _Float16 half8;
typedef __attribute__((ext_vector_type(4))) _Float16 half4v;
typedef __attribute__((ext_vector_type(4))) float    f32x4;

__device__ __forceinline__ float ldf(const float* p)  { return *p; }
__device__ __forceinline__ float ldf(const half_t* p) { return (float)*p; }
__device__ __forceinline__ void  stf(float* p, float v)  { *p = v; }
__device__ __forceinline__ void  stf(half_t* p, float v) { *p = (half_t)v; }
__device__ __forceinline__ float frcp(float x) { return __builtin_amdgcn_rcpf(x); }

// ---------------------------------------------------------------------------
// DPP wave-64 inclusive scans (VALU, no LDS): row_shr 1/2/4/8 within 16-lane
// rows, then row_bcast15 (rows 1,3) and row_bcast31 (rows 2,3).
// add: invalid/masked lanes contribute 0 (old=0, bound_ctrl=1).
// mul: invalid/masked lanes contribute 1.0 (old=0x3f800000, bound_ctrl=0).
// ---------------------------------------------------------------------------
template<int CTRL, int RMASK>
__device__ __forceinline__ float dpp_add_step(float x) {
  int t = __builtin_amdgcn_update_dpp(0, __float_as_int(x), CTRL, RMASK, 0xf, true);
  return x + __int_as_float(t);
}
template<int CTRL, int RMASK>
__device__ __forceinline__ float dpp_mul_step(float x) {
  int t = __builtin_amdgcn_update_dpp(0x3f800000, __float_as_int(x), CTRL, RMASK, 0xf, false);
  return x * __int_as_float(t);
}
__device__ __forceinline__ float wave_iscan_add(float x) {
  x = dpp_add_step<0x111,0xf>(x);   // row_shr:1
  x = dpp_add_step<0x112,0xf>(x);   // row_shr:2
  x = dpp_add_step<0x114,0xf>(x);   // row_shr:4
  x = dpp_add_step<0x118,0xf>(x);   // row_shr:8
  x = dpp_add_step<0x142,0xa>(x);   // row_bcast:15 -> rows 1,3
  x = dpp_add_step<0x143,0xc>(x);   // row_bcast:31 -> rows 2,3
  return x;
}
__device__ __forceinline__ float wave_iscan_mul(float x) {
  x = dpp_mul_step<0x111,0xf>(x);
  x = dpp_mul_step<0x112,0xf>(x);
  x = dpp_mul_step<0x114,0xf>(x);
  x = dpp_mul_step<0x118,0xf>(x);
  x = dpp_mul_step<0x142,0xa>(x);
  x = dpp_mul_step<0x143,0xc>(x);
  return x;
}

// LDS-only barrier: waits ds ops, skips the vmcnt(0) drain __syncthreads emits.
// Safe here: the only cross-thread data is the tiny LDS ws arrays; global
// loads/stores in flight are strictly thread-private.
__device__ __forceinline__ void block_sync_lds() {
  asm volatile("s_waitcnt lgkmcnt(0)" ::: "memory");
  __builtin_amdgcn_s_barrier();
  asm volatile("" ::: "memory");
}

// ---------------------------------------------------------------------------
// Weight transpose + f16 convert: WT[n][k] = (half)W[k][n], 512x512.
// ---------------------------------------------------------------------------
__global__ __launch_bounds__(256)
void wtrans(const float* __restrict__ W, half_t* __restrict__ WT)
{
  __shared__ float t[32][33];
  int bx = blockIdx.x, by = blockIdx.y;
  int tid = threadIdx.x;
  int r = tid >> 3, cq = tid & 7;
  float4 v = *(const float4*)&W[(size_t)(bx * 32 + r) * 512 + by * 32 + cq * 4];
  t[r][cq * 4 + 0] = v.x; t[r][cq * 4 + 1] = v.y;
  t[r][cq * 4 + 2] = v.z; t[r][cq * 4 + 3] = v.w;
  __syncthreads();
  half4v o;
  o[0] = (half_t)t[cq * 4 + 0][r];
  o[1] = (half_t)t[cq * 4 + 1][r];
  o[2] = (half_t)t[cq * 4 + 2][r];
  o[3] = (half_t)t[cq * 4 + 3][r];
  *(half4v*)&WT[(size_t)(by * 32 + r) * 512 + bx * 32 + cq * 4] = o;
}

// ---------------------------------------------------------------------------
// MFMA GEMM body (shared LDS passed in so it can live inside a fused kernel).
// C = A(fp32) * BT^T, tile 128x128, BK=32, 4 waves, fragment-major LDS.
// ---------------------------------------------------------------------------
struct GemmLds { half_t As[4][128][8]; half_t Bs[4][128][8]; };
struct ScanLds { float wsA[2][4]; float wsB[2][4]; };
union  MidLds  { GemmLds g; ScanLds s; };

template<int MODE, bool CT, typename TC>
__device__ __forceinline__
void mgemm_body(GemmLds& L, int bxx, int byy, int bzz,
                const float* __restrict__ A, const half_t* __restrict__ BT,
                TC* __restrict__ C, int M, int N, int Kd,
                int lda, int ldb, int ldc, int hdiv,
                long long sAb, long long sAh, long long sBb, long long sBh,
                long long sCb, long long sCh,
                const float* __restrict__ bias, const float* __restrict__ rvec)
{
  int bz = bzz / hdiv, hz = bzz - bz * hdiv;
  A  += (size_t)bz * sAb + (size_t)hz * sAh;
  BT += (size_t)bz * sBb + (size_t)hz * sBh;
  C  += (size_t)bz * sCb + (size_t)hz * sCh;

  int tid = threadIdx.x;
  int lane = tid & 63, wid = tid >> 6;
  int wm = wid >> 1, wn = wid & 1;
  int m0 = byy * 128, n0 = bxx * 128;

  f32x4 acc[4][4] = {};

  for (int k0 = 0; k0 < Kd; k0 += 32) {
    #pragma unroll
    for (int i = 0; i < 4; i++) {            // A: 128x32 f32 -> f16
      int ch = tid + i * 256;
      int m = ch >> 3, cq = ch & 7, k = cq * 4;
      float4 v = make_float4(0.f, 0.f, 0.f, 0.f);
      if (m0 + m < M && k0 + k < Kd) v = *(const float4*)&A[(size_t)(m0 + m) * lda + k0 + k];
      half4v h;
      h[0] = (half_t)v.x; h[1] = (half_t)v.y; h[2] = (half_t)v.z; h[3] = (half_t)v.w;
      *(half4v*)&L.As[cq >> 1][m][(cq & 1) * 4] = h;
    }
    #pragma unroll
    for (int i = 0; i < 2; i++) {            // B: 128x32 f16
      int ch = tid + i * 256;
      int n = ch >> 2, kb = ch & 3;
      half8 v = {(_Float16)0,(_Float16)0,(_Float16)0,(_Float16)0,
                 (_Float16)0,(_Float16)0,(_Float16)0,(_Float16)0};
      if (n0 + n < N && k0 + kb * 8 < Kd)
        v = *(const half8*)&BT[(size_t)(n0 + n) * ldb + k0 + kb * 8];
      *(half8*)&L.Bs[kb][n][0] = v;
    }
    __syncthreads();
    int kb = lane >> 4, r = lane & 15;
    half8 af[4], bfv[4];
    #pragma unroll
    for (int mi = 0; mi < 4; mi++) af[mi]  = *(const half8*)&L.As[kb][wm * 64 + mi * 16 + r][0];
    #pragma unroll
    for (int ni = 0; ni < 4; ni++) bfv[ni] = *(const half8*)&L.Bs[kb][wn * 64 + ni * 16 + r][0];
    #pragma unroll
    for (int mi = 0; mi < 4; mi++)
      #pragma unroll
      for (int ni = 0; ni < 4; ni++)
        acc[mi][ni] = __builtin_amdgcn_mfma_f32_16x16x32_f16(af[mi], bfv[ni], acc[mi][ni], 0, 0, 0);
    __syncthreads();
  }

  float radd = (MODE == 1) ? rvec[hz] : 0.f;
  int r = lane & 15, g = lane >> 4;
  #pragma unroll
  for (int mi = 0; mi < 4; mi++) {
    #pragma unroll
    for (int ni = 0; ni < 4; ni++) {
      int col = n0 + wn * 64 + ni * 16 + r;
      if (col >= N) continue;
      float bv = (MODE == 0) ? bias[col] : 0.f;
      if (CT) {
        int row0 = m0 + wm * 64 + mi * 16 + g * 4;
        if (row0 + 3 < M) {
          half4v o;
          #pragma unroll
          for (int j = 0; j < 4; j++) o[j] = (half_t)(acc[mi][ni][j] + bv);
          *(half4v*)&((half_t*)C)[(size_t)col * ldc + row0] = o;
        }
      } else {
        #pragma unroll
        for (int j = 0; j < 4; j++) {
          int row = m0 + wm * 64 + mi * 16 + g * 4 + j;
          if (row >= M) continue;
          float v = acc[mi][ni][j];
          if (MODE == 0)      v += bv;
          else if (MODE == 1) v = frcp(1.f + expf(-(v * INV_SCALE + radd)));
          else if (MODE == 2) v *= INV_SCALE;
          stf(&C[(size_t)row * ldc + col], v);
        }
      }
    }
  }
}

template<int MODE, bool CT, typename TC>
__global__ __launch_bounds__(256)
void mgemm(const float* __restrict__ A, const half_t* __restrict__ BT,
           TC* __restrict__ C, int M, int N, int Kd,
           int lda, int ldb, int ldc, int hdiv,
           long long sAb, long long sAh, long long sBb, long long sBh,
           long long sCb, long long sCh,
           const float* __restrict__ bias, const float* __restrict__ rvec)
{
  __shared__ GemmLds L;
  mgemm_body<MODE,CT,TC>(L, blockIdx.x, blockIdx.y, blockIdx.z,
                         A, BT, C, M, N, Kd, lda, ldb, ldc, hdiv,
                         sAb, sAh, sBb, sBh, sCb, sCh, bias, rvec);
}

// ---------------------------------------------------------------------------
// FUSED: blocks 0-31 run the sequential cp+alpha scan; blocks 32-415 run the
// u = q_ca.k_ca/sqrt GEMM (virtual grid 24x2x8). Independent work; the GEMM
// fills the 224 CUs the scan leaves idle.
// Scan: 256 thr x 12 elems, DPP wave scans, LDS-only barrier, ping-pong ws.
// ---------------------------------------------------------------------------
__global__ __launch_bounds__(256)
void fused_mid(const float* __restrict__ p_slot, float* __restrict__ alpha_slot,
               const float* __restrict__ qbuf, const half_t* __restrict__ kbuf,
               float* __restrict__ u_buf)
{
  __shared__ MidLds lds;
  int blk = blockIdx.x;

  if (blk >= 32) {                       // ---- u GEMM ----
    int t = blk - 32;
    int bx = t % 24; t /= 24;
    int by = t % 2;  int bz = t / 2;
    mgemm_body<2,false,float>(lds.g, bx, by, bz, qbuf, kbuf, u_buf,
        256, 3000, 512, 512, 512, 3000, 1,
        131072, 0, 1536000, 0, 768000, 0, nullptr, nullptr);
    return;
  }

  // ---- scan for chain blk ----
  float (&wsA)[2][4] = lds.s.wsA;
  float (&wsB)[2][4] = lds.s.wsB;
  int tid = threadIdx.x;
  int lane = tid & 63, wid = tid >> 6;
  int k0 = tid * 12;
  bool act = (k0 < 3000);
  size_t zbase = (size_t)blk * 768000;   // 256*3000

  float a_prev[12];
  #pragma unroll
  for (int c = 0; c < 12; c++) a_prev[c] = 0.f;
  if (tid == 0) a_prev[0] = 1.f;

  float pc[12], pv[12];
  if (act) {
    #pragma unroll
    for (int q = 0; q < 3; q++) {
      f32x4 v0 = *(const f32x4*)&p_slot[zbase + k0 + q * 4];
      f32x4 v1 = *(const f32x4*)&p_slot[zbase + 3000 + k0 + q * 4];
      #pragma unroll
      for (int j = 0; j < 4; j++) { pc[q * 4 + j] = v0[j]; pv[q * 4 + j] = v1[j]; }
    }
  } else {
    #pragma unroll
    for (int c = 0; c < 12; c++) { pc[c] = 0.f; pv[c] = 0.f; }
  }

  float cpv[12];
  { // prologue: cp row 0 (multiplicative DPP scan)
    float l[12], m = 1.f;
    #pragma unroll
    for (int c = 0; c < 12; c++) {
      l[c] = m;
      m *= fminf(fmaxf(1.f - pc[c], EPSV), 1.f);
    }
    float incl = wave_iscan_mul(m);
    if (lane == 63) wsA[1][wid] = incl;
    float excl = incl * frcp(fmaxf(m, 1e-30f));
    block_sync_lds();
    float base = excl;
    for (int w = 0; w < wid; w++) base *= wsA[1][w];
    #pragma unroll
    for (int c = 0; c < 12; c++) cpv[c] = base * l[c];
  }

  for (int i = 0; i < 256; i++) {
    int par = i & 1;
    // scan2: inclusive cumsum of a_prev * rcp(clip(cp_i))
    float inv[12];
    #pragma unroll
    for (int c = 0; c < 12; c++) inv[c] = frcp(fmaxf(cpv[c], EPSV));
    float t[12], s2 = 0.f;
    #pragma unroll
    for (int c = 0; c < 12; c++) {
      s2 = fmaf(a_prev[c], inv[c], s2);
      t[c] = s2;
    }
    float incl2 = wave_iscan_add(s2);
    if (lane == 63) wsB[par][wid] = incl2;
    float excl2 = incl2 - s2;

    // scan1: cp for row i+1 (multiplicative, recurrence-independent)
    float pn[12], l[12], m = 1.f;
    #pragma unroll
    for (int c = 0; c < 12; c++) {
      pn[c] = pv[c];
      l[c] = m;
      m *= fminf(fmaxf(1.f - pn[c], EPSV), 1.f);
    }
    float incl1 = wave_iscan_mul(m);
    if (lane == 63) wsA[par][wid] = incl1;
    float excl1 = incl1 * frcp(fmaxf(m, 1e-30f));

    block_sync_lds();                    // the single (LDS-only) barrier

    float off = excl2;
    for (int w = 0; w < wid; w++) off += wsB[par][w];
    size_t rbase = zbase + (size_t)i * 3000;
    float an[12];
    #pragma unroll
    for (int c = 0; c < 12; c++) {
      an[c] = pc[c] * cpv[c] * (off + t[c]);
      a_prev[c] = an[c];
    }
    if (act) {
      #pragma unroll
      for (int q = 0; q < 3; q++) {
        f32x4 o;
        #pragma unroll
        for (int j = 0; j < 4; j++) o[j] = an[q * 4 + j];
        *(f32x4*)&alpha_slot[rbase + k0 + q * 4] = o;
      }
    }
    float base1 = excl1;
    for (int w = 0; w < wid; w++) base1 *= wsA[par][w];
    #pragma unroll
    for (int c = 0; c < 12; c++) { cpv[c] = base1 * l[c]; pc[c] = pn[c]; }
    if (i < 254 && act) {                // prefetch p row i+2
      size_t nb = zbase + (size_t)(i + 2) * 3000;
      #pragma unroll
      for (int q = 0; q < 3; q++) {
        f32x4 v1 = *(const f32x4*)&p_slot[nb + k0 + q * 4];
        #pragma unroll
        for (int j = 0; j < 4; j++) pv[q * 4 + j] = v1[j];
      }
    }
  }
}

// ---------------------------------------------------------------------------
// Chunkwise beta (unchanged from round 10).
// ---------------------------------------------------------------------------
__global__ __launch_bounds__(256)
void beta_kernel(const float* __restrict__ ubuf, const float* __restrict__ alpha_slot,
                 float* __restrict__ beta_slot)
{
  __shared__ float se[3008];
  __shared__ float dn[3008];
  __shared__ float tt[3024];
  __shared__ float red[4];
  int bq = blockIdx.x;
  int b = bq >> 8, q = bq & 255;
  int tid = threadIdx.x;
  int lane = tid & 63, wid = tid >> 6;
  const float* urow = ubuf + (size_t)bq * 3000;
  float lmax = -3.0e38f;
  for (int i = tid; i < 3000; i += 256) { float v = urow[i]; se[i] = v; lmax = fmaxf(lmax, v); }
  #pragma unroll
  for (int d = 32; d > 0; d >>= 1) lmax = fmaxf(lmax, __shfl_xor(lmax, d));
  if (lane == 0) red[wid] = lmax;
  __syncthreads();
  float umax = fmaxf(fmaxf(red[0], red[1]), fmaxf(red[2], red[3]));
  for (int i = tid; i < 3000; i += 256) se[i] = fmaxf(expf(se[i] - umax), 1e-5f);
  if (tid < 24) tt[3000 + tid] = 0.f;
  __syncthreads();
  for (int k = tid; k < 3000; k += 256) {
    int lo = k - 15; if (lo < 0) lo = 0;
    float s = 0.f;
    for (int j = lo; j <= k; j++) s += se[j];
    dn[k] = s;
  }
  __syncthreads();
  for (int h = 0; h < 4; h++) {
    const float* arow = alpha_slot + ((size_t)((b * 4 + h) * 256 + q)) * 3000;
    for (int i = tid; i < 3000; i += 256) tt[i] = arow[i] * frcp(dn[i]);
    __syncthreads();
    float* brow = beta_slot + ((size_t)((b * 4 + h) * 256 + q)) * 3000;
    for (int k = tid; k < 3000; k += 256) {
      float s = 0.f;
      #pragma unroll
      for (int j = 0; j < 16; j++) s += tt[k + j];
      brow[k] = se[k] * s;
    }
    __syncthreads();
  }
}

// ---------------------------------------------------------------------------
extern "C" void kernel_launch(void* const* d_in, const int* in_sizes, int n_in,
                              void* d_out, int out_size, void* d_ws, size_t ws_size,
                              hipStream_t stream)
{
  const float* key        = (const float*)d_in[0];
  const float* query      = (const float*)d_in[1];
  const float* w_key_ma   = (const float*)d_in[2];
  const float* b_key_ma   = (const float*)d_in[3];
  const float* w_query_ma = (const float*)d_in[4];
  const float* b_query_ma = (const float*)d_in[5];
  const float* rvec       = (const float*)d_in[6];
  const float* w_key_ca   = (const float*)d_in[7];
  const float* b_key_ca   = (const float*)d_in[8];
  const float* w_query_ca = (const float*)d_in[9];
  const float* b_query_ca = (const float*)d_in[10];
  const float* w_value    = (const float*)d_in[11];
  const float* b_value    = (const float*)d_in[12];

  // Outputs FP32: cv | alpha | beta, flat.
  float* out       = (float*)d_out;
  float* cv_out    = out;                                  // (8,256,512)
  float* alpha_out = out + (size_t)1048576;                // (8,4,256,3000)
  float* beta_out  = alpha_out + (size_t)24576000;         // (8,4,256,3000)

  // workspace: kbuf f16 (k_ma -> k_ca -> vT) | qbuf f32 (q_ma -> q_ca) |
  // u f32 | 5x W^T f16.  Total 55,967,744 B (~53.4 MiB).
  half_t* kbuf   = (half_t*)d_ws;                              // 24000x512 (or vT 512x24000)
  float*  qbuf   = (float*)((char*)d_ws + 24576000);           // 2048x512
  float*  u_buf  = (float*)((char*)d_ws + 28770304);           // 8x256x3000
  half_t* wt_qma = (half_t*)((char*)d_ws + 53346304);
  half_t* wt_kma = (half_t*)((char*)d_ws + 53870592);
  half_t* wt_qca = (half_t*)((char*)d_ws + 54394880);
  half_t* wt_kca = (half_t*)((char*)d_ws + 54919168);
  half_t* wt_v   = (half_t*)((char*)d_ws + 55443456);
  if (ws_size < (size_t)55967744) return;

  dim3 blk(256);
  dim3 tgrid(16, 16);

  // weight transposes (f32 -> f16 [N][K])
  wtrans<<<tgrid, blk, 0, stream>>>(w_query_ma, wt_qma);
  wtrans<<<tgrid, blk, 0, stream>>>(w_key_ma,   wt_kma);
  wtrans<<<tgrid, blk, 0, stream>>>(w_query_ca, wt_qca);
  wtrans<<<tgrid, blk, 0, stream>>>(w_key_ca,   wt_kca);
  wtrans<<<tgrid, blk, 0, stream>>>(w_value,    wt_v);

  // --- MA path ---
  mgemm<0,false,float ><<<dim3(4,16,1),  blk, 0, stream>>>(query, wt_qma, qbuf, 2048, 512, 512, 512,512,512, 1, 0,0,0,0,0,0, b_query_ma, nullptr);
  mgemm<0,false,half_t><<<dim3(4,188,1), blk, 0, stream>>>(key,   wt_kma, kbuf, 24000,512, 512, 512,512,512, 1, 0,0,0,0,0,0, b_key_ma,   nullptr);
  mgemm<1,false,float ><<<dim3(24,2,32), blk, 0, stream>>>(qbuf,  kbuf, beta_out, 256,3000, 128, 512,512,3000, 4,
      131072,128, 1536000,128, 3072000,768000, nullptr, rvec);

  // --- CA projections ---
  mgemm<0,false,float ><<<dim3(4,16,1),  blk, 0, stream>>>(query, wt_qca, qbuf, 2048, 512, 512, 512,512,512, 1, 0,0,0,0,0,0, b_query_ca, nullptr);
  mgemm<0,false,half_t><<<dim3(4,188,1), blk, 0, stream>>>(key,   wt_kca, kbuf, 24000,512, 512, 512,512,512, 1, 0,0,0,0,0,0, b_key_ca,   nullptr);

  // --- FUSED: alpha scan (blocks 0-31) + u GEMM (blocks 32-415) ---
  fused_mid<<<dim3(416), blk, 0, stream>>>(beta_out, alpha_out, qbuf, kbuf, u_buf);

  // --- v projection, stored TRANSPOSED: vT[512][24000] f16 (kbuf free now) ---
  mgemm<0,true,half_t><<<dim3(4,188,1), blk, 0, stream>>>(key, wt_v, kbuf, 24000,512, 512, 512,512,24000, 1, 0,0,0,0,0,0, b_value, nullptr);

  // --- chunkwise beta ---
  beta_kernel<<<dim3(2048), blk, 0, stream>>>(u_buf, alpha_out, beta_out);

  // --- cv = beta @ v via MFMA (A=beta fp32, BT=vT f16) ---
  mgemm<3,false,float><<<dim3(1,2,32), blk, 0, stream>>>(beta_out, kbuf, cv_out, 256,128,3000, 3000,24000,512, 4,
      3072000,768000, 3000,3072000, 131072,128, nullptr, nullptr);
}

// Round 12
// 908.851 us; speedup vs baseline: 2.8533x; 1.0265x over previous
//
#include <hip/hip_runtime.h>
#include <hip/hip_bf16.h>
#include <math.h>

#define EPSV 1e-6f
#define INV_SCALE 0.04419417382415922f   // 1/sqrt(512)

typedef _Float16 half_t;
typedef __attribute__((ext_vector_type(8))) _Float16 half8;
typedef __attribute__((ext_vector_type(4))) _Float16 half4v;
typedef __attribute__((ext_vector_type(4))) float    f32x4;

__device__ __forceinline__ float ldf(const float* p)  { return *p; }
__device__ __forceinline__ float ldf(const half_t* p) { return (float)*p; }
__device__ __forceinline__ void  stf(float* p, float v)  { *p = v; }
__device__ __forceinline__ void  stf(half_t* p, float v) { *p = (half_t)v; }
__device__ __forceinline__ float frcp(float x) { return __builtin_amdgcn_rcpf(x); }

// ---------------------------------------------------------------------------
// DPP wave-64 inclusive scans (VALU, no LDS) — validated round 11.
// ---------------------------------------------------------------------------
template<int CTRL, int RMASK>
__device__ __forceinline__ float dpp_add_step(float x) {
  int t = __builtin_amdgcn_update_dpp(0, __float_as_int(x), CTRL, RMASK, 0xf, true);
  return x + __int_as_float(t);
}
template<int CTRL, int RMASK>
__device__ __forceinline__ float dpp_mul_step(float x) {
  int t = __builtin_amdgcn_update_dpp(0x3f800000, __float_as_int(x), CTRL, RMASK, 0xf, false);
  return x * __int_as_float(t);
}
__device__ __forceinline__ float wave_iscan_add(float x) {
  x = dpp_add_step<0x111,0xf>(x);
  x = dpp_add_step<0x112,0xf>(x);
  x = dpp_add_step<0x114,0xf>(x);
  x = dpp_add_step<0x118,0xf>(x);
  x = dpp_add_step<0x142,0xa>(x);
  x = dpp_add_step<0x143,0xc>(x);
  return x;
}
__device__ __forceinline__ float wave_iscan_mul(float x) {
  x = dpp_mul_step<0x111,0xf>(x);
  x = dpp_mul_step<0x112,0xf>(x);
  x = dpp_mul_step<0x114,0xf>(x);
  x = dpp_mul_step<0x118,0xf>(x);
  x = dpp_mul_step<0x142,0xa>(x);
  x = dpp_mul_step<0x143,0xc>(x);
  return x;
}

// LDS-only barrier (skips the vmcnt(0) drain __syncthreads emits).
__device__ __forceinline__ void block_sync_lds() {
  asm volatile("s_waitcnt lgkmcnt(0)" ::: "memory");
  __builtin_amdgcn_s_barrier();
  asm volatile("" ::: "memory");
}

// Cross-wave prefix helpers over 16 wave-sums: 4x f32x4 LDS reads + masked ops.
__device__ __forceinline__ float cross_sum16(const float* ws, int wid) {
  f32x4 a = *(const f32x4*)&ws[0];
  f32x4 b = *(const f32x4*)&ws[4];
  f32x4 c = *(const f32x4*)&ws[8];
  f32x4 d = *(const f32x4*)&ws[12];
  float s = 0.f;
  #pragma unroll
  for (int j = 0; j < 4; j++) s += (wid > j)      ? a[j] : 0.f;
  #pragma unroll
  for (int j = 0; j < 4; j++) s += (wid > 4 + j)  ? b[j] : 0.f;
  #pragma unroll
  for (int j = 0; j < 4; j++) s += (wid > 8 + j)  ? c[j] : 0.f;
  #pragma unroll
  for (int j = 0; j < 4; j++) s += (wid > 12 + j) ? d[j] : 0.f;
  return s;
}
__device__ __forceinline__ float cross_prod16(const float* ws, int wid) {
  f32x4 a = *(const f32x4*)&ws[0];
  f32x4 b = *(const f32x4*)&ws[4];
  f32x4 c = *(const f32x4*)&ws[8];
  f32x4 d = *(const f32x4*)&ws[12];
  float p = 1.f;
  #pragma unroll
  for (int j = 0; j < 4; j++) p *= (wid > j)      ? a[j] : 1.f;
  #pragma unroll
  for (int j = 0; j < 4; j++) p *= (wid > 4 + j)  ? b[j] : 1.f;
  #pragma unroll
  for (int j = 0; j < 4; j++) p *= (wid > 8 + j)  ? c[j] : 1.f;
  #pragma unroll
  for (int j = 0; j < 4; j++) p *= (wid > 12 + j) ? d[j] : 1.f;
  return p;
}

// ---------------------------------------------------------------------------
// Weight transpose + f16 convert: WT[n][k] = (half)W[k][n], 512x512.
// ---------------------------------------------------------------------------
__global__ __launch_bounds__(256)
void wtrans(const float* __restrict__ W, half_t* __restrict__ WT)
{
  __shared__ float t[32][33];
  int bx = blockIdx.x, by = blockIdx.y;
  int tid = threadIdx.x;
  int r = tid >> 3, cq = tid & 7;
  float4 v = *(const float4*)&W[(size_t)(bx * 32 + r) * 512 + by * 32 + cq * 4];
  t[r][cq * 4 + 0] = v.x; t[r][cq * 4 + 1] = v.y;
  t[r][cq * 4 + 2] = v.z; t[r][cq * 4 + 3] = v.w;
  __syncthreads();
  half4v o;
  o[0] = (half_t)t[cq * 4 + 0][r];
  o[1] = (half_t)t[cq * 4 + 1][r];
  o[2] = (half_t)t[cq * 4 + 2][r];
  o[3] = (half_t)t[cq * 4 + 3][r];
  *(half4v*)&WT[(size_t)(by * 32 + r) * 512 + bx * 32 + cq * 4] = o;
}

// ---------------------------------------------------------------------------
// MFMA GEMM body. G=true: running inside a 1024-thread shell block — only
// tid<256 does work, ALL threads execute the barriers.
// ---------------------------------------------------------------------------
struct GemmLds { half_t As[4][128][8]; half_t Bs[4][128][8]; };
struct __align__(16) ScanLds { float wsA[2][16]; float wsB[2][16]; };
union  MidLds  { GemmLds g; ScanLds s; };

template<int MODE, bool CT, bool G, typename TC>
__device__ __forceinline__
void mgemm_body(GemmLds& L, int bxx, int byy, int bzz,
                const float* __restrict__ A, const half_t* __restrict__ BT,
                TC* __restrict__ C, int M, int N, int Kd,
                int lda, int ldb, int ldc, int hdiv,
                long long sAb, long long sAh, long long sBb, long long sBh,
                long long sCb, long long sCh,
                const float* __restrict__ bias, const float* __restrict__ rvec)
{
  int bz = bzz / hdiv, hz = bzz - bz * hdiv;
  A  += (size_t)bz * sAb + (size_t)hz * sAh;
  BT += (size_t)bz * sBb + (size_t)hz * sBh;
  C  += (size_t)bz * sCb + (size_t)hz * sCh;

  int tid = threadIdx.x;
  bool w = !G || (tid < 256);
  int lane = tid & 63, wid = tid >> 6;
  int wm = wid >> 1, wn = wid & 1;
  int m0 = byy * 128, n0 = bxx * 128;

  f32x4 acc[4][4] = {};

  for (int k0 = 0; k0 < Kd; k0 += 32) {
    if (w) {
      #pragma unroll
      for (int i = 0; i < 4; i++) {            // A: 128x32 f32 -> f16
        int ch = tid + i * 256;
        int m = ch >> 3, cq = ch & 7, k = cq * 4;
        float4 v = make_float4(0.f, 0.f, 0.f, 0.f);
        if (m0 + m < M && k0 + k < Kd) v = *(const float4*)&A[(size_t)(m0 + m) * lda + k0 + k];
        half4v h;
        h[0] = (half_t)v.x; h[1] = (half_t)v.y; h[2] = (half_t)v.z; h[3] = (half_t)v.w;
        *(half4v*)&L.As[cq >> 1][m][(cq & 1) * 4] = h;
      }
      #pragma unroll
      for (int i = 0; i < 2; i++) {            // B: 128x32 f16
        int ch = tid + i * 256;
        int n = ch >> 2, kb = ch & 3;
        half8 v = {(_Float16)0,(_Float16)0,(_Float16)0,(_Float16)0,
                   (_Float16)0,(_Float16)0,(_Float16)0,(_Float16)0};
        if (n0 + n < N && k0 + kb * 8 < Kd)
          v = *(const half8*)&BT[(size_t)(n0 + n) * ldb + k0 + kb * 8];
        *(half8*)&L.Bs[kb][n][0] = v;
      }
    }
    __syncthreads();
    if (w) {
      int kb = lane >> 4, r = lane & 15;
      half8 af[4], bfv[4];
      #pragma unroll
      for (int mi = 0; mi < 4; mi++) af[mi]  = *(const half8*)&L.As[kb][wm * 64 + mi * 16 + r][0];
      #pragma unroll
      for (int ni = 0; ni < 4; ni++) bfv[ni] = *(const half8*)&L.Bs[kb][wn * 64 + ni * 16 + r][0];
      #pragma unroll
      for (int mi = 0; mi < 4; mi++)
        #pragma unroll
        for (int ni = 0; ni < 4; ni++)
          acc[mi][ni] = __builtin_amdgcn_mfma_f32_16x16x32_f16(af[mi], bfv[ni], acc[mi][ni], 0, 0, 0);
    }
    __syncthreads();
  }

  if (!w) return;
  float radd = (MODE == 1) ? rvec[hz] : 0.f;
  int r = lane & 15, g = lane >> 4;
  #pragma unroll
  for (int mi = 0; mi < 4; mi++) {
    #pragma unroll
    for (int ni = 0; ni < 4; ni++) {
      int col = n0 + wn * 64 + ni * 16 + r;
      if (col >= N) continue;
      float bv = (MODE == 0) ? bias[col] : 0.f;
      if (CT) {
        int row0 = m0 + wm * 64 + mi * 16 + g * 4;
        if (row0 + 3 < M) {
          half4v o;
          #pragma unroll
          for (int j = 0; j < 4; j++) o[j] = (half_t)(acc[mi][ni][j] + bv);
          *(half4v*)&((half_t*)C)[(size_t)col * ldc + row0] = o;
        }
      } else {
        #pragma unroll
        for (int j = 0; j < 4; j++) {
          int row = m0 + wm * 64 + mi * 16 + g * 4 + j;
          if (row >= M) continue;
          float v = acc[mi][ni][j];
          if (MODE == 0)      v += bv;
          else if (MODE == 1) v = frcp(1.f + expf(-(v * INV_SCALE + radd)));
          else if (MODE == 2) v *= INV_SCALE;
          stf(&C[(size_t)row * ldc + col], v);
        }
      }
    }
  }
}

template<int MODE, bool CT, typename TC>
__global__ __launch_bounds__(256)
void mgemm(const float* __restrict__ A, const half_t* __restrict__ BT,
           TC* __restrict__ C, int M, int N, int Kd,
           int lda, int ldb, int ldc, int hdiv,
           long long sAb, long long sAh, long long sBb, long long sBh,
           long long sCb, long long sCh,
           const float* __restrict__ bias, const float* __restrict__ rvec)
{
  __shared__ GemmLds L;
  mgemm_body<MODE,CT,false,TC>(L, blockIdx.x, blockIdx.y, blockIdx.z,
                               A, BT, C, M, N, Kd, lda, ldb, ldc, hdiv,
                               sAb, sAh, sBb, sBh, sCb, sCh, bias, rvec);
}

// ---------------------------------------------------------------------------
// FUSED (1024 threads): blocks 0-31 = cp+alpha scan with 16 waves (high MLP:
// prefetch + state fit in ~48 VGPR at 4 elems/thread, stores+loads from 16
// waves keep the memory system busy); blocks 32-415 = u GEMM shells (tid<256
// work, barriers by all).
// ---------------------------------------------------------------------------
__global__ __launch_bounds__(1024)
void fused_mid(const float* __restrict__ p_slot, float* __restrict__ alpha_slot,
               const float* __restrict__ qbuf, const half_t* __restrict__ kbuf,
               float* __restrict__ u_buf)
{
  __shared__ MidLds lds;
  int blk = blockIdx.x;
  int tid = threadIdx.x;

  if (blk >= 32) {                       // ---- u GEMM shell ----
    int t = blk - 32;
    int bx = t % 24; t /= 24;
    int by = t % 2;  int bz = t / 2;
    mgemm_body<2,false,true,float>(lds.g, bx, by, bz, qbuf, kbuf, u_buf,
        256, 3000, 512, 512, 512, 3000, 1,
        131072, 0, 1536000, 0, 768000, 0, nullptr, nullptr);
    return;
  }

  // ---- scan for chain blk: 1024 thr x 4 elems (3000 = 750x4) ----
  float (&wsA)[2][16] = lds.s.wsA;
  float (&wsB)[2][16] = lds.s.wsB;
  int lane = tid & 63, wid = tid >> 6;
  int k0 = tid * 4;
  bool act = (k0 < 3000);
  size_t zbase = (size_t)blk * 768000;   // 256*3000

  f32x4 a_prev = {0.f, 0.f, 0.f, 0.f};
  if (tid == 0) a_prev[0] = 1.f;

  f32x4 pc = {0.f,0.f,0.f,0.f}, pv = {0.f,0.f,0.f,0.f};
  if (act) {
    pc = *(const f32x4*)&p_slot[zbase + k0];
    pv = *(const f32x4*)&p_slot[zbase + 3000 + k0];
  }

  f32x4 cpv;
  { // prologue: cp row 0 (multiplicative DPP scan)
    float l[4], m = 1.f;
    #pragma unroll
    for (int c = 0; c < 4; c++) {
      l[c] = m;
      m *= fminf(fmaxf(1.f - pc[c], EPSV), 1.f);
    }
    float incl = wave_iscan_mul(m);
    if (lane == 63) wsA[1][wid] = incl;
    float exclw = incl * frcp(fmaxf(m, 1e-30f));
    block_sync_lds();
    float base = exclw * cross_prod16(&wsA[1][0], wid);
    #pragma unroll
    for (int c = 0; c < 4; c++) cpv[c] = base * l[c];
  }

  for (int i = 0; i < 256; i++) {
    int par = i & 1;
    // scan2: inclusive cumsum of a_prev * rcp(clip(cp_i))
    float t4[4], s2 = 0.f;
    #pragma unroll
    for (int c = 0; c < 4; c++) {
      s2 = fmaf(a_prev[c], frcp(fmaxf(cpv[c], EPSV)), s2);
      t4[c] = s2;
    }
    float incl2 = wave_iscan_add(s2);
    if (lane == 63) wsB[par][wid] = incl2;
    float excl2 = incl2 - s2;

    // scan1: cp for row i+1 (multiplicative, recurrence-independent)
    f32x4 pn = pv;
    float l[4], m = 1.f;
    #pragma unroll
    for (int c = 0; c < 4; c++) {
      l[c] = m;
      m *= fminf(fmaxf(1.f - pn[c], EPSV), 1.f);
    }
    float incl1 = wave_iscan_mul(m);
    if (lane == 63) wsA[par][wid] = incl1;
    float excl1 = incl1 * frcp(fmaxf(m, 1e-30f));

    block_sync_lds();                    // the single (LDS-only) barrier

    float off = excl2 + cross_sum16(&wsB[par][0], wid);
    size_t rbase = zbase + (size_t)i * 3000;
    f32x4 an;
    #pragma unroll
    for (int c = 0; c < 4; c++) an[c] = pc[c] * cpv[c] * (off + t4[c]);
    a_prev = an;
    if (act) *(f32x4*)&alpha_slot[rbase + k0] = an;

    float base1 = excl1 * cross_prod16(&wsA[par][0], wid);
    #pragma unroll
    for (int c = 0; c < 4; c++) cpv[c] = base1 * l[c];
    pc = pn;
    if (i < 254 && act)                  // prefetch p row i+2 (stays in VGPRs)
      pv = *(const f32x4*)&p_slot[zbase + (size_t)(i + 2) * 3000 + k0];
  }
}

// ---------------------------------------------------------------------------
// Chunkwise beta (unchanged).
// ---------------------------------------------------------------------------
__global__ __launch_bounds__(256)
void beta_kernel(const float* __restrict__ ubuf, const float* __restrict__ alpha_slot,
                 float* __restrict__ beta_slot)
{
  __shared__ float se[3008];
  __shared__ float dn[3008];
  __shared__ float tt[3024];
  __shared__ float red[4];
  int bq = blockIdx.x;
  int b = bq >> 8, q = bq & 255;
  int tid = threadIdx.x;
  int lane = tid & 63, wid = tid >> 6;
  const float* urow = ubuf + (size_t)bq * 3000;
  float lmax = -3.0e38f;
  for (int i = tid; i < 3000; i += 256) { float v = urow[i]; se[i] = v; lmax = fmaxf(lmax, v); }
  #pragma unroll
  for (int d = 32; d > 0; d >>= 1) lmax = fmaxf(lmax, __shfl_xor(lmax, d));
  if (lane == 0) red[wid] = lmax;
  __syncthreads();
  float umax = fmaxf(fmaxf(red[0], red[1]), fmaxf(red[2], red[3]));
  for (int i = tid; i < 3000; i += 256) se[i] = fmaxf(expf(se[i] - umax), 1e-5f);
  if (tid < 24) tt[3000 + tid] = 0.f;
  __syncthreads();
  for (int k = tid; k < 3000; k += 256) {
    int lo = k - 15; if (lo < 0) lo = 0;
    float s = 0.f;
    for (int j = lo; j <= k; j++) s += se[j];
    dn[k] = s;
  }
  __syncthreads();
  for (int h = 0; h < 4; h++) {
    const float* arow = alpha_slot + ((size_t)((b * 4 + h) * 256 + q)) * 3000;
    for (int i = tid; i < 3000; i += 256) tt[i] = arow[i] * frcp(dn[i]);
    __syncthreads();
    float* brow = beta_slot + ((size_t)((b * 4 + h) * 256 + q)) * 3000;
    for (int k = tid; k < 3000; k += 256) {
      float s = 0.f;
      #pragma unroll
      for (int j = 0; j < 16; j++) s += tt[k + j];
      brow[k] = se[k] * s;
    }
    __syncthreads();
  }
}

// ---------------------------------------------------------------------------
extern "C" void kernel_launch(void* const* d_in, const int* in_sizes, int n_in,
                              void* d_out, int out_size, void* d_ws, size_t ws_size,
                              hipStream_t stream)
{
  const float* key        = (const float*)d_in[0];
  const float* query      = (const float*)d_in[1];
  const float* w_key_ma   = (const float*)d_in[2];
  const float* b_key_ma   = (const float*)d_in[3];
  const float* w_query_ma = (const float*)d_in[4];
  const float* b_query_ma = (const float*)d_in[5];
  const float* rvec       = (const float*)d_in[6];
  const float* w_key_ca   = (const float*)d_in[7];
  const float* b_key_ca   = (const float*)d_in[8];
  const float* w_query_ca = (const float*)d_in[9];
  const float* b_query_ca = (const float*)d_in[10];
  const float* w_value    = (const float*)d_in[11];
  const float* b_value    = (const float*)d_in[12];

  // Outputs FP32: cv | alpha | beta, flat.
  float* out       = (float*)d_out;
  float* cv_out    = out;                                  // (8,256,512)
  float* alpha_out = out + (size_t)1048576;                // (8,4,256,3000)
  float* beta_out  = alpha_out + (size_t)24576000;         // (8,4,256,3000)

  // workspace: kbuf f16 (k_ma -> k_ca -> vT) | qbuf f32 (q_ma -> q_ca) |
  // u f32 | 5x W^T f16.  Total 55,967,744 B (~53.4 MiB).
  half_t* kbuf   = (half_t*)d_ws;                              // 24000x512 (or vT 512x24000)
  float*  qbuf   = (float*)((char*)d_ws + 24576000);           // 2048x512
  float*  u_buf  = (float*)((char*)d_ws + 28770304);           // 8x256x3000
  half_t* wt_qma = (half_t*)((char*)d_ws + 53346304);
  half_t* wt_kma = (half_t*)((char*)d_ws + 53870592);
  half_t* wt_qca = (half_t*)((char*)d_ws + 54394880);
  half_t* wt_kca = (half_t*)((char*)d_ws + 54919168);
  half_t* wt_v   = (half_t*)((char*)d_ws + 55443456);
  if (ws_size < (size_t)55967744) return;

  dim3 blk(256);
  dim3 tgrid(16, 16);

  // weight transposes (f32 -> f16 [N][K])
  wtrans<<<tgrid, blk, 0, stream>>>(w_query_ma, wt_qma);
  wtrans<<<tgrid, blk, 0, stream>>>(w_key_ma,   wt_kma);
  wtrans<<<tgrid, blk, 0, stream>>>(w_query_ca, wt_qca);
  wtrans<<<tgrid, blk, 0, stream>>>(w_key_ca,   wt_kca);
  wtrans<<<tgrid, blk, 0, stream>>>(w_value,    wt_v);

  // --- MA path ---
  mgemm<0,false,float ><<<dim3(4,16,1),  blk, 0, stream>>>(query, wt_qma, qbuf, 2048, 512, 512, 512,512,512, 1, 0,0,0,0,0,0, b_query_ma, nullptr);
  mgemm<0,false,half_t><<<dim3(4,188,1), blk, 0, stream>>>(key,   wt_kma, kbuf, 24000,512, 512, 512,512,512, 1, 0,0,0,0,0,0, b_key_ma,   nullptr);
  mgemm<1,false,float ><<<dim3(24,2,32), blk, 0, stream>>>(qbuf,  kbuf, beta_out, 256,3000, 128, 512,512,3000, 4,
      131072,128, 1536000,128, 3072000,768000, nullptr, rvec);

  // --- CA projections ---
  mgemm<0,false,float ><<<dim3(4,16,1),  blk, 0, stream>>>(query, wt_qca, qbuf, 2048, 512, 512, 512,512,512, 1, 0,0,0,0,0,0, b_query_ca, nullptr);
  mgemm<0,false,half_t><<<dim3(4,188,1), blk, 0, stream>>>(key,   wt_kca, kbuf, 24000,512, 512, 512,512,512, 1, 0,0,0,0,0,0, b_key_ca,   nullptr);

  // --- FUSED (1024 thr): alpha scan (blocks 0-31) + u GEMM shells (32-415) ---
  fused_mid<<<dim3(416), dim3(1024), 0, stream>>>(beta_out, alpha_out, qbuf, kbuf, u_buf);

  // --- v projection, stored TRANSPOSED: vT[512][24000] f16 (kbuf free now) ---
  mgemm<0,true,half_t><<<dim3(4,188,1), blk, 0, stream>>>(key, wt_v, kbuf, 24000,512, 512, 512,512,24000, 1, 0,0,0,0,0,0, b_value, nullptr);

  // --- chunkwise beta ---
  beta_kernel<<<dim3(2048), blk, 0, stream>>>(u_buf, alpha_out, beta_out);

  // --- cv = beta @ v via MFMA (A=beta fp32, BT=vT f16) ---
  mgemm<3,false,float><<<dim3(1,2,32), blk, 0, stream>>>(beta_out, kbuf, cv_out, 256,128,3000, 3000,24000,512, 4,
      3072000,768000, 3000,3072000, 131072,128, nullptr, nullptr);
}

// Round 13
// 682.296 us; speedup vs baseline: 3.8008x; 1.3320x over previous
//
#include <hip/hip_runtime.h>
#include <hip/hip_bf16.h>
#include <math.h>

#define EPSV 1e-6f
#define INV_SCALE 0.04419417382415922f   // 1/sqrt(512)

typedef _Float16 half_t;
typedef __attribute__((ext_vector_type(8))) _Float16 half8;
typedef __attribute__((ext_vector_type(4))) _Float16 half4v;
typedef __attribute__((ext_vector_type(2))) _Float16 half2v;
typedef __attribute__((ext_vector_type(4))) float    f32x4;

__device__ __forceinline__ float ldf(const float* p)  { return *p; }
__device__ __forceinline__ float ldf(const half_t* p) { return (float)*p; }
__device__ __forceinline__ void  stf(float* p, float v)  { *p = v; }
__device__ __forceinline__ void  stf(half_t* p, float v) { *p = (half_t)v; }
__device__ __forceinline__ float frcp(float x) { return __builtin_amdgcn_rcpf(x); }

// ---------------------------------------------------------------------------
// DPP wave-64 inclusive scans (validated rounds 11-12).
// ---------------------------------------------------------------------------
template<int CTRL, int RMASK>
__device__ __forceinline__ float dpp_add_step(float x) {
  int t = __builtin_amdgcn_update_dpp(0, __float_as_int(x), CTRL, RMASK, 0xf, true);
  return x + __int_as_float(t);
}
template<int CTRL, int RMASK>
__device__ __forceinline__ float dpp_mul_step(float x) {
  int t = __builtin_amdgcn_update_dpp(0x3f800000, __float_as_int(x), CTRL, RMASK, 0xf, false);
  return x * __int_as_float(t);
}
__device__ __forceinline__ float wave_iscan_add(float x) {
  x = dpp_add_step<0x111,0xf>(x);
  x = dpp_add_step<0x112,0xf>(x);
  x = dpp_add_step<0x114,0xf>(x);
  x = dpp_add_step<0x118,0xf>(x);
  x = dpp_add_step<0x142,0xa>(x);
  x = dpp_add_step<0x143,0xc>(x);
  return x;
}
__device__ __forceinline__ float wave_iscan_mul(float x) {
  x = dpp_mul_step<0x111,0xf>(x);
  x = dpp_mul_step<0x112,0xf>(x);
  x = dpp_mul_step<0x114,0xf>(x);
  x = dpp_mul_step<0x118,0xf>(x);
  x = dpp_mul_step<0x142,0xa>(x);
  x = dpp_mul_step<0x143,0xc>(x);
  return x;
}

// LDS-only barrier (skips the vmcnt(0) drain __syncthreads emits).
__device__ __forceinline__ void block_sync_lds() {
  asm volatile("s_waitcnt lgkmcnt(0)" ::: "memory");
  __builtin_amdgcn_s_barrier();
  asm volatile("" ::: "memory");
}

// Cross-wave prefix helpers over 16 wave-sums.
__device__ __forceinline__ float cross_sum16(const float* ws, int wid) {
  f32x4 a = *(const f32x4*)&ws[0];
  f32x4 b = *(const f32x4*)&ws[4];
  f32x4 c = *(const f32x4*)&ws[8];
  f32x4 d = *(const f32x4*)&ws[12];
  float s = 0.f;
  #pragma unroll
  for (int j = 0; j < 4; j++) s += (wid > j)      ? a[j] : 0.f;
  #pragma unroll
  for (int j = 0; j < 4; j++) s += (wid > 4 + j)  ? b[j] : 0.f;
  #pragma unroll
  for (int j = 0; j < 4; j++) s += (wid > 8 + j)  ? c[j] : 0.f;
  #pragma unroll
  for (int j = 0; j < 4; j++) s += (wid > 12 + j) ? d[j] : 0.f;
  return s;
}
__device__ __forceinline__ float cross_prod16(const float* ws, int wid) {
  f32x4 a = *(const f32x4*)&ws[0];
  f32x4 b = *(const f32x4*)&ws[4];
  f32x4 c = *(const f32x4*)&ws[8];
  f32x4 d = *(const f32x4*)&ws[12];
  float p = 1.f;
  #pragma unroll
  for (int j = 0; j < 4; j++) p *= (wid > j)      ? a[j] : 1.f;
  #pragma unroll
  for (int j = 0; j < 4; j++) p *= (wid > 4 + j)  ? b[j] : 1.f;
  #pragma unroll
  for (int j = 0; j < 4; j++) p *= (wid > 8 + j)  ? c[j] : 1.f;
  #pragma unroll
  for (int j = 0; j < 4; j++) p *= (wid > 12 + j) ? d[j] : 1.f;
  return p;
}

// ---------------------------------------------------------------------------
// Weight transpose + f16 convert: WT[n][k] = (half)W[k][n], 512x512.
// ---------------------------------------------------------------------------
__global__ __launch_bounds__(256)
void wtrans(const float* __restrict__ W, half_t* __restrict__ WT)
{
  __shared__ float t[32][33];
  int bx = blockIdx.x, by = blockIdx.y;
  int tid = threadIdx.x;
  int r = tid >> 3, cq = tid & 7;
  float4 v = *(const float4*)&W[(size_t)(bx * 32 + r) * 512 + by * 32 + cq * 4];
  t[r][cq * 4 + 0] = v.x; t[r][cq * 4 + 1] = v.y;
  t[r][cq * 4 + 2] = v.z; t[r][cq * 4 + 3] = v.w;
  __syncthreads();
  half4v o;
  o[0] = (half_t)t[cq * 4 + 0][r];
  o[1] = (half_t)t[cq * 4 + 1][r];
  o[2] = (half_t)t[cq * 4 + 2][r];
  o[3] = (half_t)t[cq * 4 + 3][r];
  *(half4v*)&WT[(size_t)(by * 32 + r) * 512 + bx * 32 + cq * 4] = o;
}

// ---------------------------------------------------------------------------
// MFMA GEMM body. tid in [0,256). K-split via kdiv/kc (kc%32==0); ATOM ->
// atomicAdd epilogue. CT -> store C transposed (vT).
// ---------------------------------------------------------------------------
struct GemmLds { half_t As[4][128][8]; half_t Bs[4][128][8]; };
struct __align__(16) ScanLds { float wsA[2][16]; float wsB[2][16]; };

template<int MODE, bool CT, bool ATOM, typename TC>
__device__ __forceinline__
void mgemm_body(GemmLds& L, int tid, int bxx, int byy, int bzz,
                const float* __restrict__ A, const half_t* __restrict__ BT,
                TC* __restrict__ C, int M, int N, int Kd,
                int lda, int ldb, int ldc, int hdiv, int kdiv, int kc,
                long long sAb, long long sAh, long long sBb, long long sBh,
                long long sCb, long long sCh,
                const float* __restrict__ bias, const float* __restrict__ rvec)
{
  int ks = bzz % kdiv; int zz = bzz / kdiv;
  int bz = zz / hdiv, hz = zz - bz * hdiv;
  A  += (size_t)bz * sAb + (size_t)hz * sAh + (size_t)ks * kc;
  BT += (size_t)bz * sBb + (size_t)hz * sBh + (size_t)ks * kc;
  C  += (size_t)bz * sCb + (size_t)hz * sCh;
  int Ke = Kd - ks * kc; if (Ke > kc) Ke = kc;

  int lane = tid & 63, wid = tid >> 6;
  int wm = wid >> 1, wn = wid & 1;
  int m0 = byy * 128, n0 = bxx * 128;

  f32x4 acc[4][4] = {};

  for (int k0 = 0; k0 < Ke; k0 += 32) {
    #pragma unroll
    for (int i = 0; i < 4; i++) {            // A: 128x32 f32 -> f16
      int ch = tid + i * 256;
      int m = ch >> 3, cq = ch & 7, k = cq * 4;
      float4 v = make_float4(0.f, 0.f, 0.f, 0.f);
      if (m0 + m < M && k0 + k < Ke) v = *(const float4*)&A[(size_t)(m0 + m) * lda + k0 + k];
      half4v h;
      h[0] = (half_t)v.x; h[1] = (half_t)v.y; h[2] = (half_t)v.z; h[3] = (half_t)v.w;
      *(half4v*)&L.As[cq >> 1][m][(cq & 1) * 4] = h;
    }
    #pragma unroll
    for (int i = 0; i < 2; i++) {            // B: 128x32 f16
      int ch = tid + i * 256;
      int n = ch >> 2, kb = ch & 3;
      half8 v = {(_Float16)0,(_Float16)0,(_Float16)0,(_Float16)0,
                 (_Float16)0,(_Float16)0,(_Float16)0,(_Float16)0};
      if (n0 + n < N && k0 + kb * 8 < Ke)
        v = *(const half8*)&BT[(size_t)(n0 + n) * ldb + k0 + kb * 8];
      *(half8*)&L.Bs[kb][n][0] = v;
    }
    __syncthreads();
    int kb = lane >> 4, r = lane & 15;
    half8 af[4], bfv[4];
    #pragma unroll
    for (int mi = 0; mi < 4; mi++) af[mi]  = *(const half8*)&L.As[kb][wm * 64 + mi * 16 + r][0];
    #pragma unroll
    for (int ni = 0; ni < 4; ni++) bfv[ni] = *(const half8*)&L.Bs[kb][wn * 64 + ni * 16 + r][0];
    #pragma unroll
    for (int mi = 0; mi < 4; mi++)
      #pragma unroll
      for (int ni = 0; ni < 4; ni++)
        acc[mi][ni] = __builtin_amdgcn_mfma_f32_16x16x32_f16(af[mi], bfv[ni], acc[mi][ni], 0, 0, 0);
    __syncthreads();
  }

  float radd = (MODE == 1) ? rvec[hz] : 0.f;
  int r = lane & 15, g = lane >> 4;
  #pragma unroll
  for (int mi = 0; mi < 4; mi++) {
    #pragma unroll
    for (int ni = 0; ni < 4; ni++) {
      int col = n0 + wn * 64 + ni * 16 + r;
      if (col >= N) continue;
      float bv = (MODE == 0) ? bias[col] : 0.f;
      if (CT) {
        int row0 = m0 + wm * 64 + mi * 16 + g * 4;
        if (row0 + 3 < M) {
          half4v o;
          #pragma unroll
          for (int j = 0; j < 4; j++) o[j] = (half_t)(acc[mi][ni][j] + bv);
          *(half4v*)&((half_t*)C)[(size_t)col * ldc + row0] = o;
        }
      } else {
        #pragma unroll
        for (int j = 0; j < 4; j++) {
          int row = m0 + wm * 64 + mi * 16 + g * 4 + j;
          if (row >= M) continue;
          float v = acc[mi][ni][j];
          if (MODE == 0)      v += bv;
          else if (MODE == 1) v = frcp(1.f + expf(-(v * INV_SCALE + radd)));
          else if (MODE == 2) v *= INV_SCALE;
          if (ATOM) atomicAdd((float*)&C[(size_t)row * ldc + col], v);
          else      stf(&C[(size_t)row * ldc + col], v);
        }
      }
    }
  }
}

template<int MODE, bool CT, bool ATOM, typename TC>
__global__ __launch_bounds__(256)
void mgemm(const float* __restrict__ A, const half_t* __restrict__ BT,
           TC* __restrict__ C, int M, int N, int Kd,
           int lda, int ldb, int ldc, int hdiv, int kdiv, int kc,
           long long sAb, long long sAh, long long sBb, long long sBh,
           long long sCb, long long sCh,
           const float* __restrict__ bias, const float* __restrict__ rvec)
{
  __shared__ GemmLds L;
  mgemm_body<MODE,CT,ATOM,TC>(L, threadIdx.x, blockIdx.x, blockIdx.y, blockIdx.z,
                              A, BT, C, M, N, Kd, lda, ldb, ldc, hdiv, kdiv, kc,
                              sAb, sAh, sBb, sBh, sCb, sCh, bias, rvec);
}

// ---------------------------------------------------------------------------
// FUSED (1024 threads):
//  blocks 0-31   : cp+alpha scan (reads p16, writes alpha fp32)
//  blocks 32-127 : u GEMM — 4 virtual 256-thr blocks per block, lockstep
//  blocks 128+   : vT projection shells (only launched when ws fits vtbuf)
// Subgroups share __syncthreads legally: same Kd -> identical barrier counts.
// ---------------------------------------------------------------------------
union MidLds { GemmLds g[4]; ScanLds s; };

__global__ __launch_bounds__(1024)
void fused_mid(const half_t* __restrict__ p16, float* __restrict__ alpha_slot,
               const float* __restrict__ qbuf, const half_t* __restrict__ kbuf,
               float* __restrict__ u_buf,
               const float* __restrict__ key, const half_t* __restrict__ wt_v,
               half_t* __restrict__ vtbuf, const float* __restrict__ b_value)
{
  __shared__ MidLds lds;
  int blk = blockIdx.x;
  int tid = threadIdx.x;

  if (blk >= 32) {
    int sg = tid >> 8, t256 = tid & 255;
    if (blk < 128) {                     // ---- u GEMM: vb in [0,384) ----
      int vb = (blk - 32) * 4 + sg;
      int bx = vb % 24; int t = vb / 24;
      int by = t & 1;   int bz = t >> 1;
      mgemm_body<2,false,false,float>(lds.g[sg], t256, bx, by, bz, qbuf, kbuf, u_buf,
          256, 3000, 512, 512, 512, 3000, 1, 1, 512,
          131072, 0, 1536000, 0, 768000, 0, nullptr, nullptr);
    } else {                             // ---- vT proj: vb in [0,752) ----
      int vb = (blk - 128) * 4 + sg;
      int bx = vb & 3; int by = vb >> 2;
      mgemm_body<0,true,false,half_t>(lds.g[sg], t256, bx, by, 0, key, wt_v, vtbuf,
          24000, 512, 512, 512, 512, 24000, 1, 1, 512,
          0, 0, 0, 0, 0, 0, b_value, nullptr);
    }
    return;
  }

  // ---- scan for chain blk: 1024 thr x 4 elems (3000 = 750x4) ----
  float (&wsA)[2][16] = lds.s.wsA;
  float (&wsB)[2][16] = lds.s.wsB;
  int lane = tid & 63, wid = tid >> 6;
  int k0 = tid * 4;
  bool act = (k0 < 3000);
  size_t zbase = (size_t)blk * 768000;   // 256*3000

  f32x4 a_prev = {0.f, 0.f, 0.f, 0.f};
  if (tid == 0) a_prev[0] = 1.f;

  f32x4 pc = {0.f,0.f,0.f,0.f}, pv = {0.f,0.f,0.f,0.f};
  if (act) {
    half2v a0 = *(const half2v*)&p16[zbase + k0];
    half2v a1 = *(const half2v*)&p16[zbase + k0 + 2];
    half2v b0 = *(const half2v*)&p16[zbase + 3000 + k0];
    half2v b1 = *(const half2v*)&p16[zbase + 3000 + k0 + 2];
    pc[0] = (float)a0[0]; pc[1] = (float)a0[1]; pc[2] = (float)a1[0]; pc[3] = (float)a1[1];
    pv[0] = (float)b0[0]; pv[1] = (float)b0[1]; pv[2] = (float)b1[0]; pv[3] = (float)b1[1];
  }

  f32x4 cpv;
  { // prologue: cp row 0 (multiplicative DPP scan)
    float l[4], m = 1.f;
    #pragma unroll
    for (int c = 0; c < 4; c++) {
      l[c] = m;
      m *= fminf(fmaxf(1.f - pc[c], EPSV), 1.f);
    }
    float incl = wave_iscan_mul(m);
    if (lane == 63) wsA[1][wid] = incl;
    float exclw = incl * frcp(fmaxf(m, 1e-30f));
    block_sync_lds();
    float base = exclw * cross_prod16(&wsA[1][0], wid);
    #pragma unroll
    for (int c = 0; c < 4; c++) cpv[c] = base * l[c];
  }

  for (int i = 0; i < 256; i++) {
    int par = i & 1;
    // scan2: inclusive cumsum of a_prev * rcp(clip(cp_i))
    float t4[4], s2 = 0.f;
    #pragma unroll
    for (int c = 0; c < 4; c++) {
      s2 = fmaf(a_prev[c], frcp(fmaxf(cpv[c], EPSV)), s2);
      t4[c] = s2;
    }
    float incl2 = wave_iscan_add(s2);
    if (lane == 63) wsB[par][wid] = incl2;
    float excl2 = incl2 - s2;

    // scan1: cp for row i+1 (multiplicative, recurrence-independent)
    f32x4 pn = pv;
    float l[4], m = 1.f;
    #pragma unroll
    for (int c = 0; c < 4; c++) {
      l[c] = m;
      m *= fminf(fmaxf(1.f - pn[c], EPSV), 1.f);
    }
    float incl1 = wave_iscan_mul(m);
    if (lane == 63) wsA[par][wid] = incl1;
    float excl1 = incl1 * frcp(fmaxf(m, 1e-30f));

    block_sync_lds();                    // the single (LDS-only) barrier

    float off = excl2 + cross_sum16(&wsB[par][0], wid);
    size_t rbase = zbase + (size_t)i * 3000;
    f32x4 an;
    #pragma unroll
    for (int c = 0; c < 4; c++) an[c] = pc[c] * cpv[c] * (off + t4[c]);
    a_prev = an;
    if (act) *(f32x4*)&alpha_slot[rbase + k0] = an;

    float base1 = excl1 * cross_prod16(&wsA[par][0], wid);
    #pragma unroll
    for (int c = 0; c < 4; c++) cpv[c] = base1 * l[c];
    pc = pn;
    if (i < 254 && act) {                // prefetch p row i+2
      size_t nb = zbase + (size_t)(i + 2) * 3000 + k0;
      half2v b0 = *(const half2v*)&p16[nb];
      half2v b1 = *(const half2v*)&p16[nb + 2];
      pv[0] = (float)b0[0]; pv[1] = (float)b0[1]; pv[2] = (float)b1[0]; pv[3] = (float)b1[1];
    }
  }
}

// ---------------------------------------------------------------------------
// Chunkwise beta (unchanged).
// ---------------------------------------------------------------------------
__global__ __launch_bounds__(256)
void beta_kernel(const float* __restrict__ ubuf, const float* __restrict__ alpha_slot,
                 float* __restrict__ beta_slot)
{
  __shared__ float se[3008];
  __shared__ float dn[3008];
  __shared__ float tt[3024];
  __shared__ float red[4];
  int bq = blockIdx.x;
  int b = bq >> 8, q = bq & 255;
  int tid = threadIdx.x;
  int lane = tid & 63, wid = tid >> 6;
  const float* urow = ubuf + (size_t)bq * 3000;
  float lmax = -3.0e38f;
  for (int i = tid; i < 3000; i += 256) { float v = urow[i]; se[i] = v; lmax = fmaxf(lmax, v); }
  #pragma unroll
  for (int d = 32; d > 0; d >>= 1) lmax = fmaxf(lmax, __shfl_xor(lmax, d));
  if (lane == 0) red[wid] = lmax;
  __syncthreads();
  float umax = fmaxf(fmaxf(red[0], red[1]), fmaxf(red[2], red[3]));
  for (int i = tid; i < 3000; i += 256) se[i] = fmaxf(expf(se[i] - umax), 1e-5f);
  if (tid < 24) tt[3000 + tid] = 0.f;
  __syncthreads();
  for (int k = tid; k < 3000; k += 256) {
    int lo = k - 15; if (lo < 0) lo = 0;
    float s = 0.f;
    for (int j = lo; j <= k; j++) s += se[j];
    dn[k] = s;
  }
  __syncthreads();
  for (int h = 0; h < 4; h++) {
    const float* arow = alpha_slot + ((size_t)((b * 4 + h) * 256 + q)) * 3000;
    for (int i = tid; i < 3000; i += 256) tt[i] = arow[i] * frcp(dn[i]);
    __syncthreads();
    float* brow = beta_slot + ((size_t)((b * 4 + h) * 256 + q)) * 3000;
    for (int k = tid; k < 3000; k += 256) {
      float s = 0.f;
      #pragma unroll
      for (int j = 0; j < 16; j++) s += tt[k + j];
      brow[k] = se[k] * s;
    }
    __syncthreads();
  }
}

// ---------------------------------------------------------------------------
extern "C" void kernel_launch(void* const* d_in, const int* in_sizes, int n_in,
                              void* d_out, int out_size, void* d_ws, size_t ws_size,
                              hipStream_t stream)
{
  const float* key        = (const float*)d_in[0];
  const float* query      = (const float*)d_in[1];
  const float* w_key_ma   = (const float*)d_in[2];
  const float* b_key_ma   = (const float*)d_in[3];
  const float* w_query_ma = (const float*)d_in[4];
  const float* b_query_ma = (const float*)d_in[5];
  const float* rvec       = (const float*)d_in[6];
  const float* w_key_ca   = (const float*)d_in[7];
  const float* b_key_ca   = (const float*)d_in[8];
  const float* w_query_ca = (const float*)d_in[9];
  const float* b_query_ca = (const float*)d_in[10];
  const float* w_value    = (const float*)d_in[11];
  const float* b_value    = (const float*)d_in[12];

  // Outputs FP32: cv | alpha | beta, flat.
  float* out       = (float*)d_out;
  float* cv_out    = out;                                  // (8,256,512)
  float* alpha_out = out + (size_t)1048576;                // (8,4,256,3000)
  float* beta_out  = alpha_out + (size_t)24576000;         // (8,4,256,3000)

  // p_choose lives as fp16 in the beta slot's first half (dead before beta
  // is written). Workspace v1 (55.97MB): kbuf | qbuf | u | 5x wt.
  // v2 (80.54MB): + vtbuf so the vT projection fuses into fused_mid.
  half_t* p16    = (half_t*)beta_out;
  half_t* kbuf   = (half_t*)d_ws;                              // 24000x512 f16
  float*  qbuf   = (float*)((char*)d_ws + 24576000);           // 2048x512 f32
  float*  u_buf  = (float*)((char*)d_ws + 28770304);           // 8x256x3000 f32
  half_t* wt_qma = (half_t*)((char*)d_ws + 53346304);
  half_t* wt_kma = (half_t*)((char*)d_ws + 53870592);
  half_t* wt_qca = (half_t*)((char*)d_ws + 54394880);
  half_t* wt_kca = (half_t*)((char*)d_ws + 54919168);
  half_t* wt_v   = (half_t*)((char*)d_ws + 55443456);
  if (ws_size < (size_t)55967744) return;
  bool v2 = ws_size >= (size_t)80543744;
  half_t* vtbuf = v2 ? (half_t*)((char*)d_ws + 55967744) : kbuf;

  dim3 blk(256);
  dim3 tgrid(16, 16);

  hipMemsetAsync(cv_out, 0, (size_t)1048576 * sizeof(float), stream);  // cv K-split atomics

  // weight transposes (f32 -> f16 [N][K])
  wtrans<<<tgrid, blk, 0, stream>>>(w_query_ma, wt_qma);
  wtrans<<<tgrid, blk, 0, stream>>>(w_key_ma,   wt_kma);
  wtrans<<<tgrid, blk, 0, stream>>>(w_query_ca, wt_qca);
  wtrans<<<tgrid, blk, 0, stream>>>(w_key_ca,   wt_kca);
  wtrans<<<tgrid, blk, 0, stream>>>(w_value,    wt_v);

  // --- MA path: projections, p_choose (fp16) into beta-slot lower half ---
  mgemm<0,false,false,float ><<<dim3(4,16,1),  blk, 0, stream>>>(query, wt_qma, qbuf, 2048, 512, 512, 512,512,512, 1,1,512, 0,0,0,0,0,0, b_query_ma, nullptr);
  mgemm<0,false,false,half_t><<<dim3(4,188,1), blk, 0, stream>>>(key,   wt_kma, kbuf, 24000,512, 512, 512,512,512, 1,1,512, 0,0,0,0,0,0, b_key_ma,   nullptr);
  mgemm<1,false,false,half_t><<<dim3(24,2,32), blk, 0, stream>>>(qbuf,  kbuf, p16, 256,3000, 128, 512,512,3000, 4,1,128,
      131072,128, 1536000,128, 3072000,768000, nullptr, rvec);

  // --- CA projections ---
  mgemm<0,false,false,float ><<<dim3(4,16,1),  blk, 0, stream>>>(query, wt_qca, qbuf, 2048, 512, 512, 512,512,512, 1,1,512, 0,0,0,0,0,0, b_query_ca, nullptr);
  mgemm<0,false,false,half_t><<<dim3(4,188,1), blk, 0, stream>>>(key,   wt_kca, kbuf, 24000,512, 512, 512,512,512, 1,1,512, 0,0,0,0,0,0, b_key_ca,   nullptr);

  // --- FUSED: scan (0-31) + u GEMM (32-127) [+ vT shells (128-315) in v2] ---
  fused_mid<<<dim3(v2 ? 316 : 128), dim3(1024), 0, stream>>>(p16, alpha_out, qbuf, kbuf, u_buf,
                                                             key, wt_v, vtbuf, b_value);

  // --- v1 fallback: vT projection into kbuf after fused (kbuf dead) ---
  if (!v2)
    mgemm<0,true,false,half_t><<<dim3(4,188,1), blk, 0, stream>>>(key, wt_v, kbuf, 24000,512, 512, 512,512,24000, 1,1,512, 0,0,0,0,0,0, b_value, nullptr);

  // --- chunkwise beta (overwrites p16 region — p16 dead after scan) ---
  beta_kernel<<<dim3(2048), blk, 0, stream>>>(u_buf, alpha_out, beta_out);

  // --- cv = beta @ v via MFMA, K-split x8 + atomicAdd ---
  mgemm<3,false,true,float><<<dim3(1,2,256), blk, 0, stream>>>(beta_out, vtbuf, cv_out, 256,128,3000, 3000,24000,512, 4,8,384,
      3072000,768000, 3000,3072000, 131072,128, nullptr, nullptr);
}

// Round 14
// 606.996 us; speedup vs baseline: 4.2722x; 1.1241x over previous
//
#include <hip/hip_runtime.h>
#include <hip/hip_bf16.h>
#include <math.h>

#define EPSV 1e-6f
#define INV_SCALE 0.04419417382415922f   // 1/sqrt(512)

typedef _Float16 half_t;
typedef __attribute__((ext_vector_type(8))) _Float16 half8;
typedef __attribute__((ext_vector_type(4))) _Float16 half4v;
typedef __attribute__((ext_vector_type(2))) _Float16 half2v;
typedef __attribute__((ext_vector_type(4))) float    f32x4;

__device__ __forceinline__ float ldf(const float* p)  { return *p; }
__device__ __forceinline__ float ldf(const half_t* p) { return (float)*p; }
__device__ __forceinline__ void  stf(float* p, float v)  { *p = v; }
__device__ __forceinline__ void  stf(half_t* p, float v) { *p = (half_t)v; }
__device__ __forceinline__ float frcp(float x) { return __builtin_amdgcn_rcpf(x); }

// ---------------------------------------------------------------------------
// DPP wave-64 inclusive scans (validated rounds 11-13).
// ---------------------------------------------------------------------------
template<int CTRL, int RMASK>
__device__ __forceinline__ float dpp_add_step(float x) {
  int t = __builtin_amdgcn_update_dpp(0, __float_as_int(x), CTRL, RMASK, 0xf, true);
  return x + __int_as_float(t);
}
template<int CTRL, int RMASK>
__device__ __forceinline__ float dpp_mul_step(float x) {
  int t = __builtin_amdgcn_update_dpp(0x3f800000, __float_as_int(x), CTRL, RMASK, 0xf, false);
  return x * __int_as_float(t);
}
__device__ __forceinline__ float wave_iscan_add(float x) {
  x = dpp_add_step<0x111,0xf>(x);
  x = dpp_add_step<0x112,0xf>(x);
  x = dpp_add_step<0x114,0xf>(x);
  x = dpp_add_step<0x118,0xf>(x);
  x = dpp_add_step<0x142,0xa>(x);
  x = dpp_add_step<0x143,0xc>(x);
  return x;
}
__device__ __forceinline__ float wave_iscan_mul(float x) {
  x = dpp_mul_step<0x111,0xf>(x);
  x = dpp_mul_step<0x112,0xf>(x);
  x = dpp_mul_step<0x114,0xf>(x);
  x = dpp_mul_step<0x118,0xf>(x);
  x = dpp_mul_step<0x142,0xa>(x);
  x = dpp_mul_step<0x143,0xc>(x);
  return x;
}

// LDS-only barrier (skips the vmcnt(0) drain __syncthreads emits).
__device__ __forceinline__ void block_sync_lds() {
  asm volatile("s_waitcnt lgkmcnt(0)" ::: "memory");
  __builtin_amdgcn_s_barrier();
  asm volatile("" ::: "memory");
}

// Cross-wave prefix helpers over 16 wave-sums.
__device__ __forceinline__ float cross_sum16(const float* ws, int wid) {
  f32x4 a = *(const f32x4*)&ws[0];
  f32x4 b = *(const f32x4*)&ws[4];
  f32x4 c = *(const f32x4*)&ws[8];
  f32x4 d = *(const f32x4*)&ws[12];
  float s = 0.f;
  #pragma unroll
  for (int j = 0; j < 4; j++) s += (wid > j)      ? a[j] : 0.f;
  #pragma unroll
  for (int j = 0; j < 4; j++) s += (wid > 4 + j)  ? b[j] : 0.f;
  #pragma unroll
  for (int j = 0; j < 4; j++) s += (wid > 8 + j)  ? c[j] : 0.f;
  #pragma unroll
  for (int j = 0; j < 4; j++) s += (wid > 12 + j) ? d[j] : 0.f;
  return s;
}
__device__ __forceinline__ float cross_prod16(const float* ws, int wid) {
  f32x4 a = *(const f32x4*)&ws[0];
  f32x4 b = *(const f32x4*)&ws[4];
  f32x4 c = *(const f32x4*)&ws[8];
  f32x4 d = *(const f32x4*)&ws[12];
  float p = 1.f;
  #pragma unroll
  for (int j = 0; j < 4; j++) p *= (wid > j)      ? a[j] : 1.f;
  #pragma unroll
  for (int j = 0; j < 4; j++) p *= (wid > 4 + j)  ? b[j] : 1.f;
  #pragma unroll
  for (int j = 0; j < 4; j++) p *= (wid > 8 + j)  ? c[j] : 1.f;
  #pragma unroll
  for (int j = 0; j < 4; j++) p *= (wid > 12 + j) ? d[j] : 1.f;
  return p;
}

// ---------------------------------------------------------------------------
// All five weight transposes in ONE dispatch: grid (16,16,5), z picks weight.
// WT[n][k] = (half)W[k][n], each 512x512.
// ---------------------------------------------------------------------------
__global__ __launch_bounds__(256)
void wtrans_all(const float* __restrict__ s0, half_t* __restrict__ d0,
                const float* __restrict__ s1, half_t* __restrict__ d1,
                const float* __restrict__ s2, half_t* __restrict__ d2,
                const float* __restrict__ s3, half_t* __restrict__ d3,
                const float* __restrict__ s4, half_t* __restrict__ d4)
{
  __shared__ float t[32][33];
  const float* W; half_t* WT;
  switch (blockIdx.z) {
    case 0: W = s0; WT = d0; break;
    case 1: W = s1; WT = d1; break;
    case 2: W = s2; WT = d2; break;
    case 3: W = s3; WT = d3; break;
    default: W = s4; WT = d4; break;
  }
  int bx = blockIdx.x, by = blockIdx.y;
  int tid = threadIdx.x;
  int r = tid >> 3, cq = tid & 7;
  float4 v = *(const float4*)&W[(size_t)(bx * 32 + r) * 512 + by * 32 + cq * 4];
  t[r][cq * 4 + 0] = v.x; t[r][cq * 4 + 1] = v.y;
  t[r][cq * 4 + 2] = v.z; t[r][cq * 4 + 3] = v.w;
  __syncthreads();
  half4v o;
  o[0] = (half_t)t[cq * 4 + 0][r];
  o[1] = (half_t)t[cq * 4 + 1][r];
  o[2] = (half_t)t[cq * 4 + 2][r];
  o[3] = (half_t)t[cq * 4 + 3][r];
  *(half4v*)&WT[(size_t)(by * 32 + r) * 512 + bx * 32 + cq * 4] = o;
}

// Concatenated biases for the merged N=1024 projections (v3 only).
__global__ __launch_bounds__(256)
void catbias(const float* __restrict__ a, const float* __restrict__ b,
             const float* __restrict__ c, const float* __restrict__ d,
             float* __restrict__ cbq, float* __restrict__ cbk)
{
  int t = threadIdx.x;
  for (int i = t; i < 512; i += 256) {
    cbq[i] = a[i]; cbq[512 + i] = b[i];
    cbk[i] = c[i]; cbk[512 + i] = d[i];
  }
}

// ---------------------------------------------------------------------------
// MFMA GEMM body. tid in [0,256). K-split via kdiv/kc (kc%32==0); ATOM ->
// atomicAdd epilogue. CT -> store C transposed (vT).
// ---------------------------------------------------------------------------
struct GemmLds { half_t As[4][128][8]; half_t Bs[4][128][8]; };
struct __align__(16) ScanLds { float wsA[2][16]; float wsB[2][16]; };

template<int MODE, bool CT, bool ATOM, typename TC>
__device__ __forceinline__
void mgemm_body(GemmLds& L, int tid, int bxx, int byy, int bzz,
                const float* __restrict__ A, const half_t* __restrict__ BT,
                TC* __restrict__ C, int M, int N, int Kd,
                int lda, int ldb, int ldc, int hdiv, int kdiv, int kc,
                long long sAb, long long sAh, long long sBb, long long sBh,
                long long sCb, long long sCh,
                const float* __restrict__ bias, const float* __restrict__ rvec)
{
  int ks = bzz % kdiv; int zz = bzz / kdiv;
  int bz = zz / hdiv, hz = zz - bz * hdiv;
  A  += (size_t)bz * sAb + (size_t)hz * sAh + (size_t)ks * kc;
  BT += (size_t)bz * sBb + (size_t)hz * sBh + (size_t)ks * kc;
  C  += (size_t)bz * sCb + (size_t)hz * sCh;
  int Ke = Kd - ks * kc; if (Ke > kc) Ke = kc;

  int lane = tid & 63, wid = tid >> 6;
  int wm = wid >> 1, wn = wid & 1;
  int m0 = byy * 128, n0 = bxx * 128;

  f32x4 acc[4][4] = {};

  for (int k0 = 0; k0 < Ke; k0 += 32) {
    #pragma unroll
    for (int i = 0; i < 4; i++) {            // A: 128x32 f32 -> f16
      int ch = tid + i * 256;
      int m = ch >> 3, cq = ch & 7, k = cq * 4;
      float4 v = make_float4(0.f, 0.f, 0.f, 0.f);
      if (m0 + m < M && k0 + k < Ke) v = *(const float4*)&A[(size_t)(m0 + m) * lda + k0 + k];
      half4v h;
      h[0] = (half_t)v.x; h[1] = (half_t)v.y; h[2] = (half_t)v.z; h[3] = (half_t)v.w;
      *(half4v*)&L.As[cq >> 1][m][(cq & 1) * 4] = h;
    }
    #pragma unroll
    for (int i = 0; i < 2; i++) {            // B: 128x32 f16
      int ch = tid + i * 256;
      int n = ch >> 2, kb = ch & 3;
      half8 v = {(_Float16)0,(_Float16)0,(_Float16)0,(_Float16)0,
                 (_Float16)0,(_Float16)0,(_Float16)0,(_Float16)0};
      if (n0 + n < N && k0 + kb * 8 < Ke)
        v = *(const half8*)&BT[(size_t)(n0 + n) * ldb + k0 + kb * 8];
      *(half8*)&L.Bs[kb][n][0] = v;
    }
    __syncthreads();
    int kb = lane >> 4, r = lane & 15;
    half8 af[4], bfv[4];
    #pragma unroll
    for (int mi = 0; mi < 4; mi++) af[mi]  = *(const half8*)&L.As[kb][wm * 64 + mi * 16 + r][0];
    #pragma unroll
    for (int ni = 0; ni < 4; ni++) bfv[ni] = *(const half8*)&L.Bs[kb][wn * 64 + ni * 16 + r][0];
    #pragma unroll
    for (int mi = 0; mi < 4; mi++)
      #pragma unroll
      for (int ni = 0; ni < 4; ni++)
        acc[mi][ni] = __builtin_amdgcn_mfma_f32_16x16x32_f16(af[mi], bfv[ni], acc[mi][ni], 0, 0, 0);
    __syncthreads();
  }

  float radd = (MODE == 1) ? rvec[hz] : 0.f;
  int r = lane & 15, g = lane >> 4;
  #pragma unroll
  for (int mi = 0; mi < 4; mi++) {
    #pragma unroll
    for (int ni = 0; ni < 4; ni++) {
      int col = n0 + wn * 64 + ni * 16 + r;
      if (col >= N) continue;
      float bv = (MODE == 0) ? bias[col] : 0.f;
      if (CT) {
        int row0 = m0 + wm * 64 + mi * 16 + g * 4;
        if (row0 + 3 < M) {
          half4v o;
          #pragma unroll
          for (int j = 0; j < 4; j++) o[j] = (half_t)(acc[mi][ni][j] + bv);
          *(half4v*)&((half_t*)C)[(size_t)col * ldc + row0] = o;
        }
      } else {
        #pragma unroll
        for (int j = 0; j < 4; j++) {
          int row = m0 + wm * 64 + mi * 16 + g * 4 + j;
          if (row >= M) continue;
          float v = acc[mi][ni][j];
          if (MODE == 0)      v += bv;
          else if (MODE == 1) v = frcp(1.f + expf(-(v * INV_SCALE + radd)));
          else if (MODE == 2) v *= INV_SCALE;
          if (ATOM) atomicAdd((float*)&C[(size_t)row * ldc + col], v);
          else      stf(&C[(size_t)row * ldc + col], v);
        }
      }
    }
  }
}

template<int MODE, bool CT, bool ATOM, typename TC>
__global__ __launch_bounds__(256)
void mgemm(const float* __restrict__ A, const half_t* __restrict__ BT,
           TC* __restrict__ C, int M, int N, int Kd,
           int lda, int ldb, int ldc, int hdiv, int kdiv, int kc,
           long long sAb, long long sAh, long long sBb, long long sBh,
           long long sCb, long long sCh,
           const float* __restrict__ bias, const float* __restrict__ rvec)
{
  __shared__ GemmLds L;
  mgemm_body<MODE,CT,ATOM,TC>(L, threadIdx.x, blockIdx.x, blockIdx.y, blockIdx.z,
                              A, BT, C, M, N, Kd, lda, ldb, ldc, hdiv, kdiv, kc,
                              sAb, sAh, sBb, sBh, sCb, sCh, bias, rvec);
}

// ---------------------------------------------------------------------------
// FUSED (1024 threads):
//  blocks 0-31        : cp+alpha scan at s_setprio(1), NT alpha stores
//  blocks 32-127      : u GEMM — 4 virtual 256-thr blocks per block
//  blocks 128-128+nvt : vT projection shells (when vtbuf is separate)
// ---------------------------------------------------------------------------
union MidLds { GemmLds g[4]; ScanLds s; };

__global__ __launch_bounds__(1024)
void fused_mid(const half_t* __restrict__ p16, float* __restrict__ alpha_slot,
               const float* __restrict__ qa, const half_t* __restrict__ kb,
               int lda_u, int ldb_u, long long sAb_u, long long sBb_u,
               float* __restrict__ u_buf,
               const float* __restrict__ key, const half_t* __restrict__ wt_v,
               half_t* __restrict__ vtbuf, const float* __restrict__ b_value)
{
  __shared__ MidLds lds;
  int blk = blockIdx.x;
  int tid = threadIdx.x;

  if (blk >= 32) {
    int sg = tid >> 8, t256 = tid & 255;
    if (blk < 128) {                     // ---- u GEMM: vb in [0,384) ----
      int vb = (blk - 32) * 4 + sg;
      int bx = vb % 24; int t = vb / 24;
      int by = t & 1;   int bz = t >> 1;
      mgemm_body<2,false,false,float>(lds.g[sg], t256, bx, by, bz, qa, kb, u_buf,
          256, 3000, 512, lda_u, ldb_u, 3000, 1, 1, 512,
          sAb_u, 0, sBb_u, 0, 768000, 0, nullptr, nullptr);
    } else {                             // ---- vT proj: vb in [0,752) ----
      int vb = (blk - 128) * 4 + sg;
      int bx = vb & 3; int by = vb >> 2;
      mgemm_body<0,true,false,half_t>(lds.g[sg], t256, bx, by, 0, key, wt_v, vtbuf,
          24000, 512, 512, 512, 512, 24000, 1, 1, 512,
          0, 0, 0, 0, 0, 0, b_value, nullptr);
    }
    return;
  }

  // ---- scan for chain blk: 1024 thr x 4 elems (3000 = 750x4) ----
  __builtin_amdgcn_s_setprio(1);         // T5: win issue arbitration vs GEMM waves
  float (&wsA)[2][16] = lds.s.wsA;
  float (&wsB)[2][16] = lds.s.wsB;
  int lane = tid & 63, wid = tid >> 6;
  int k0 = tid * 4;
  bool act = (k0 < 3000);
  size_t zbase = (size_t)blk * 768000;   // 256*3000

  f32x4 a_prev = {0.f, 0.f, 0.f, 0.f};
  if (tid == 0) a_prev[0] = 1.f;

  f32x4 pc = {0.f,0.f,0.f,0.f}, pv = {0.f,0.f,0.f,0.f};
  if (act) {
    half2v a0 = *(const half2v*)&p16[zbase + k0];
    half2v a1 = *(const half2v*)&p16[zbase + k0 + 2];
    half2v b0 = *(const half2v*)&p16[zbase + 3000 + k0];
    half2v b1 = *(const half2v*)&p16[zbase + 3000 + k0 + 2];
    pc[0] = (float)a0[0]; pc[1] = (float)a0[1]; pc[2] = (float)a1[0]; pc[3] = (float)a1[1];
    pv[0] = (float)b0[0]; pv[1] = (float)b0[1]; pv[2] = (float)b1[0]; pv[3] = (float)b1[1];
  }

  f32x4 cpv;
  { // prologue: cp row 0 (multiplicative DPP scan)
    float l[4], m = 1.f;
    #pragma unroll
    for (int c = 0; c < 4; c++) {
      l[c] = m;
      m *= fminf(fmaxf(1.f - pc[c], EPSV), 1.f);
    }
    float incl = wave_iscan_mul(m);
    if (lane == 63) wsA[1][wid] = incl;
    float exclw = incl * frcp(fmaxf(m, 1e-30f));
    block_sync_lds();
    float base = exclw * cross_prod16(&wsA[1][0], wid);
    #pragma unroll
    for (int c = 0; c < 4; c++) cpv[c] = base * l[c];
  }

  for (int i = 0; i < 256; i++) {
    int par = i & 1;
    // scan2: inclusive cumsum of a_prev * rcp(clip(cp_i))
    float t4[4], s2 = 0.f;
    #pragma unroll
    for (int c = 0; c < 4; c++) {
      s2 = fmaf(a_prev[c], frcp(fmaxf(cpv[c], EPSV)), s2);
      t4[c] = s2;
    }
    float incl2 = wave_iscan_add(s2);
    if (lane == 63) wsB[par][wid] = incl2;
    float excl2 = incl2 - s2;

    // scan1: cp for row i+1 (multiplicative, recurrence-independent)
    f32x4 pn = pv;
    float l[4], m = 1.f;
    #pragma unroll
    for (int c = 0; c < 4; c++) {
      l[c] = m;
      m *= fminf(fmaxf(1.f - pn[c], EPSV), 1.f);
    }
    float incl1 = wave_iscan_mul(m);
    if (lane == 63) wsA[par][wid] = incl1;
    float excl1 = incl1 * frcp(fmaxf(m, 1e-30f));

    block_sync_lds();                    // the single (LDS-only) barrier

    float off = excl2 + cross_sum16(&wsB[par][0], wid);
    size_t rbase = zbase + (size_t)i * 3000;
    f32x4 an;
    #pragma unroll
    for (int c = 0; c < 4; c++) an[c] = pc[c] * cpv[c] * (off + t4[c]);
    a_prev = an;
    if (act) __builtin_nontemporal_store(an, (f32x4*)&alpha_slot[rbase + k0]);

    float base1 = excl1 * cross_prod16(&wsA[par][0], wid);
    #pragma unroll
    for (int c = 0; c < 4; c++) cpv[c] = base1 * l[c];
    pc = pn;
    if (i < 254 && act) {                // prefetch p row i+2
      size_t nb = zbase + (size_t)(i + 2) * 3000 + k0;
      half2v b0 = *(const half2v*)&p16[nb];
      half2v b1 = *(const half2v*)&p16[nb + 2];
      pv[0] = (float)b0[0]; pv[1] = (float)b0[1]; pv[2] = (float)b1[0]; pv[3] = (float)b1[1];
    }
  }
}

// ---------------------------------------------------------------------------
// Chunkwise beta — streaming passes vectorized to f32x4 (rows are 16B-aligned:
// 3000 f32 = 750 exact f32x4 chunks; bases are multiples of 12000B).
// ---------------------------------------------------------------------------
__global__ __launch_bounds__(256)
void beta_kernel(const float* __restrict__ ubuf, const float* __restrict__ alpha_slot,
                 float* __restrict__ beta_slot)
{
  __shared__ __align__(16) float se[3008];
  __shared__ __align__(16) float dn[3008];
  __shared__ __align__(16) float tt[3024];
  __shared__ float red[4];
  int bq = blockIdx.x;
  int b = bq >> 8, q = bq & 255;
  int tid = threadIdx.x;
  int lane = tid & 63, wid = tid >> 6;
  const float* urow = ubuf + (size_t)bq * 3000;
  float lmax = -3.0e38f;
  for (int c = tid; c < 750; c += 256) {
    f32x4 v = *(const f32x4*)&urow[c * 4];
    *(f32x4*)&se[c * 4] = v;
    lmax = fmaxf(lmax, fmaxf(fmaxf(v[0], v[1]), fmaxf(v[2], v[3])));
  }
  #pragma unroll
  for (int d = 32; d > 0; d >>= 1) lmax = fmaxf(lmax, __shfl_xor(lmax, d));
  if (lane == 0) red[wid] = lmax;
  __syncthreads();
  float umax = fmaxf(fmaxf(red[0], red[1]), fmaxf(red[2], red[3]));
  for (int c = tid; c < 750; c += 256) {
    f32x4 v = *(const f32x4*)&se[c * 4];
    #pragma unroll
    for (int j = 0; j < 4; j++) v[j] = fmaxf(expf(v[j] - umax), 1e-5f);
    *(f32x4*)&se[c * 4] = v;
  }
  if (tid < 24) tt[3000 + tid] = 0.f;              // forward-window zero pad
  __syncthreads();
  for (int k = tid; k < 3000; k += 256) {
    int lo = k - 15; if (lo < 0) lo = 0;
    float s = 0.f;
    for (int j = lo; j <= k; j++) s += se[j];
    dn[k] = s;
  }
  __syncthreads();
  for (int h = 0; h < 4; h++) {
    const float* arow = alpha_slot + ((size_t)((b * 4 + h) * 256 + q)) * 3000;
    for (int c = tid; c < 750; c += 256) {
      f32x4 a = *(const f32x4*)&arow[c * 4];
      f32x4 d = *(const f32x4*)&dn[c * 4];
      f32x4 o;
      #pragma unroll
      for (int j = 0; j < 4; j++) o[j] = a[j] * frcp(d[j]);
      *(f32x4*)&tt[c * 4] = o;
    }
    __syncthreads();
    float* brow = beta_slot + ((size_t)((b * 4 + h) * 256 + q)) * 3000;
    for (int c = tid; c < 750; c += 256) {
      f32x4 o;
      #pragma unroll
      for (int j = 0; j < 4; j++) {
        int k = c * 4 + j;
        float s = 0.f;
        #pragma unroll
        for (int w = 0; w < 16; w++) s += tt[k + w];
        o[j] = se[k] * s;
      }
      *(f32x4*)&brow[c * 4] = o;
    }
    __syncthreads();
  }
}

// ---------------------------------------------------------------------------
extern "C" void kernel_launch(void* const* d_in, const int* in_sizes, int n_in,
                              void* d_out, int out_size, void* d_ws, size_t ws_size,
                              hipStream_t stream)
{
  const float* key        = (const float*)d_in[0];
  const float* query      = (const float*)d_in[1];
  const float* w_key_ma   = (const float*)d_in[2];
  const float* b_key_ma   = (const float*)d_in[3];
  const float* w_query_ma = (const float*)d_in[4];
  const float* b_query_ma = (const float*)d_in[5];
  const float* rvec       = (const float*)d_in[6];
  const float* w_key_ca   = (const float*)d_in[7];
  const float* b_key_ca   = (const float*)d_in[8];
  const float* w_query_ca = (const float*)d_in[9];
  const float* b_query_ca = (const float*)d_in[10];
  const float* w_value    = (const float*)d_in[11];
  const float* b_value    = (const float*)d_in[12];

  // Outputs FP32: cv | alpha | beta, flat.
  float* out       = (float*)d_out;
  float* cv_out    = out;                                  // (8,256,512)
  float* alpha_out = out + (size_t)1048576;                // (8,4,256,3000)
  float* beta_out  = alpha_out + (size_t)24576000;         // (8,4,256,3000)
  half_t* p16      = (half_t*)beta_out;                    // p_choose fp16, dead before beta

  dim3 blk(256);
  bool v3 = ws_size >= (size_t)109322240;

  hipMemsetAsync(cv_out, 0, (size_t)1048576 * sizeof(float), stream);  // cv K-split atomics

  if (v3) {
    // v3 layout: kbuf2[24000][1024] | qbuf[2048][1024] f32 | u | vtbuf | wts | catbias
    half_t* kbuf2 = (half_t*)d_ws;
    float*  qbuf  = (float*)((char*)d_ws + 49152000);
    float*  u_buf = (float*)((char*)d_ws + 57540608);
    half_t* vtbuf = (half_t*)((char*)d_ws + 82116608);
    half_t* wt_q  = (half_t*)((char*)d_ws + 106692608);   // [1024][512]: qma rows 0-511, qca 512-1023
    half_t* wt_k  = (half_t*)((char*)d_ws + 107741184);   // [1024][512]: kma, kca
    half_t* wt_v  = (half_t*)((char*)d_ws + 108789760);
    float*  cb_q  = (float*)((char*)d_ws + 109314048);
    float*  cb_k  = (float*)((char*)d_ws + 109318144);

    wtrans_all<<<dim3(16,16,5), blk, 0, stream>>>(
        w_query_ma, wt_q, w_query_ca, wt_q + 262144,
        w_key_ma,   wt_k, w_key_ca,   wt_k + 262144,
        w_value,    wt_v);
    catbias<<<dim3(1), blk, 0, stream>>>(b_query_ma, b_query_ca, b_key_ma, b_key_ca, cb_q, cb_k);

    // merged projections: qall (2048x1024), kall (24000x1024)
    mgemm<0,false,false,float ><<<dim3(8,16,1),  blk, 0, stream>>>(query, wt_q, qbuf, 2048, 1024, 512, 512,512,1024, 1,1,512, 0,0,0,0,0,0, cb_q, nullptr);
    mgemm<0,false,false,half_t><<<dim3(8,188,1), blk, 0, stream>>>(key,   wt_k, kbuf2, 24000,1024, 512, 512,512,1024, 1,1,512, 0,0,0,0,0,0, cb_k, nullptr);

    // e_ma -> p16 (A = q_ma cols of qbuf, BT = k_ma cols of kbuf2)
    mgemm<1,false,false,half_t><<<dim3(24,2,32), blk, 0, stream>>>(qbuf, kbuf2, p16, 256,3000, 128, 1024,1024,3000, 4,1,128,
        262144,128, 3072000,128, 3072000,768000, nullptr, rvec);

    // FUSED: scan + u GEMM (q_ca/k_ca halves) + vT shells
    fused_mid<<<dim3(316), dim3(1024), 0, stream>>>(p16, alpha_out,
        qbuf + 512, kbuf2 + 512, 1024, 1024, 262144, 3072000,
        u_buf, key, wt_v, vtbuf, b_value);

    beta_kernel<<<dim3(2048), blk, 0, stream>>>(u_buf, alpha_out, beta_out);

    mgemm<3,false,true,float><<<dim3(1,2,256), blk, 0, stream>>>(beta_out, vtbuf, cv_out, 256,128,3000, 3000,24000,512, 4,8,384,
        3072000,768000, 3000,3072000, 131072,128, nullptr, nullptr);
  } else {
    // v1 fallback (round-13 structure): kbuf | qbuf | u | 5x wt. 55.97MB.
    if (ws_size < (size_t)55967744) return;
    half_t* kbuf   = (half_t*)d_ws;
    float*  qbuf   = (float*)((char*)d_ws + 24576000);
    float*  u_buf  = (float*)((char*)d_ws + 28770304);
    half_t* wt_qma = (half_t*)((char*)d_ws + 53346304);
    half_t* wt_kma = (half_t*)((char*)d_ws + 53870592);
    half_t* wt_qca = (half_t*)((char*)d_ws + 54394880);
    half_t* wt_kca = (half_t*)((char*)d_ws + 54919168);
    half_t* wt_v   = (half_t*)((char*)d_ws + 55443456);

    wtrans_all<<<dim3(16,16,5), blk, 0, stream>>>(
        w_query_ma, wt_qma, w_query_ca, wt_qca,
        w_key_ma,   wt_kma, w_key_ca,   wt_kca,
        w_value,    wt_v);

    mgemm<0,false,false,float ><<<dim3(4,16,1),  blk, 0, stream>>>(query, wt_qma, qbuf, 2048, 512, 512, 512,512,512, 1,1,512, 0,0,0,0,0,0, b_query_ma, nullptr);
    mgemm<0,false,false,half_t><<<dim3(4,188,1), blk, 0, stream>>>(key,   wt_kma, kbuf, 24000,512, 512, 512,512,512, 1,1,512, 0,0,0,0,0,0, b_key_ma,   nullptr);
    mgemm<1,false,false,half_t><<<dim3(24,2,32), blk, 0, stream>>>(qbuf,  kbuf, p16, 256,3000, 128, 512,512,3000, 4,1,128,
        131072,128, 1536000,128, 3072000,768000, nullptr, rvec);

    mgemm<0,false,false,float ><<<dim3(4,16,1),  blk, 0, stream>>>(query, wt_qca, qbuf, 2048, 512, 512, 512,512,512, 1,1,512, 0,0,0,0,0,0, b_query_ca, nullptr);
    mgemm<0,false,false,half_t><<<dim3(4,188,1), blk, 0, stream>>>(key,   wt_kca, kbuf, 24000,512, 512, 512,512,512, 1,1,512, 0,0,0,0,0,0, b_key_ca,   nullptr);

    // FUSED: scan + u GEMM only (vT serial after, into kbuf)
    fused_mid<<<dim3(128), dim3(1024), 0, stream>>>(p16, alpha_out,
        qbuf, kbuf, 512, 512, 131072, 1536000,
        u_buf, key, wt_v, kbuf, b_value);

    mgemm<0,true,false,half_t><<<dim3(4,188,1), blk, 0, stream>>>(key, wt_v, kbuf, 24000,512, 512, 512,512,24000, 1,1,512, 0,0,0,0,0,0, b_value, nullptr);

    beta_kernel<<<dim3(2048), blk, 0, stream>>>(u_buf, alpha_out, beta_out);

    mgemm<3,false,true,float><<<dim3(1,2,256), blk, 0, stream>>>(beta_out, kbuf, cv_out, 256,128,3000, 3000,24000,512, 4,8,384,
        3072000,768000, 3000,3072000, 131072,128, nullptr, nullptr);
  }
}

// Round 15
// 596.107 us; speedup vs baseline: 4.3503x; 1.0183x over previous
//
#include <hip/hip_runtime.h>
#include <hip/hip_bf16.h>
#include <math.h>

#define EPSV 1e-6f
#define INV_SCALE 0.04419417382415922f   // 1/sqrt(512)

typedef _Float16 half_t;
typedef __attribute__((ext_vector_type(8))) _Float16 half8;
typedef __attribute__((ext_vector_type(4))) _Float16 half4v;
typedef __attribute__((ext_vector_type(2))) _Float16 half2v;
typedef __attribute__((ext_vector_type(4))) float    f32x4;

__device__ __forceinline__ float ldf(const float* p)  { return *p; }
__device__ __forceinline__ float ldf(const half_t* p) { return (float)*p; }
__device__ __forceinline__ void  stf(float* p, float v)  { *p = v; }
__device__ __forceinline__ void  stf(half_t* p, float v) { *p = (half_t)v; }
__device__ __forceinline__ float frcp(float x) { return __builtin_amdgcn_rcpf(x); }

// ---------------------------------------------------------------------------
// DPP wave-64 inclusive scans (validated rounds 11-14).
// ---------------------------------------------------------------------------
template<int CTRL, int RMASK>
__device__ __forceinline__ float dpp_add_step(float x) {
  int t = __builtin_amdgcn_update_dpp(0, __float_as_int(x), CTRL, RMASK, 0xf, true);
  return x + __int_as_float(t);
}
template<int CTRL, int RMASK>
__device__ __forceinline__ float dpp_mul_step(float x) {
  int t = __builtin_amdgcn_update_dpp(0x3f800000, __float_as_int(x), CTRL, RMASK, 0xf, false);
  return x * __int_as_float(t);
}
__device__ __forceinline__ float wave_iscan_add(float x) {
  x = dpp_add_step<0x111,0xf>(x);
  x = dpp_add_step<0x112,0xf>(x);
  x = dpp_add_step<0x114,0xf>(x);
  x = dpp_add_step<0x118,0xf>(x);
  x = dpp_add_step<0x142,0xa>(x);
  x = dpp_add_step<0x143,0xc>(x);
  return x;
}
__device__ __forceinline__ float wave_iscan_mul(float x) {
  x = dpp_mul_step<0x111,0xf>(x);
  x = dpp_mul_step<0x112,0xf>(x);
  x = dpp_mul_step<0x114,0xf>(x);
  x = dpp_mul_step<0x118,0xf>(x);
  x = dpp_mul_step<0x142,0xa>(x);
  x = dpp_mul_step<0x143,0xc>(x);
  return x;
}

// LDS-only barrier (skips the vmcnt(0) drain __syncthreads emits).
__device__ __forceinline__ void block_sync_lds() {
  asm volatile("s_waitcnt lgkmcnt(0)" ::: "memory");
  __builtin_amdgcn_s_barrier();
  asm volatile("" ::: "memory");
}

// Cross-wave prefix helpers over 4 wave-sums (one f32x4 read + masked ops).
__device__ __forceinline__ float cross_sum4(const float* ws, int wid) {
  f32x4 a = *(const f32x4*)ws;
  float s = 0.f;
  #pragma unroll
  for (int j = 0; j < 4; j++) s += (wid > j) ? a[j] : 0.f;
  return s;
}
__device__ __forceinline__ float cross_prod4(const float* ws, int wid) {
  f32x4 a = *(const f32x4*)ws;
  float p = 1.f;
  #pragma unroll
  for (int j = 0; j < 4; j++) p *= (wid > j) ? a[j] : 1.f;
  return p;
}

// ---------------------------------------------------------------------------
// All five weight transposes in ONE dispatch: grid (16,16,5).
// ---------------------------------------------------------------------------
__global__ __launch_bounds__(256)
void wtrans_all(const float* __restrict__ s0, half_t* __restrict__ d0,
                const float* __restrict__ s1, half_t* __restrict__ d1,
                const float* __restrict__ s2, half_t* __restrict__ d2,
                const float* __restrict__ s3, half_t* __restrict__ d3,
                const float* __restrict__ s4, half_t* __restrict__ d4)
{
  __shared__ float t[32][33];
  const float* W; half_t* WT;
  switch (blockIdx.z) {
    case 0: W = s0; WT = d0; break;
    case 1: W = s1; WT = d1; break;
    case 2: W = s2; WT = d2; break;
    case 3: W = s3; WT = d3; break;
    default: W = s4; WT = d4; break;
  }
  int bx = blockIdx.x, by = blockIdx.y;
  int tid = threadIdx.x;
  int r = tid >> 3, cq = tid & 7;
  float4 v = *(const float4*)&W[(size_t)(bx * 32 + r) * 512 + by * 32 + cq * 4];
  t[r][cq * 4 + 0] = v.x; t[r][cq * 4 + 1] = v.y;
  t[r][cq * 4 + 2] = v.z; t[r][cq * 4 + 3] = v.w;
  __syncthreads();
  half4v o;
  o[0] = (half_t)t[cq * 4 + 0][r];
  o[1] = (half_t)t[cq * 4 + 1][r];
  o[2] = (half_t)t[cq * 4 + 2][r];
  o[3] = (half_t)t[cq * 4 + 3][r];
  *(half4v*)&WT[(size_t)(by * 32 + r) * 512 + bx * 32 + cq * 4] = o;
}

// Concatenated biases for the merged N=1024 projections (v3 only).
__global__ __launch_bounds__(256)
void catbias(const float* __restrict__ a, const float* __restrict__ b,
             const float* __restrict__ c, const float* __restrict__ d,
             float* __restrict__ cbq, float* __restrict__ cbk)
{
  int t = threadIdx.x;
  for (int i = t; i < 512; i += 256) {
    cbq[i] = a[i]; cbq[512 + i] = b[i];
    cbk[i] = c[i]; cbk[512 + i] = d[i];
  }
}

// ---------------------------------------------------------------------------
// MFMA GEMM body. tid in [0,256). K-split via kdiv/kc; ATOM -> atomicAdd;
// CT -> store C transposed (vT).
// ---------------------------------------------------------------------------
struct GemmLds { half_t As[4][128][8]; half_t Bs[4][128][8]; };
struct __align__(16) ScanLds { float wsA[2][4]; float wsB[2][4]; };

template<int MODE, bool CT, bool ATOM, typename TC>
__device__ __forceinline__
void mgemm_body(GemmLds& L, int tid, int bxx, int byy, int bzz,
                const float* __restrict__ A, const half_t* __restrict__ BT,
                TC* __restrict__ C, int M, int N, int Kd,
                int lda, int ldb, int ldc, int hdiv, int kdiv, int kc,
                long long sAb, long long sAh, long long sBb, long long sBh,
                long long sCb, long long sCh,
                const float* __restrict__ bias, const float* __restrict__ rvec)
{
  int ks = bzz % kdiv; int zz = bzz / kdiv;
  int bz = zz / hdiv, hz = zz - bz * hdiv;
  A  += (size_t)bz * sAb + (size_t)hz * sAh + (size_t)ks * kc;
  BT += (size_t)bz * sBb + (size_t)hz * sBh + (size_t)ks * kc;
  C  += (size_t)bz * sCb + (size_t)hz * sCh;
  int Ke = Kd - ks * kc; if (Ke > kc) Ke = kc;

  int lane = tid & 63, wid = tid >> 6;
  int wm = wid >> 1, wn = wid & 1;
  int m0 = byy * 128, n0 = bxx * 128;

  f32x4 acc[4][4] = {};

  for (int k0 = 0; k0 < Ke; k0 += 32) {
    #pragma unroll
    for (int i = 0; i < 4; i++) {            // A: 128x32 f32 -> f16
      int ch = tid + i * 256;
      int m = ch >> 3, cq = ch & 7, k = cq * 4;
      float4 v = make_float4(0.f, 0.f, 0.f, 0.f);
      if (m0 + m < M && k0 + k < Ke) v = *(const float4*)&A[(size_t)(m0 + m) * lda + k0 + k];
      half4v h;
      h[0] = (half_t)v.x; h[1] = (half_t)v.y; h[2] = (half_t)v.z; h[3] = (half_t)v.w;
      *(half4v*)&L.As[cq >> 1][m][(cq & 1) * 4] = h;
    }
    #pragma unroll
    for (int i = 0; i < 2; i++) {            // B: 128x32 f16
      int ch = tid + i * 256;
      int n = ch >> 2, kb = ch & 3;
      half8 v = {(_Float16)0,(_Float16)0,(_Float16)0,(_Float16)0,
                 (_Float16)0,(_Float16)0,(_Float16)0,(_Float16)0};
      if (n0 + n < N && k0 + kb * 8 < Ke)
        v = *(const half8*)&BT[(size_t)(n0 + n) * ldb + k0 + kb * 8];
      *(half8*)&L.Bs[kb][n][0] = v;
    }
    __syncthreads();
    int kb = lane >> 4, r = lane & 15;
    half8 af[4], bfv[4];
    #pragma unroll
    for (int mi = 0; mi < 4; mi++) af[mi]  = *(const half8*)&L.As[kb][wm * 64 + mi * 16 + r][0];
    #pragma unroll
    for (int ni = 0; ni < 4; ni++) bfv[ni] = *(const half8*)&L.Bs[kb][wn * 64 + ni * 16 + r][0];
    #pragma unroll
    for (int mi = 0; mi < 4; mi++)
      #pragma unroll
      for (int ni = 0; ni < 4; ni++)
        acc[mi][ni] = __builtin_amdgcn_mfma_f32_16x16x32_f16(af[mi], bfv[ni], acc[mi][ni], 0, 0, 0);
    __syncthreads();
  }

  float radd = (MODE == 1) ? rvec[hz] : 0.f;
  int r = lane & 15, g = lane >> 4;
  #pragma unroll
  for (int mi = 0; mi < 4; mi++) {
    #pragma unroll
    for (int ni = 0; ni < 4; ni++) {
      int col = n0 + wn * 64 + ni * 16 + r;
      if (col >= N) continue;
      float bv = (MODE == 0) ? bias[col] : 0.f;
      if (CT) {
        int row0 = m0 + wm * 64 + mi * 16 + g * 4;
        if (row0 + 3 < M) {
          half4v o;
          #pragma unroll
          for (int j = 0; j < 4; j++) o[j] = (half_t)(acc[mi][ni][j] + bv);
          *(half4v*)&((half_t*)C)[(size_t)col * ldc + row0] = o;
        }
      } else {
        #pragma unroll
        for (int j = 0; j < 4; j++) {
          int row = m0 + wm * 64 + mi * 16 + g * 4 + j;
          if (row >= M) continue;
          float v = acc[mi][ni][j];
          if (MODE == 0)      v += bv;
          else if (MODE == 1) v = frcp(1.f + expf(-(v * INV_SCALE + radd)));
          else if (MODE == 2) v *= INV_SCALE;
          if (ATOM) atomicAdd((float*)&C[(size_t)row * ldc + col], v);
          else      stf(&C[(size_t)row * ldc + col], v);
        }
      }
    }
  }
}

template<int MODE, bool CT, bool ATOM, typename TC>
__global__ __launch_bounds__(256)
void mgemm(const float* __restrict__ A, const half_t* __restrict__ BT,
           TC* __restrict__ C, int M, int N, int Kd,
           int lda, int ldb, int ldc, int hdiv, int kdiv, int kc,
           long long sAb, long long sAh, long long sBb, long long sBh,
           long long sCb, long long sCh,
           const float* __restrict__ bias, const float* __restrict__ rvec)
{
  __shared__ GemmLds L;
  mgemm_body<MODE,CT,ATOM,TC>(L, threadIdx.x, blockIdx.x, blockIdx.y, blockIdx.z,
                              A, BT, C, M, N, Kd, lda, ldb, ldc, hdiv, kdiv, kc,
                              sAb, sAh, sBb, sBh, sCb, sCh, bias, rvec);
}

// ---------------------------------------------------------------------------
// FUSED (256 threads, launch_bounds(256,1) -> VGPR headroom for the scan):
//  blocks 0-31   : cp+alpha scan — ONE block per chain, 4 waves, 12 elems/lane
//  blocks 32-415 : u GEMM (384 virtual blocks)
//  blocks 416+   : vT projection (v3 only, 752 blocks)
// Scan: setprio(1), DPP scans, single lgkm barrier, ping-pong ws, NT stores,
// w = p*cp folded at row build (removes cvt+mul from the an phase).
// ---------------------------------------------------------------------------
union MidLds { GemmLds g; ScanLds s; };

__global__ __launch_bounds__(256, 1)
void fused_mid(const half_t* __restrict__ p16, float* __restrict__ alpha_slot,
               const float* __restrict__ qa, const half_t* __restrict__ kb,
               int lda_u, int ldb_u, long long sAb_u, long long sBb_u,
               float* __restrict__ u_buf,
               const float* __restrict__ key, const half_t* __restrict__ wt_v,
               half_t* __restrict__ vtbuf, const float* __restrict__ b_value)
{
  __shared__ MidLds lds;
  int blk = blockIdx.x;
  int tid = threadIdx.x;

  if (blk >= 32) {
    if (blk < 416) {                     // ---- u GEMM: vb in [0,384) ----
      int vb = blk - 32;
      int bx = vb % 24; int t = vb / 24;
      int by = t & 1;   int bz = t >> 1;
      mgemm_body<2,false,false,float>(lds.g, tid, bx, by, bz, qa, kb, u_buf,
          256, 3000, 512, lda_u, ldb_u, 3000, 1, 1, 512,
          sAb_u, 0, sBb_u, 0, 768000, 0, nullptr, nullptr);
    } else {                             // ---- vT proj: vb in [0,752) ----
      int vb = blk - 416;
      int bx = vb & 3; int by = vb >> 2;
      mgemm_body<0,true,false,half_t>(lds.g, tid, bx, by, 0, key, wt_v, vtbuf,
          24000, 512, 512, 512, 512, 24000, 1, 1, 512,
          0, 0, 0, 0, 0, 0, b_value, nullptr);
    }
    return;
  }

  // ---- scan for chain blk: 256 thr x 12 elems (3000 = 250x12) ----
  __builtin_amdgcn_s_setprio(1);
  float (&wsA)[2][4] = lds.s.wsA;
  float (&wsB)[2][4] = lds.s.wsB;
  int lane = tid & 63, wid = tid >> 6;
  int k0 = tid * 12;
  size_t zbase = (size_t)blk * 768000;   // 256*3000
  const half_t* prow = p16 + zbase;

  half4v ph0[3], pvh[3];
  #pragma unroll
  for (int j = 0; j < 3; j++) {
    int k = k0 + j * 4;
    half4v z4 = {(_Float16)0,(_Float16)0,(_Float16)0,(_Float16)0};
    ph0[j] = (k + 4 <= 3000) ? *(const half4v*)&prow[k]        : z4;
    pvh[j] = (k + 4 <= 3000) ? *(const half4v*)&prow[3000 + k] : z4;
  }

  float a_prev[12];
  #pragma unroll
  for (int c = 0; c < 12; c++) a_prev[c] = 0.f;
  if (tid == 0) a_prev[0] = 1.f;

  float cpv[12], w[12];
  { // prologue: cp row 0 (multiplicative DPP scan), w = p0*cp0
    float l[12], m = 1.f;
    float p0f[12];
    #pragma unroll
    for (int c = 0; c < 12; c++) {
      p0f[c] = (float)ph0[c >> 2][c & 3];
      l[c] = m;
      m *= fmaxf(1.f - p0f[c], EPSV);    // 1-p <= 1 always: min clamp dropped
    }
    float incl = wave_iscan_mul(m);
    if (lane == 63) wsA[1][wid] = incl;
    float exclw = incl * frcp(fmaxf(m, 1e-30f));
    block_sync_lds();
    float base = exclw * cross_prod4(&wsA[1][0], wid);
    #pragma unroll
    for (int c = 0; c < 12; c++) { cpv[c] = base * l[c]; w[c] = p0f[c] * cpv[c]; }
  }

  for (int i = 0; i < 256; i++) {
    int par = i & 1;
    // scan2: inclusive cumsum of a_prev * rcp(clip(cp_i))
    float t[12], s2 = 0.f;
    #pragma unroll
    for (int c = 0; c < 12; c++) {
      s2 = fmaf(a_prev[c], frcp(fmaxf(cpv[c], EPSV)), s2);
      t[c] = s2;
    }
    float incl2 = wave_iscan_add(s2);
    if (lane == 63) wsB[par][wid] = incl2;
    float excl2 = incl2 - s2;

    // scan1: cp for row i+1 (multiplicative, recurrence-independent)
    float pnf[12], l[12], m = 1.f;
    #pragma unroll
    for (int c = 0; c < 12; c++) {
      pnf[c] = (float)pvh[c >> 2][c & 3];
      l[c] = m;
      m *= fmaxf(1.f - pnf[c], EPSV);
    }
    float incl1 = wave_iscan_mul(m);
    if (lane == 63) wsA[par][wid] = incl1;
    float excl1 = incl1 * frcp(fmaxf(m, 1e-30f));

    block_sync_lds();                    // the single (LDS-only) barrier

    float off = excl2 + cross_sum4(&wsB[par][0], wid);
    size_t rbase = zbase + (size_t)i * 3000;
    #pragma unroll
    for (int q4 = 0; q4 < 3; q4++) {
      f32x4 o;
      #pragma unroll
      for (int j = 0; j < 4; j++) {
        int c = q4 * 4 + j;
        float an = w[c] * (off + t[c]);
        a_prev[c] = an;
        o[j] = an;
      }
      int k = k0 + q4 * 4;
      if (k + 4 <= 3000)
        __builtin_nontemporal_store(o, (f32x4*)&alpha_slot[rbase + k]);
    }
    float base1 = excl1 * cross_prod4(&wsA[par][0], wid);
    #pragma unroll
    for (int c = 0; c < 12; c++) { cpv[c] = base1 * l[c]; w[c] = pnf[c] * cpv[c]; }
    if (i < 254) {                       // prefetch p row i+2 (packed fp16)
      const half_t* nrow = prow + (size_t)(i + 2) * 3000;
      #pragma unroll
      for (int j = 0; j < 3; j++) {
        int k = k0 + j * 4;
        if (k + 4 <= 3000) pvh[j] = *(const half4v*)&nrow[k];
      }
    }
  }
}

// ---------------------------------------------------------------------------
// Chunkwise beta — streaming passes vectorized to f32x4.
// ---------------------------------------------------------------------------
__global__ __launch_bounds__(256)
void beta_kernel(const float* __restrict__ ubuf, const float* __restrict__ alpha_slot,
                 float* __restrict__ beta_slot)
{
  __shared__ __align__(16) float se[3008];
  __shared__ __align__(16) float dn[3008];
  __shared__ __align__(16) float tt[3024];
  __shared__ float red[4];
  int bq = blockIdx.x;
  int b = bq >> 8, q = bq & 255;
  int tid = threadIdx.x;
  int lane = tid & 63, wid = tid >> 6;
  const float* urow = ubuf + (size_t)bq * 3000;
  float lmax = -3.0e38f;
  for (int c = tid; c < 750; c += 256) {
    f32x4 v = *(const f32x4*)&urow[c * 4];
    *(f32x4*)&se[c * 4] = v;
    lmax = fmaxf(lmax, fmaxf(fmaxf(v[0], v[1]), fmaxf(v[2], v[3])));
  }
  #pragma unroll
  for (int d = 32; d > 0; d >>= 1) lmax = fmaxf(lmax, __shfl_xor(lmax, d));
  if (lane == 0) red[wid] = lmax;
  __syncthreads();
  float umax = fmaxf(fmaxf(red[0], red[1]), fmaxf(red[2], red[3]));
  for (int c = tid; c < 750; c += 256) {
    f32x4 v = *(const f32x4*)&se[c * 4];
    #pragma unroll
    for (int j = 0; j < 4; j++) v[j] = fmaxf(expf(v[j] - umax), 1e-5f);
    *(f32x4*)&se[c * 4] = v;
  }
  if (tid < 24) tt[3000 + tid] = 0.f;              // forward-window zero pad
  __syncthreads();
  for (int k = tid; k < 3000; k += 256) {
    int lo = k - 15; if (lo < 0) lo = 0;
    float s = 0.f;
    for (int j = lo; j <= k; j++) s += se[j];
    dn[k] = s;
  }
  __syncthreads();
  for (int h = 0; h < 4; h++) {
    const float* arow = alpha_slot + ((size_t)((b * 4 + h) * 256 + q)) * 3000;
    for (int c = tid; c < 750; c += 256) {
      f32x4 a = *(const f32x4*)&arow[c * 4];
      f32x4 d = *(const f32x4*)&dn[c * 4];
      f32x4 o;
      #pragma unroll
      for (int j = 0; j < 4; j++) o[j] = a[j] * frcp(d[j]);
      *(f32x4*)&tt[c * 4] = o;
    }
    __syncthreads();
    float* brow = beta_slot + ((size_t)((b * 4 + h) * 256 + q)) * 3000;
    for (int c = tid; c < 750; c += 256) {
      f32x4 o;
      #pragma unroll
      for (int j = 0; j < 4; j++) {
        int k = c * 4 + j;
        float s = 0.f;
        #pragma unroll
        for (int w = 0; w < 16; w++) s += tt[k + w];
        o[j] = se[k] * s;
      }
      *(f32x4*)&brow[c * 4] = o;
    }
    __syncthreads();
  }
}

// ---------------------------------------------------------------------------
extern "C" void kernel_launch(void* const* d_in, const int* in_sizes, int n_in,
                              void* d_out, int out_size, void* d_ws, size_t ws_size,
                              hipStream_t stream)
{
  const float* key        = (const float*)d_in[0];
  const float* query      = (const float*)d_in[1];
  const float* w_key_ma   = (const float*)d_in[2];
  const float* b_key_ma   = (const float*)d_in[3];
  const float* w_query_ma = (const float*)d_in[4];
  const float* b_query_ma = (const float*)d_in[5];
  const float* rvec       = (const float*)d_in[6];
  const float* w_key_ca   = (const float*)d_in[7];
  const float* b_key_ca   = (const float*)d_in[8];
  const float* w_query_ca = (const float*)d_in[9];
  const float* b_query_ca = (const float*)d_in[10];
  const float* w_value    = (const float*)d_in[11];
  const float* b_value    = (const float*)d_in[12];

  // Outputs FP32: cv | alpha | beta, flat.
  float* out       = (float*)d_out;
  float* cv_out    = out;                                  // (8,256,512)
  float* alpha_out = out + (size_t)1048576;                // (8,4,256,3000)
  float* beta_out  = alpha_out + (size_t)24576000;         // (8,4,256,3000)
  half_t* p16      = (half_t*)beta_out;                    // p_choose fp16, dead before beta

  dim3 blk(256);
  bool v3 = ws_size >= (size_t)109322240;

  hipMemsetAsync(cv_out, 0, (size_t)1048576 * sizeof(float), stream);  // cv K-split atomics

  if (v3) {
    // v3 layout: kbuf2[24000][1024] | qbuf[2048][1024] f32 | u | vtbuf | wts | catbias
    half_t* kbuf2 = (half_t*)d_ws;
    float*  qbuf  = (float*)((char*)d_ws + 49152000);
    float*  u_buf = (float*)((char*)d_ws + 57540608);
    half_t* vtbuf = (half_t*)((char*)d_ws + 82116608);
    half_t* wt_q  = (half_t*)((char*)d_ws + 106692608);   // [1024][512]
    half_t* wt_k  = (half_t*)((char*)d_ws + 107741184);   // [1024][512]
    half_t* wt_v  = (half_t*)((char*)d_ws + 108789760);
    float*  cb_q  = (float*)((char*)d_ws + 109314048);
    float*  cb_k  = (float*)((char*)d_ws + 109318144);

    wtrans_all<<<dim3(16,16,5), blk, 0, stream>>>(
        w_query_ma, wt_q, w_query_ca, wt_q + 262144,
        w_key_ma,   wt_k, w_key_ca,   wt_k + 262144,
        w_value,    wt_v);
    catbias<<<dim3(1), blk, 0, stream>>>(b_query_ma, b_query_ca, b_key_ma, b_key_ca, cb_q, cb_k);

    mgemm<0,false,false,float ><<<dim3(8,16,1),  blk, 0, stream>>>(query, wt_q, qbuf, 2048, 1024, 512, 512,512,1024, 1,1,512, 0,0,0,0,0,0, cb_q, nullptr);
    mgemm<0,false,false,half_t><<<dim3(8,188,1), blk, 0, stream>>>(key,   wt_k, kbuf2, 24000,1024, 512, 512,512,1024, 1,1,512, 0,0,0,0,0,0, cb_k, nullptr);

    mgemm<1,false,false,half_t><<<dim3(24,2,32), blk, 0, stream>>>(qbuf, kbuf2, p16, 256,3000, 128, 1024,1024,3000, 4,1,128,
        262144,128, 3072000,128, 3072000,768000, nullptr, rvec);

    // FUSED: scan (0-31) + u GEMM (32-415) + vT shells (416-1167)
    fused_mid<<<dim3(1168), blk, 0, stream>>>(p16, alpha_out,
        qbuf + 512, kbuf2 + 512, 1024, 1024, 262144, 3072000,
        u_buf, key, wt_v, vtbuf, b_value);

    beta_kernel<<<dim3(2048), blk, 0, stream>>>(u_buf, alpha_out, beta_out);

    mgemm<3,false,true,float><<<dim3(1,2,256), blk, 0, stream>>>(beta_out, vtbuf, cv_out, 256,128,3000, 3000,24000,512, 4,8,384,
        3072000,768000, 3000,3072000, 131072,128, nullptr, nullptr);
  } else {
    // v1 fallback: kbuf | qbuf | u | 5x wt. 55.97MB.
    if (ws_size < (size_t)55967744) return;
    half_t* kbuf   = (half_t*)d_ws;
    float*  qbuf   = (float*)((char*)d_ws + 24576000);
    float*  u_buf  = (float*)((char*)d_ws + 28770304);
    half_t* wt_qma = (half_t*)((char*)d_ws + 53346304);
    half_t* wt_kma = (half_t*)((char*)d_ws + 53870592);
    half_t* wt_qca = (half_t*)((char*)d_ws + 54394880);
    half_t* wt_kca = (half_t*)((char*)d_ws + 54919168);
    half_t* wt_v   = (half_t*)((char*)d_ws + 55443456);

    wtrans_all<<<dim3(16,16,5), blk, 0, stream>>>(
        w_query_ma, wt_qma, w_query_ca, wt_qca,
        w_key_ma,   wt_kma, w_key_ca,   wt_kca,
        w_value,    wt_v);

    mgemm<0,false,false,float ><<<dim3(4,16,1),  blk, 0, stream>>>(query, wt_qma, qbuf, 2048, 512, 512, 512,512,512, 1,1,512, 0,0,0,0,0,0, b_query_ma, nullptr);
    mgemm<0,false,false,half_t><<<dim3(4,188,1), blk, 0, stream>>>(key,   wt_kma, kbuf, 24000,512, 512, 512,512,512, 1,1,512, 0,0,0,0,0,0, b_key_ma,   nullptr);
    mgemm<1,false,false,half_t><<<dim3(24,2,32), blk, 0, stream>>>(qbuf,  kbuf, p16, 256,3000, 128, 512,512,3000, 4,1,128,
        131072,128, 1536000,128, 3072000,768000, nullptr, rvec);

    mgemm<0,false,false,float ><<<dim3(4,16,1),  blk, 0, stream>>>(query, wt_qca, qbuf, 2048, 512, 512, 512,512,512, 1,1,512, 0,0,0,0,0,0, b_query_ca, nullptr);
    mgemm<0,false,false,half_t><<<dim3(4,188,1), blk, 0, stream>>>(key,   wt_kca, kbuf, 24000,512, 512, 512,512,512, 1,1,512, 0,0,0,0,0,0, b_key_ca,   nullptr);

    // FUSED: scan (0-31) + u GEMM (32-415); vT serial after (into kbuf)
    fused_mid<<<dim3(416), blk, 0, stream>>>(p16, alpha_out,
        qbuf, kbuf, 512, 512, 131072, 1536000,
        u_buf, key, wt_v, kbuf, b_value);

    mgemm<0,true,false,half_t><<<dim3(4,188,1), blk, 0, stream>>>(key, wt_v, kbuf, 24000,512, 512, 512,512,24000, 1,1,512, 0,0,0,0,0,0, b_value, nullptr);

    beta_kernel<<<dim3(2048), blk, 0, stream>>>(u_buf, alpha_out, beta_out);

    mgemm<3,false,true,float><<<dim3(1,2,256), blk, 0, stream>>>(beta_out, kbuf, cv_out, 256,128,3000, 3000,24000,512, 4,8,384,
        3072000,768000, 3000,3072000, 131072,128, nullptr, nullptr);
  }
}

// Round 16
// 578.184 us; speedup vs baseline: 4.4851x; 1.0310x over previous
//
#include <hip/hip_runtime.h>
#include <hip/hip_bf16.h>
#include <math.h>

#define EPSV 1e-6f
#define INV_SCALE 0.04419417382415922f   // 1/sqrt(512)

typedef _Float16 half_t;
typedef __attribute__((ext_vector_type(8))) _Float16 half8;
typedef __attribute__((ext_vector_type(4))) _Float16 half4v;
typedef __attribute__((ext_vector_type(2))) _Float16 half2v;
typedef __attribute__((ext_vector_type(4))) float    f32x4;

__device__ __forceinline__ float ldf(const float* p)  { return *p; }
__device__ __forceinline__ float ldf(const half_t* p) { return (float)*p; }
__device__ __forceinline__ void  stf(float* p, float v)  { *p = v; }
__device__ __forceinline__ void  stf(half_t* p, float v) { *p = (half_t)v; }
__device__ __forceinline__ float frcp(float x) { return __builtin_amdgcn_rcpf(x); }

// ---------------------------------------------------------------------------
// DPP wave-64 inclusive scans (validated rounds 11-15).
// ---------------------------------------------------------------------------
template<int CTRL, int RMASK>
__device__ __forceinline__ float dpp_add_step(float x) {
  int t = __builtin_amdgcn_update_dpp(0, __float_as_int(x), CTRL, RMASK, 0xf, true);
  return x + __int_as_float(t);
}
template<int CTRL, int RMASK>
__device__ __forceinline__ float dpp_mul_step(float x) {
  int t = __builtin_amdgcn_update_dpp(0x3f800000, __float_as_int(x), CTRL, RMASK, 0xf, false);
  return x * __int_as_float(t);
}
__device__ __forceinline__ float wave_iscan_add(float x) {
  x = dpp_add_step<0x111,0xf>(x);
  x = dpp_add_step<0x112,0xf>(x);
  x = dpp_add_step<0x114,0xf>(x);
  x = dpp_add_step<0x118,0xf>(x);
  x = dpp_add_step<0x142,0xa>(x);
  x = dpp_add_step<0x143,0xc>(x);
  return x;
}
__device__ __forceinline__ float wave_iscan_mul(float x) {
  x = dpp_mul_step<0x111,0xf>(x);
  x = dpp_mul_step<0x112,0xf>(x);
  x = dpp_mul_step<0x114,0xf>(x);
  x = dpp_mul_step<0x118,0xf>(x);
  x = dpp_mul_step<0x142,0xa>(x);
  x = dpp_mul_step<0x143,0xc>(x);
  return x;
}

// LDS-only barrier (skips the vmcnt(0) drain __syncthreads emits).
__device__ __forceinline__ void block_sync_lds() {
  asm volatile("s_waitcnt lgkmcnt(0)" ::: "memory");
  __builtin_amdgcn_s_barrier();
  asm volatile("" ::: "memory");
}

// Cross-wave prefix helpers over 4 wave-sums (one f32x4 read + masked ops).
__device__ __forceinline__ float cross_sum4(const float* ws, int wid) {
  f32x4 a = *(const f32x4*)ws;
  float s = 0.f;
  #pragma unroll
  for (int j = 0; j < 4; j++) s += (wid > j) ? a[j] : 0.f;
  return s;
}
__device__ __forceinline__ float cross_prod4(const float* ws, int wid) {
  f32x4 a = *(const f32x4*)ws;
  float p = 1.f;
  #pragma unroll
  for (int j = 0; j < 4; j++) p *= (wid > j) ? a[j] : 1.f;
  return p;
}

// ---------------------------------------------------------------------------
// All five weight transposes in ONE dispatch: grid (16,16,5).
// ---------------------------------------------------------------------------
__global__ __launch_bounds__(256)
void wtrans_all(const float* __restrict__ s0, half_t* __restrict__ d0,
                const float* __restrict__ s1, half_t* __restrict__ d1,
                const float* __restrict__ s2, half_t* __restrict__ d2,
                const float* __restrict__ s3, half_t* __restrict__ d3,
                const float* __restrict__ s4, half_t* __restrict__ d4)
{
  __shared__ float t[32][33];
  const float* W; half_t* WT;
  switch (blockIdx.z) {
    case 0: W = s0; WT = d0; break;
    case 1: W = s1; WT = d1; break;
    case 2: W = s2; WT = d2; break;
    case 3: W = s3; WT = d3; break;
    default: W = s4; WT = d4; break;
  }
  int bx = blockIdx.x, by = blockIdx.y;
  int tid = threadIdx.x;
  int r = tid >> 3, cq = tid & 7;
  float4 v = *(const float4*)&W[(size_t)(bx * 32 + r) * 512 + by * 32 + cq * 4];
  t[r][cq * 4 + 0] = v.x; t[r][cq * 4 + 1] = v.y;
  t[r][cq * 4 + 2] = v.z; t[r][cq * 4 + 3] = v.w;
  __syncthreads();
  half4v o;
  o[0] = (half_t)t[cq * 4 + 0][r];
  o[1] = (half_t)t[cq * 4 + 1][r];
  o[2] = (half_t)t[cq * 4 + 2][r];
  o[3] = (half_t)t[cq * 4 + 3][r];
  *(half4v*)&WT[(size_t)(by * 32 + r) * 512 + bx * 32 + cq * 4] = o;
}

// Concatenated biases for the merged N=1024 projections (v3 only).
__global__ __launch_bounds__(256)
void catbias(const float* __restrict__ a, const float* __restrict__ b,
             const float* __restrict__ c, const float* __restrict__ d,
             float* __restrict__ cbq, float* __restrict__ cbk)
{
  int t = threadIdx.x;
  for (int i = t; i < 512; i += 256) {
    cbq[i] = a[i]; cbq[512 + i] = b[i];
    cbk[i] = c[i]; cbk[512 + i] = d[i];
  }
}

// ---------------------------------------------------------------------------
// MFMA GEMM body. tid in [0,256). K-split via kdiv/kc; ATOM -> atomicAdd;
// CT -> store C transposed (vT).
// ---------------------------------------------------------------------------
struct GemmLds { half_t As[4][128][8]; half_t Bs[4][128][8]; };
struct __align__(16) ScanLds { float wsA[2][4]; float wsB[2][4]; };

template<int MODE, bool CT, bool ATOM, typename TC>
__device__ __forceinline__
void mgemm_body(GemmLds& L, int tid, int bxx, int byy, int bzz,
                const float* __restrict__ A, const half_t* __restrict__ BT,
                TC* __restrict__ C, int M, int N, int Kd,
                int lda, int ldb, int ldc, int hdiv, int kdiv, int kc,
                long long sAb, long long sAh, long long sBb, long long sBh,
                long long sCb, long long sCh,
                const float* __restrict__ bias, const float* __restrict__ rvec)
{
  int ks = bzz % kdiv; int zz = bzz / kdiv;
  int bz = zz / hdiv, hz = zz - bz * hdiv;
  A  += (size_t)bz * sAb + (size_t)hz * sAh + (size_t)ks * kc;
  BT += (size_t)bz * sBb + (size_t)hz * sBh + (size_t)ks * kc;
  C  += (size_t)bz * sCb + (size_t)hz * sCh;
  int Ke = Kd - ks * kc; if (Ke > kc) Ke = kc;

  int lane = tid & 63, wid = tid >> 6;
  int wm = wid >> 1, wn = wid & 1;
  int m0 = byy * 128, n0 = bxx * 128;

  f32x4 acc[4][4] = {};

  for (int k0 = 0; k0 < Ke; k0 += 32) {
    #pragma unroll
    for (int i = 0; i < 4; i++) {            // A: 128x32 f32 -> f16
      int ch = tid + i * 256;
      int m = ch >> 3, cq = ch & 7, k = cq * 4;
      float4 v = make_float4(0.f, 0.f, 0.f, 0.f);
      if (m0 + m < M && k0 + k < Ke) v = *(const float4*)&A[(size_t)(m0 + m) * lda + k0 + k];
      half4v h;
      h[0] = (half_t)v.x; h[1] = (half_t)v.y; h[2] = (half_t)v.z; h[3] = (half_t)v.w;
      *(half4v*)&L.As[cq >> 1][m][(cq & 1) * 4] = h;
    }
    #pragma unroll
    for (int i = 0; i < 2; i++) {            // B: 128x32 f16
      int ch = tid + i * 256;
      int n = ch >> 2, kb = ch & 3;
      half8 v = {(_Float16)0,(_Float16)0,(_Float16)0,(_Float16)0,
                 (_Float16)0,(_Float16)0,(_Float16)0,(_Float16)0};
      if (n0 + n < N && k0 + kb * 8 < Ke)
        v = *(const half8*)&BT[(size_t)(n0 + n) * ldb + k0 + kb * 8];
      *(half8*)&L.Bs[kb][n][0] = v;
    }
    __syncthreads();
    int kb = lane >> 4, r = lane & 15;
    half8 af[4], bfv[4];
    #pragma unroll
    for (int mi = 0; mi < 4; mi++) af[mi]  = *(const half8*)&L.As[kb][wm * 64 + mi * 16 + r][0];
    #pragma unroll
    for (int ni = 0; ni < 4; ni++) bfv[ni] = *(const half8*)&L.Bs[kb][wn * 64 + ni * 16 + r][0];
    #pragma unroll
    for (int mi = 0; mi < 4; mi++)
      #pragma unroll
      for (int ni = 0; ni < 4; ni++)
        acc[mi][ni] = __builtin_amdgcn_mfma_f32_16x16x32_f16(af[mi], bfv[ni], acc[mi][ni], 0, 0, 0);
    __syncthreads();
  }

  float radd = (MODE == 1) ? rvec[hz] : 0.f;
  int r = lane & 15, g = lane >> 4;
  #pragma unroll
  for (int mi = 0; mi < 4; mi++) {
    #pragma unroll
    for (int ni = 0; ni < 4; ni++) {
      int col = n0 + wn * 64 + ni * 16 + r;
      if (col >= N) continue;
      float bv = (MODE == 0) ? bias[col] : 0.f;
      if (CT) {
        int row0 = m0 + wm * 64 + mi * 16 + g * 4;
        if (row0 + 3 < M) {
          half4v o;
          #pragma unroll
          for (int j = 0; j < 4; j++) o[j] = (half_t)(acc[mi][ni][j] + bv);
          *(half4v*)&((half_t*)C)[(size_t)col * ldc + row0] = o;
        }
      } else {
        #pragma unroll
        for (int j = 0; j < 4; j++) {
          int row = m0 + wm * 64 + mi * 16 + g * 4 + j;
          if (row >= M) continue;
          float v = acc[mi][ni][j];
          if (MODE == 0)      v += bv;
          else if (MODE == 1) v = frcp(1.f + expf(-(v * INV_SCALE + radd)));
          else if (MODE == 2) v *= INV_SCALE;
          if (ATOM) atomicAdd((float*)&C[(size_t)row * ldc + col], v);
          else      stf(&C[(size_t)row * ldc + col], v);
        }
      }
    }
  }
}

template<int MODE, bool CT, bool ATOM, typename TC>
__global__ __launch_bounds__(256)
void mgemm(const float* __restrict__ A, const half_t* __restrict__ BT,
           TC* __restrict__ C, int M, int N, int Kd,
           int lda, int ldb, int ldc, int hdiv, int kdiv, int kc,
           long long sAb, long long sAh, long long sBb, long long sBh,
           long long sCb, long long sCh,
           const float* __restrict__ bias, const float* __restrict__ rvec)
{
  __shared__ GemmLds L;
  mgemm_body<MODE,CT,ATOM,TC>(L, threadIdx.x, blockIdx.x, blockIdx.y, blockIdx.z,
                              A, BT, C, M, N, Kd, lda, ldb, ldc, hdiv, kdiv, kc,
                              sAb, sAh, sBb, sBh, sCb, sCh, bias, rvec);
}

// ---------------------------------------------------------------------------
// FUSED (256 threads, launch_bounds(256,1)):
//  blocks 0-31   : cp+alpha scan — ONE block per chain, 4 waves, 12 elems/lane
//  blocks 32-415 : u GEMM (384 virtual blocks)
//  blocks 416+   : vT projection (v3 only, 752 blocks)
// Scan vmem-queue discipline (round 16): prefetch LOADS issued BEFORE the
// alpha stores each step (loads are older in the vmcnt queue, so the next
// step's pvh use waits vmcnt(12) — no store-ack drain on the serial path).
// Stores are regular (not NT): acks come from L2, and beta_kernel re-reads
// alpha warm.
// ---------------------------------------------------------------------------
union MidLds { GemmLds g; ScanLds s; };

__global__ __launch_bounds__(256, 1)
void fused_mid(const half_t* __restrict__ p16, float* __restrict__ alpha_slot,
               const float* __restrict__ qa, const half_t* __restrict__ kb,
               int lda_u, int ldb_u, long long sAb_u, long long sBb_u,
               float* __restrict__ u_buf,
               const float* __restrict__ key, const half_t* __restrict__ wt_v,
               half_t* __restrict__ vtbuf, const float* __restrict__ b_value)
{
  __shared__ MidLds lds;
  int blk = blockIdx.x;
  int tid = threadIdx.x;

  if (blk >= 32) {
    if (blk < 416) {                     // ---- u GEMM: vb in [0,384) ----
      int vb = blk - 32;
      int bx = vb % 24; int t = vb / 24;
      int by = t & 1;   int bz = t >> 1;
      mgemm_body<2,false,false,float>(lds.g, tid, bx, by, bz, qa, kb, u_buf,
          256, 3000, 512, lda_u, ldb_u, 3000, 1, 1, 512,
          sAb_u, 0, sBb_u, 0, 768000, 0, nullptr, nullptr);
    } else {                             // ---- vT proj: vb in [0,752) ----
      int vb = blk - 416;
      int bx = vb & 3; int by = vb >> 2;
      mgemm_body<0,true,false,half_t>(lds.g, tid, bx, by, 0, key, wt_v, vtbuf,
          24000, 512, 512, 512, 512, 24000, 1, 1, 512,
          0, 0, 0, 0, 0, 0, b_value, nullptr);
    }
    return;
  }

  // ---- scan for chain blk: 256 thr x 12 elems (3000 = 250x12) ----
  __builtin_amdgcn_s_setprio(1);
  float (&wsA)[2][4] = lds.s.wsA;
  float (&wsB)[2][4] = lds.s.wsB;
  int lane = tid & 63, wid = tid >> 6;
  int k0 = tid * 12;
  size_t zbase = (size_t)blk * 768000;   // 256*3000
  const half_t* prow = p16 + zbase;

  half4v ph0[3], pvh[3];
  #pragma unroll
  for (int j = 0; j < 3; j++) {
    int k = k0 + j * 4;
    half4v z4 = {(_Float16)0,(_Float16)0,(_Float16)0,(_Float16)0};
    ph0[j] = (k + 4 <= 3000) ? *(const half4v*)&prow[k]        : z4;
    pvh[j] = (k + 4 <= 3000) ? *(const half4v*)&prow[3000 + k] : z4;
  }

  float a_prev[12];
  #pragma unroll
  for (int c = 0; c < 12; c++) a_prev[c] = 0.f;
  if (tid == 0) a_prev[0] = 1.f;

  float cpv[12], w[12];
  { // prologue: cp row 0 (multiplicative DPP scan), w = p0*cp0
    float l[12], m = 1.f;
    float p0f[12];
    #pragma unroll
    for (int c = 0; c < 12; c++) {
      p0f[c] = (float)ph0[c >> 2][c & 3];
      l[c] = m;
      m *= fmaxf(1.f - p0f[c], EPSV);    // 1-p <= 1 always: min clamp dropped
    }
    float incl = wave_iscan_mul(m);
    if (lane == 63) wsA[1][wid] = incl;
    float exclw = incl * frcp(fmaxf(m, 1e-30f));
    block_sync_lds();
    float base = exclw * cross_prod4(&wsA[1][0], wid);
    #pragma unroll
    for (int c = 0; c < 12; c++) { cpv[c] = base * l[c]; w[c] = p0f[c] * cpv[c]; }
  }

  for (int i = 0; i < 256; i++) {
    int par = i & 1;
    // scan2: inclusive cumsum of a_prev * rcp(clip(cp_i))
    float t[12], s2 = 0.f;
    #pragma unroll
    for (int c = 0; c < 12; c++) {
      s2 = fmaf(a_prev[c], frcp(fmaxf(cpv[c], EPSV)), s2);
      t[c] = s2;
    }
    float incl2 = wave_iscan_add(s2);
    if (lane == 63) wsB[par][wid] = incl2;
    float excl2 = incl2 - s2;

    // scan1: cp for row i+1 (multiplicative, recurrence-independent).
    // pvh is fully consumed into pnf here, so it can be re-loaded after
    // the barrier.
    float pnf[12], l[12], m = 1.f;
    #pragma unroll
    for (int c = 0; c < 12; c++) {
      pnf[c] = (float)pvh[c >> 2][c & 3];
      l[c] = m;
      m *= fmaxf(1.f - pnf[c], EPSV);
    }
    float incl1 = wave_iscan_mul(m);
    if (lane == 63) wsA[par][wid] = incl1;
    float excl1 = incl1 * frcp(fmaxf(m, 1e-30f));

    block_sync_lds();                    // the single (LDS-only) barrier

    // ---- PREFETCH FIRST (older vmcnt entries than the stores below) ----
    if (i < 254) {
      const half_t* nrow = prow + (size_t)(i + 2) * 3000;
      #pragma unroll
      for (int j = 0; j < 3; j++) {
        int k = k0 + j * 4;
        if (k + 4 <= 3000) pvh[j] = *(const half4v*)&nrow[k];
      }
    }
    __builtin_amdgcn_sched_barrier(0);   // keep stores AFTER the loads

    float off = excl2 + cross_sum4(&wsB[par][0], wid);
    size_t rbase = zbase + (size_t)i * 3000;
    #pragma unroll
    for (int q4 = 0; q4 < 3; q4++) {
      f32x4 o;
      #pragma unroll
      for (int j = 0; j < 4; j++) {
        int c = q4 * 4 + j;
        float an = w[c] * (off + t[c]);
        a_prev[c] = an;
        o[j] = an;
      }
      int k = k0 + q4 * 4;
      if (k + 4 <= 3000)
        *(f32x4*)&alpha_slot[rbase + k] = o;   // regular store: L2 ack, cached for beta
    }
    float base1 = excl1 * cross_prod4(&wsA[par][0], wid);
    #pragma unroll
    for (int c = 0; c < 12; c++) { cpv[c] = base1 * l[c]; w[c] = pnf[c] * cpv[c]; }
  }
}

// ---------------------------------------------------------------------------
// Chunkwise beta — streaming passes vectorized to f32x4.
// ---------------------------------------------------------------------------
__global__ __launch_bounds__(256)
void beta_kernel(const float* __restrict__ ubuf, const float* __restrict__ alpha_slot,
                 float* __restrict__ beta_slot)
{
  __shared__ __align__(16) float se[3008];
  __shared__ __align__(16) float dn[3008];
  __shared__ __align__(16) float tt[3024];
  __shared__ float red[4];
  int bq = blockIdx.x;
  int b = bq >> 8, q = bq & 255;
  int tid = threadIdx.x;
  int lane = tid & 63, wid = tid >> 6;
  const float* urow = ubuf + (size_t)bq * 3000;
  float lmax = -3.0e38f;
  for (int c = tid; c < 750; c += 256) {
    f32x4 v = *(const f32x4*)&urow[c * 4];
    *(f32x4*)&se[c * 4] = v;
    lmax = fmaxf(lmax, fmaxf(fmaxf(v[0], v[1]), fmaxf(v[2], v[3])));
  }
  #pragma unroll
  for (int d = 32; d > 0; d >>= 1) lmax = fmaxf(lmax, __shfl_xor(lmax, d));
  if (lane == 0) red[wid] = lmax;
  __syncthreads();
  float umax = fmaxf(fmaxf(red[0], red[1]), fmaxf(red[2], red[3]));
  for (int c = tid; c < 750; c += 256) {
    f32x4 v = *(const f32x4*)&se[c * 4];
    #pragma unroll
    for (int j = 0; j < 4; j++) v[j] = fmaxf(expf(v[j] - umax), 1e-5f);
    *(f32x4*)&se[c * 4] = v;
  }
  if (tid < 24) tt[3000 + tid] = 0.f;              // forward-window zero pad
  __syncthreads();
  for (int k = tid; k < 3000; k += 256) {
    int lo = k - 15; if (lo < 0) lo = 0;
    float s = 0.f;
    for (int j = lo; j <= k; j++) s += se[j];
    dn[k] = s;
  }
  __syncthreads();
  for (int h = 0; h < 4; h++) {
    const float* arow = alpha_slot + ((size_t)((b * 4 + h) * 256 + q)) * 3000;
    for (int c = tid; c < 750; c += 256) {
      f32x4 a = *(const f32x4*)&arow[c * 4];
      f32x4 d = *(const f32x4*)&dn[c * 4];
      f32x4 o;
      #pragma unroll
      for (int j = 0; j < 4; j++) o[j] = a[j] * frcp(d[j]);
      *(f32x4*)&tt[c * 4] = o;
    }
    __syncthreads();
    float* brow = beta_slot + ((size_t)((b * 4 + h) * 256 + q)) * 3000;
    for (int c = tid; c < 750; c += 256) {
      f32x4 o;
      #pragma unroll
      for (int j = 0; j < 4; j++) {
        int k = c * 4 + j;
        float s = 0.f;
        #pragma unroll
        for (int w = 0; w < 16; w++) s += tt[k + w];
        o[j] = se[k] * s;
      }
      *(f32x4*)&brow[c * 4] = o;
    }
    __syncthreads();
  }
}

// ---------------------------------------------------------------------------
extern "C" void kernel_launch(void* const* d_in, const int* in_sizes, int n_in,
                              void* d_out, int out_size, void* d_ws, size_t ws_size,
                              hipStream_t stream)
{
  const float* key        = (const float*)d_in[0];
  const float* query      = (const float*)d_in[1];
  const float* w_key_ma   = (const float*)d_in[2];
  const float* b_key_ma   = (const float*)d_in[3];
  const float* w_query_ma = (const float*)d_in[4];
  const float* b_query_ma = (const float*)d_in[5];
  const float* rvec       = (const float*)d_in[6];
  const float* w_key_ca   = (const float*)d_in[7];
  const float* b_key_ca   = (const float*)d_in[8];
  const float* w_query_ca = (const float*)d_in[9];
  const float* b_query_ca = (const float*)d_in[10];
  const float* w_value    = (const float*)d_in[11];
  const float* b_value    = (const float*)d_in[12];

  // Outputs FP32: cv | alpha | beta, flat.
  float* out       = (float*)d_out;
  float* cv_out    = out;                                  // (8,256,512)
  float* alpha_out = out + (size_t)1048576;                // (8,4,256,3000)
  float* beta_out  = alpha_out + (size_t)24576000;         // (8,4,256,3000)
  half_t* p16      = (half_t*)beta_out;                    // p_choose fp16, dead before beta

  dim3 blk(256);
  bool v3 = ws_size >= (size_t)109322240;

  hipMemsetAsync(cv_out, 0, (size_t)1048576 * sizeof(float), stream);  // cv K-split atomics

  if (v3) {
    // v3 layout: kbuf2[24000][1024] | qbuf[2048][1024] f32 | u | vtbuf | wts | catbias
    half_t* kbuf2 = (half_t*)d_ws;
    float*  qbuf  = (float*)((char*)d_ws + 49152000);
    float*  u_buf = (float*)((char*)d_ws + 57540608);
    half_t* vtbuf = (half_t*)((char*)d_ws + 82116608);
    half_t* wt_q  = (half_t*)((char*)d_ws + 106692608);   // [1024][512]
    half_t* wt_k  = (half_t*)((char*)d_ws + 107741184);   // [1024][512]
    half_t* wt_v  = (half_t*)((char*)d_ws + 108789760);
    float*  cb_q  = (float*)((char*)d_ws + 109314048);
    float*  cb_k  = (float*)((char*)d_ws + 109318144);

    wtrans_all<<<dim3(16,16,5), blk, 0, stream>>>(
        w_query_ma, wt_q, w_query_ca, wt_q + 262144,
        w_key_ma,   wt_k, w_key_ca,   wt_k + 262144,
        w_value,    wt_v);
    catbias<<<dim3(1), blk, 0, stream>>>(b_query_ma, b_query_ca, b_key_ma, b_key_ca, cb_q, cb_k);

    mgemm<0,false,false,float ><<<dim3(8,16,1),  blk, 0, stream>>>(query, wt_q, qbuf, 2048, 1024, 512, 512,512,1024, 1,1,512, 0,0,0,0,0,0, cb_q, nullptr);
    mgemm<0,false,false,half_t><<<dim3(8,188,1), blk, 0, stream>>>(key,   wt_k, kbuf2, 24000,1024, 512, 512,512,1024, 1,1,512, 0,0,0,0,0,0, cb_k, nullptr);

    mgemm<1,false,false,half_t><<<dim3(24,2,32), blk, 0, stream>>>(qbuf, kbuf2, p16, 256,3000, 128, 1024,1024,3000, 4,1,128,
        262144,128, 3072000,128, 3072000,768000, nullptr, rvec);

    // FUSED: scan (0-31) + u GEMM (32-415) + vT shells (416-1167)
    fused_mid<<<dim3(1168), blk, 0, stream>>>(p16, alpha_out,
        qbuf + 512, kbuf2 + 512, 1024, 1024, 262144, 3072000,
        u_buf, key, wt_v, vtbuf, b_value);

    beta_kernel<<<dim3(2048), blk, 0, stream>>>(u_buf, alpha_out, beta_out);

    mgemm<3,false,true,float><<<dim3(1,2,256), blk, 0, stream>>>(beta_out, vtbuf, cv_out, 256,128,3000, 3000,24000,512, 4,8,384,
        3072000,768000, 3000,3072000, 131072,128, nullptr, nullptr);
  } else {
    // v1 fallback: kbuf | qbuf | u | 5x wt. 55.97MB.
    if (ws_size < (size_t)55967744) return;
    half_t* kbuf   = (half_t*)d_ws;
    float*  qbuf   = (float*)((char*)d_ws + 24576000);
    float*  u_buf  = (float*)((char*)d_ws + 28770304);
    half_t* wt_qma = (half_t*)((char*)d_ws + 53346304);
    half_t* wt_kma = (half_t*)((char*)d_ws + 53870592);
    half_t* wt_qca = (half_t*)((char*)d_ws + 54394880);
    half_t* wt_kca = (half_t*)((char*)d_ws + 54919168);
    half_t* wt_v   = (half_t*)((char*)d_ws + 55443456);

    wtrans_all<<<dim3(16,16,5), blk, 0, stream>>>(
        w_query_ma, wt_qma, w_query_ca, wt_qca,
        w_key_ma,   wt_kma, w_key_ca,   wt_kca,
        w_value,    wt_v);

    mgemm<0,false,false,float ><<<dim3(4,16,1),  blk, 0, stream>>>(query, wt_qma, qbuf, 2048, 512, 512, 512,512,512, 1,1,512, 0,0,0,0,0,0, b_query_ma, nullptr);
    mgemm<0,false,false,half_t><<<dim3(4,188,1), blk, 0, stream>>>(key,   wt_kma, kbuf, 24000,512, 512, 512,512,512, 1,1,512, 0,0,0,0,0,0, b_key_ma,   nullptr);
    mgemm<1,false,false,half_t><<<dim3(24,2,32), blk, 0, stream>>>(qbuf,  kbuf, p16, 256,3000, 128, 512,512,3000, 4,1,128,
        131072,128, 1536000,128, 3072000,768000, nullptr, rvec);

    mgemm<0,false,false,float ><<<dim3(4,16,1),  blk, 0, stream>>>(query, wt_qca, qbuf, 2048, 512, 512, 512,512,512, 1,1,512, 0,0,0,0,0,0, b_query_ca, nullptr);
    mgemm<0,false,false,half_t><<<dim3(4,188,1), blk, 0, stream>>>(key,   wt_kca, kbuf, 24000,512, 512, 512,512,512, 1,1,512, 0,0,0,0,0,0, b_key_ca,   nullptr);

    // FUSED: scan (0-31) + u GEMM (32-415); vT serial after (into kbuf)
    fused_mid<<<dim3(416), blk, 0, stream>>>(p16, alpha_out,
        qbuf, kbuf, 512, 512, 131072, 1536000,
        u_buf, key, wt_v, kbuf, b_value);

    mgemm<0,true,false,half_t><<<dim3(4,188,1), blk, 0, stream>>>(key, wt_v, kbuf, 24000,512, 512, 512,512,24000, 1,1,512, 0,0,0,0,0,0, b_value, nullptr);

    beta_kernel<<<dim3(2048), blk, 0, stream>>>(u_buf, alpha_out, beta_out);

    mgemm<3,false,true,float><<<dim3(1,2,256), blk, 0, stream>>>(beta_out, kbuf, cv_out, 256,128,3000, 3000,24000,512, 4,8,384,
        3072000,768000, 3000,3072000, 131072,128, nullptr, nullptr);
  }
}

// Round 17
// 544.448 us; speedup vs baseline: 4.7631x; 1.0620x over previous
//
#include <hip/hip_runtime.h>
#include <hip/hip_bf16.h>
#include <math.h>

#define EPSV 1e-6f
#define INV_SCALE 0.04419417382415922f   // 1/sqrt(512)

typedef _Float16 half_t;
typedef __attribute__((ext_vector_type(8))) _Float16 half8;
typedef __attribute__((ext_vector_type(4))) _Float16 half4v;
typedef __attribute__((ext_vector_type(4))) float    f32x4;

__device__ __forceinline__ float ldf(const float* p)  { return *p; }
__device__ __forceinline__ float ldf(const half_t* p) { return (float)*p; }
__device__ __forceinline__ void  stf(float* p, float v)  { *p = v; }
__device__ __forceinline__ void  stf(half_t* p, float v) { *p = (half_t)v; }
__device__ __forceinline__ float frcp(float x) { return __builtin_amdgcn_rcpf(x); }

// ---------------------------------------------------------------------------
// DPP wave-64 inclusive scans (validated rounds 11-16).
// ---------------------------------------------------------------------------
template<int CTRL, int RMASK>
__device__ __forceinline__ float dpp_add_step(float x) {
  int t = __builtin_amdgcn_update_dpp(0, __float_as_int(x), CTRL, RMASK, 0xf, true);
  return x + __int_as_float(t);
}
template<int CTRL, int RMASK>
__device__ __forceinline__ float dpp_mul_step(float x) {
  int t = __builtin_amdgcn_update_dpp(0x3f800000, __float_as_int(x), CTRL, RMASK, 0xf, false);
  return x * __int_as_float(t);
}
__device__ __forceinline__ float wave_iscan_add(float x) {
  x = dpp_add_step<0x111,0xf>(x);
  x = dpp_add_step<0x112,0xf>(x);
  x = dpp_add_step<0x114,0xf>(x);
  x = dpp_add_step<0x118,0xf>(x);
  x = dpp_add_step<0x142,0xa>(x);
  x = dpp_add_step<0x143,0xc>(x);
  return x;
}
__device__ __forceinline__ float wave_iscan_mul(float x) {
  x = dpp_mul_step<0x111,0xf>(x);
  x = dpp_mul_step<0x112,0xf>(x);
  x = dpp_mul_step<0x114,0xf>(x);
  x = dpp_mul_step<0x118,0xf>(x);
  x = dpp_mul_step<0x142,0xa>(x);
  x = dpp_mul_step<0x143,0xc>(x);
  return x;
}

// LDS-only barrier (skips the vmcnt(0) drain __syncthreads emits).
__device__ __forceinline__ void block_sync_lds() {
  asm volatile("s_waitcnt lgkmcnt(0)" ::: "memory");
  __builtin_amdgcn_s_barrier();
  asm volatile("" ::: "memory");
}

// Cross-wave prefix helpers over 4 wave-sums (one f32x4 read + masked ops).
__device__ __forceinline__ float cross_sum4(const float* ws, int wid) {
  f32x4 a = *(const f32x4*)ws;
  float s = 0.f;
  #pragma unroll
  for (int j = 0; j < 4; j++) s += (wid > j) ? a[j] : 0.f;
  return s;
}
__device__ __forceinline__ float cross_prod4(const float* ws, int wid) {
  f32x4 a = *(const f32x4*)ws;
  float p = 1.f;
  #pragma unroll
  for (int j = 0; j < 4; j++) p *= (wid > j) ? a[j] : 1.f;
  return p;
}

// ---------------------------------------------------------------------------
// All five weight transposes in ONE dispatch: grid (16,16,5).
// ---------------------------------------------------------------------------
__global__ __launch_bounds__(256)
void wtrans_all(const float* __restrict__ s0, half_t* __restrict__ d0,
                const float* __restrict__ s1, half_t* __restrict__ d1,
                const float* __restrict__ s2, half_t* __restrict__ d2,
                const float* __restrict__ s3, half_t* __restrict__ d3,
                const float* __restrict__ s4, half_t* __restrict__ d4)
{
  __shared__ float t[32][33];
  const float* W; half_t* WT;
  switch (blockIdx.z) {
    case 0: W = s0; WT = d0; break;
    case 1: W = s1; WT = d1; break;
    case 2: W = s2; WT = d2; break;
    case 3: W = s3; WT = d3; break;
    default: W = s4; WT = d4; break;
  }
  int bx = blockIdx.x, by = blockIdx.y;
  int tid = threadIdx.x;
  int r = tid >> 3, cq = tid & 7;
  float4 v = *(const float4*)&W[(size_t)(bx * 32 + r) * 512 + by * 32 + cq * 4];
  t[r][cq * 4 + 0] = v.x; t[r][cq * 4 + 1] = v.y;
  t[r][cq * 4 + 2] = v.z; t[r][cq * 4 + 3] = v.w;
  __syncthreads();
  half4v o;
  o[0] = (half_t)t[cq * 4 + 0][r];
  o[1] = (half_t)t[cq * 4 + 1][r];
  o[2] = (half_t)t[cq * 4 + 2][r];
  o[3] = (half_t)t[cq * 4 + 3][r];
  *(half4v*)&WT[(size_t)(by * 32 + r) * 512 + bx * 32 + cq * 4] = o;
}

// Concatenated biases for the merged N=1024 projections (v3 only).
__global__ __launch_bounds__(256)
void catbias(const float* __restrict__ a, const float* __restrict__ b,
             const float* __restrict__ c, const float* __restrict__ d,
             float* __restrict__ cbq, float* __restrict__ cbk)
{
  int t = threadIdx.x;
  for (int i = t; i < 512; i += 256) {
    cbq[i] = a[i]; cbq[512 + i] = b[i];
    cbk[i] = c[i]; cbk[512 + i] = d[i];
  }
}

// ---------------------------------------------------------------------------
// MFMA GEMM body. tid in [0,256). K-split via kdiv/kc; ATOM -> atomicAdd;
// CT -> store C transposed (vT).
// ---------------------------------------------------------------------------
struct GemmLds { half_t As[4][128][8]; half_t Bs[4][128][8]; };
struct __align__(16) ScanLds { float wsA[2][4]; float wsB[2][4]; };

template<int MODE, bool CT, bool ATOM, typename TC>
__device__ __forceinline__
void mgemm_body(GemmLds& L, int tid, int bxx, int byy, int bzz,
                const float* __restrict__ A, const half_t* __restrict__ BT,
                TC* __restrict__ C, int M, int N, int Kd,
                int lda, int ldb, int ldc, int hdiv, int kdiv, int kc,
                long long sAb, long long sAh, long long sBb, long long sBh,
                long long sCb, long long sCh,
                const float* __restrict__ bias, const float* __restrict__ rvec)
{
  int ks = bzz % kdiv; int zz = bzz / kdiv;
  int bz = zz / hdiv, hz = zz - bz * hdiv;
  A  += (size_t)bz * sAb + (size_t)hz * sAh + (size_t)ks * kc;
  BT += (size_t)bz * sBb + (size_t)hz * sBh + (size_t)ks * kc;
  C  += (size_t)bz * sCb + (size_t)hz * sCh;
  int Ke = Kd - ks * kc; if (Ke > kc) Ke = kc;

  int lane = tid & 63, wid = tid >> 6;
  int wm = wid >> 1, wn = wid & 1;
  int m0 = byy * 128, n0 = bxx * 128;

  f32x4 acc[4][4] = {};

  for (int k0 = 0; k0 < Ke; k0 += 32) {
    #pragma unroll
    for (int i = 0; i < 4; i++) {            // A: 128x32 f32 -> f16
      int ch = tid + i * 256;
      int m = ch >> 3, cq = ch & 7, k = cq * 4;
      float4 v = make_float4(0.f, 0.f, 0.f, 0.f);
      if (m0 + m < M && k0 + k < Ke) v = *(const float4*)&A[(size_t)(m0 + m) * lda + k0 + k];
      half4v h;
      h[0] = (half_t)v.x; h[1] = (half_t)v.y; h[2] = (half_t)v.z; h[3] = (half_t)v.w;
      *(half4v*)&L.As[cq >> 1][m][(cq & 1) * 4] = h;
    }
    #pragma unroll
    for (int i = 0; i < 2; i++) {            // B: 128x32 f16
      int ch = tid + i * 256;
      int n = ch >> 2, kb = ch & 3;
      half8 v = {(_Float16)0,(_Float16)0,(_Float16)0,(_Float16)0,
                 (_Float16)0,(_Float16)0,(_Float16)0,(_Float16)0};
      if (n0 + n < N && k0 + kb * 8 < Ke)
        v = *(const half8*)&BT[(size_t)(n0 + n) * ldb + k0 + kb * 8];
      *(half8*)&L.Bs[kb][n][0] = v;
    }
    __syncthreads();
    int kb = lane >> 4, r = lane & 15;
    half8 af[4], bfv[4];
    #pragma unroll
    for (int mi = 0; mi < 4; mi++) af[mi]  = *(const half8*)&L.As[kb][wm * 64 + mi * 16 + r][0];
    #pragma unroll
    for (int ni = 0; ni < 4; ni++) bfv[ni] = *(const half8*)&L.Bs[kb][wn * 64 + ni * 16 + r][0];
    #pragma unroll
    for (int mi = 0; mi < 4; mi++)
      #pragma unroll
      for (int ni = 0; ni < 4; ni++)
        acc[mi][ni] = __builtin_amdgcn_mfma_f32_16x16x32_f16(af[mi], bfv[ni], acc[mi][ni], 0, 0, 0);
    __syncthreads();
  }

  float radd = (MODE == 1) ? rvec[hz] : 0.f;
  int r = lane & 15, g = lane >> 4;
  #pragma unroll
  for (int mi = 0; mi < 4; mi++) {
    #pragma unroll
    for (int ni = 0; ni < 4; ni++) {
      int col = n0 + wn * 64 + ni * 16 + r;
      if (col >= N) continue;
      float bv = (MODE == 0) ? bias[col] : 0.f;
      if (CT) {
        int row0 = m0 + wm * 64 + mi * 16 + g * 4;
        if (row0 + 3 < M) {
          half4v o;
          #pragma unroll
          for (int j = 0; j < 4; j++) o[j] = (half_t)(acc[mi][ni][j] + bv);
          *(half4v*)&((half_t*)C)[(size_t)col * ldc + row0] = o;
        }
      } else {
        #pragma unroll
        for (int j = 0; j < 4; j++) {
          int row = m0 + wm * 64 + mi * 16 + g * 4 + j;
          if (row >= M) continue;
          float v = acc[mi][ni][j];
          if (MODE == 0)      v += bv;
          else if (MODE == 1) v = frcp(1.f + expf(-(v * INV_SCALE + radd)));
          else if (MODE == 2) v *= INV_SCALE;
          if (ATOM) atomicAdd((float*)&C[(size_t)row * ldc + col], v);
          else      stf(&C[(size_t)row * ldc + col], v);
        }
      }
    }
  }
}

template<int MODE, bool CT, bool ATOM, typename TC>
__global__ __launch_bounds__(256)
void mgemm(const float* __restrict__ A, const half_t* __restrict__ BT,
           TC* __restrict__ C, int M, int N, int Kd,
           int lda, int ldb, int ldc, int hdiv, int kdiv, int kc,
           long long sAb, long long sAh, long long sBb, long long sBh,
           long long sCb, long long sCh,
           const float* __restrict__ bias, const float* __restrict__ rvec)
{
  __shared__ GemmLds L;
  mgemm_body<MODE,CT,ATOM,TC>(L, threadIdx.x, blockIdx.x, blockIdx.y, blockIdx.z,
                              A, BT, C, M, N, Kd, lda, ldb, ldc, hdiv, kdiv, kc,
                              sAb, sAh, sBb, sBh, sCb, sCh, bias, rvec);
}

// ---------------------------------------------------------------------------
// FUSED (256 threads, launch_bounds(256,1)):
//  blocks 0-31   : cp+alpha scan — ONE block per chain, 4 waves, 12 elems/lane
//  blocks 32-415 : u GEMM (384 virtual blocks)
//  blocks 416+   : vT projection (v3 only, 752 blocks)
// Scan (round 17): 4-deep software-pipelined p prefetch — four register
// buffers, loop unrolled x4; row i+5 loads into the buffer consumed at step
// i+4 (coverage ~4 steps >> HBM latency; consume-wait is vmcnt(9), no drain).
// ---------------------------------------------------------------------------
union MidLds { GemmLds g; ScanLds s; };

__global__ __launch_bounds__(256, 1)
void fused_mid(const half_t* __restrict__ p16, float* __restrict__ alpha_slot,
               const float* __restrict__ qa, const half_t* __restrict__ kb,
               int lda_u, int ldb_u, long long sAb_u, long long sBb_u,
               float* __restrict__ u_buf,
               const float* __restrict__ key, const half_t* __restrict__ wt_v,
               half_t* __restrict__ vtbuf, const float* __restrict__ b_value)
{
  __shared__ MidLds lds;
  int blk = blockIdx.x;
  int tid = threadIdx.x;

  if (blk >= 32) {
    if (blk < 416) {                     // ---- u GEMM: vb in [0,384) ----
      int vb = blk - 32;
      int bx = vb % 24; int t = vb / 24;
      int by = t & 1;   int bz = t >> 1;
      mgemm_body<2,false,false,float>(lds.g, tid, bx, by, bz, qa, kb, u_buf,
          256, 3000, 512, lda_u, ldb_u, 3000, 1, 1, 512,
          sAb_u, 0, sBb_u, 0, 768000, 0, nullptr, nullptr);
    } else {                             // ---- vT proj: vb in [0,752) ----
      int vb = blk - 416;
      int bx = vb & 3; int by = vb >> 2;
      mgemm_body<0,true,false,half_t>(lds.g, tid, bx, by, 0, key, wt_v, vtbuf,
          24000, 512, 512, 512, 512, 24000, 1, 1, 512,
          0, 0, 0, 0, 0, 0, b_value, nullptr);
    }
    return;
  }

  // ---- scan for chain blk: 256 thr x 12 elems (3000 = 250x12) ----
  __builtin_amdgcn_s_setprio(1);
  float (&wsA)[2][4] = lds.s.wsA;
  float (&wsB)[2][4] = lds.s.wsB;
  int lane = tid & 63, wid = tid >> 6;
  int k0 = tid * 12;
  size_t zbase = (size_t)blk * 768000;   // 256*3000
  const half_t* prow = p16 + zbase;

  half4v ph0[3], pb0[3], pb1[3], pb2[3], pb3[3];
  #pragma unroll
  for (int j = 0; j < 3; j++) {
    int k = k0 + j * 4;
    half4v z = {(_Float16)0,(_Float16)0,(_Float16)0,(_Float16)0};
    bool ok = (k + 4 <= 3000);
    ph0[j] = ok ? *(const half4v*)&prow[k]         : z;   // row 0
    pb0[j] = ok ? *(const half4v*)&prow[3000 + k]  : z;   // row 1
    pb1[j] = ok ? *(const half4v*)&prow[6000 + k]  : z;   // row 2
    pb2[j] = ok ? *(const half4v*)&prow[9000 + k]  : z;   // row 3
    pb3[j] = ok ? *(const half4v*)&prow[12000 + k] : z;   // row 4
  }

  float a_prev[12];
  #pragma unroll
  for (int c = 0; c < 12; c++) a_prev[c] = 0.f;
  if (tid == 0) a_prev[0] = 1.f;

  float cpv[12], w[12];
  { // prologue: cp row 0 (multiplicative DPP scan), w = p0*cp0
    float l[12], m = 1.f;
    float p0f[12];
    #pragma unroll
    for (int c = 0; c < 12; c++) {
      p0f[c] = (float)ph0[c >> 2][c & 3];
      l[c] = m;
      m *= fmaxf(1.f - p0f[c], EPSV);
    }
    float incl = wave_iscan_mul(m);
    if (lane == 63) wsA[1][wid] = incl;
    float exclw = incl * frcp(fmaxf(m, 1e-30f));
    block_sync_lds();
    float base = exclw * cross_prod4(&wsA[1][0], wid);
    #pragma unroll
    for (int c = 0; c < 12; c++) { cpv[c] = base * l[c]; w[c] = p0f[c] * cpv[c]; }
  }

#define SCAN_STEP(I, BUF)                                                     \
  {                                                                           \
    int par = (I) & 1;                                                        \
    float t_[12], s2 = 0.f;                                                   \
    _Pragma("unroll")                                                         \
    for (int c = 0; c < 12; c++) {                                            \
      s2 = fmaf(a_prev[c], frcp(fmaxf(cpv[c], EPSV)), s2);                    \
      t_[c] = s2;                                                             \
    }                                                                         \
    float incl2 = wave_iscan_add(s2);                                         \
    if (lane == 63) wsB[par][wid] = incl2;                                    \
    float excl2 = incl2 - s2;                                                 \
    float pnf[12], l_[12], m_ = 1.f;                                          \
    _Pragma("unroll")                                                         \
    for (int c = 0; c < 12; c++) {                                            \
      pnf[c] = (float)BUF[c >> 2][c & 3];                                     \
      l_[c] = m_;                                                             \
      m_ *= fmaxf(1.f - pnf[c], EPSV);                                        \
    }                                                                         \
    float incl1 = wave_iscan_mul(m_);                                         \
    if (lane == 63) wsA[par][wid] = incl1;                                    \
    float excl1 = incl1 * frcp(fmaxf(m_, 1e-30f));                            \
    block_sync_lds();                                                         \
    if ((I) + 5 <= 255) {                                                     \
      const half_t* nrow = prow + (size_t)((I) + 5) * 3000;                   \
      _Pragma("unroll")                                                       \
      for (int j = 0; j < 3; j++) {                                           \
        int k = k0 + j * 4;                                                   \
        if (k + 4 <= 3000) BUF[j] = *(const half4v*)&nrow[k];                 \
      }                                                                       \
    }                                                                         \
    __builtin_amdgcn_sched_barrier(0);                                        \
    float off = excl2 + cross_sum4(&wsB[par][0], wid);                        \
    size_t rbase = zbase + (size_t)(I) * 3000;                                \
    _Pragma("unroll")                                                         \
    for (int q4 = 0; q4 < 3; q4++) {                                          \
      f32x4 o;                                                                \
      _Pragma("unroll")                                                       \
      for (int j = 0; j < 4; j++) {                                           \
        int c = q4 * 4 + j;                                                   \
        float an = w[c] * (off + t_[c]);                                      \
        a_prev[c] = an;                                                       \
        o[j] = an;                                                            \
      }                                                                       \
      int k = k0 + q4 * 4;                                                    \
      if (k + 4 <= 3000) *(f32x4*)&alpha_slot[rbase + k] = o;                 \
    }                                                                         \
    float base1 = excl1 * cross_prod4(&wsA[par][0], wid);                     \
    _Pragma("unroll")                                                         \
    for (int c = 0; c < 12; c++) { cpv[c] = base1 * l_[c]; w[c] = pnf[c] * cpv[c]; } \
  }

  for (int i = 0; i < 256; i += 4) {
    SCAN_STEP(i,     pb0);
    SCAN_STEP(i + 1, pb1);
    SCAN_STEP(i + 2, pb2);
    SCAN_STEP(i + 3, pb3);
  }
#undef SCAN_STEP
}

// ---------------------------------------------------------------------------
// Chunkwise beta — streaming passes vectorized to f32x4.
// ---------------------------------------------------------------------------
__global__ __launch_bounds__(256)
void beta_kernel(const float* __restrict__ ubuf, const float* __restrict__ alpha_slot,
                 float* __restrict__ beta_slot)
{
  __shared__ __align__(16) float se[3008];
  __shared__ __align__(16) float dn[3008];
  __shared__ __align__(16) float tt[3024];
  __shared__ float red[4];
  int bq = blockIdx.x;
  int b = bq >> 8, q = bq & 255;
  int tid = threadIdx.x;
  int lane = tid & 63, wid = tid >> 6;
  const float* urow = ubuf + (size_t)bq * 3000;
  float lmax = -3.0e38f;
  for (int c = tid; c < 750; c += 256) {
    f32x4 v = *(const f32x4*)&urow[c * 4];
    *(f32x4*)&se[c * 4] = v;
    lmax = fmaxf(lmax, fmaxf(fmaxf(v[0], v[1]), fmaxf(v[2], v[3])));
  }
  #pragma unroll
  for (int d = 32; d > 0; d >>= 1) lmax = fmaxf(lmax, __shfl_xor(lmax, d));
  if (lane == 0) red[wid] = lmax;
  __syncthreads();
  float umax = fmaxf(fmaxf(red[0], red[1]), fmaxf(red[2], red[3]));
  for (int c = tid; c < 750; c += 256) {
    f32x4 v = *(const f32x4*)&se[c * 4];
    #pragma unroll
    for (int j = 0; j < 4; j++) v[j] = fmaxf(expf(v[j] - umax), 1e-5f);
    *(f32x4*)&se[c * 4] = v;
  }
  if (tid < 24) tt[3000 + tid] = 0.f;              // forward-window zero pad
  __syncthreads();
  for (int k = tid; k < 3000; k += 256) {
    int lo = k - 15; if (lo < 0) lo = 0;
    float s = 0.f;
    for (int j = lo; j <= k; j++) s += se[j];
    dn[k] = s;
  }
  __syncthreads();
  for (int h = 0; h < 4; h++) {
    const float* arow = alpha_slot + ((size_t)((b * 4 + h) * 256 + q)) * 3000;
    for (int c = tid; c < 750; c += 256) {
      f32x4 a = *(const f32x4*)&arow[c * 4];
      f32x4 d = *(const f32x4*)&dn[c * 4];
      f32x4 o;
      #pragma unroll
      for (int j = 0; j < 4; j++) o[j] = a[j] * frcp(d[j]);
      *(f32x4*)&tt[c * 4] = o;
    }
    __syncthreads();
    float* brow = beta_slot + ((size_t)((b * 4 + h) * 256 + q)) * 3000;
    for (int c = tid; c < 750; c += 256) {
      f32x4 o;
      #pragma unroll
      for (int j = 0; j < 4; j++) {
        int k = c * 4 + j;
        float s = 0.f;
        #pragma unroll
        for (int w = 0; w < 16; w++) s += tt[k + w];
        o[j] = se[k] * s;
      }
      *(f32x4*)&brow[c * 4] = o;
    }
    __syncthreads();
  }
}

// ---------------------------------------------------------------------------
extern "C" void kernel_launch(void* const* d_in, const int* in_sizes, int n_in,
                              void* d_out, int out_size, void* d_ws, size_t ws_size,
                              hipStream_t stream)
{
  const float* key        = (const float*)d_in[0];
  const float* query      = (const float*)d_in[1];
  const float* w_key_ma   = (const float*)d_in[2];
  const float* b_key_ma   = (const float*)d_in[3];
  const float* w_query_ma = (const float*)d_in[4];
  const float* b_query_ma = (const float*)d_in[5];
  const float* rvec       = (const float*)d_in[6];
  const float* w_key_ca   = (const float*)d_in[7];
  const float* b_key_ca   = (const float*)d_in[8];
  const float* w_query_ca = (const float*)d_in[9];
  const float* b_query_ca = (const float*)d_in[10];
  const float* w_value    = (const float*)d_in[11];
  const float* b_value    = (const float*)d_in[12];

  // Outputs FP32: cv | alpha | beta, flat.
  float* out       = (float*)d_out;
  float* cv_out    = out;                                  // (8,256,512)
  float* alpha_out = out + (size_t)1048576;                // (8,4,256,3000)
  float* beta_out  = alpha_out + (size_t)24576000;         // (8,4,256,3000)
  half_t* p16      = (half_t*)beta_out;                    // p_choose fp16, dead before beta

  dim3 blk(256);
  bool v3 = ws_size >= (size_t)109322240;

  hipMemsetAsync(cv_out, 0, (size_t)1048576 * sizeof(float), stream);  // cv K-split atomics

  if (v3) {
    // v3 layout: kbuf2[24000][1024] | qbuf[2048][1024] f32 | u | vtbuf | wts | catbias
    half_t* kbuf2 = (half_t*)d_ws;
    float*  qbuf  = (float*)((char*)d_ws + 49152000);
    float*  u_buf = (float*)((char*)d_ws + 57540608);
    half_t* vtbuf = (half_t*)((char*)d_ws + 82116608);
    half_t* wt_q  = (half_t*)((char*)d_ws + 106692608);   // [1024][512]
    half_t* wt_k  = (half_t*)((char*)d_ws + 107741184);   // [1024][512]
    half_t* wt_v  = (half_t*)((char*)d_ws + 108789760);
    float*  cb_q  = (float*)((char*)d_ws + 109314048);
    float*  cb_k  = (float*)((char*)d_ws + 109318144);

    wtrans_all<<<dim3(16,16,5), blk, 0, stream>>>(
        w_query_ma, wt_q, w_query_ca, wt_q + 262144,
        w_key_ma,   wt_k, w_key_ca,   wt_k + 262144,
        w_value,    wt_v);
    catbias<<<dim3(1), blk, 0, stream>>>(b_query_ma, b_query_ca, b_key_ma, b_key_ca, cb_q, cb_k);

    mgemm<0,false,false,float ><<<dim3(8,16,1),  blk, 0, stream>>>(query, wt_q, qbuf, 2048, 1024, 512, 512,512,1024, 1,1,512, 0,0,0,0,0,0, cb_q, nullptr);
    mgemm<0,false,false,half_t><<<dim3(8,188,1), blk, 0, stream>>>(key,   wt_k, kbuf2, 24000,1024, 512, 512,512,1024, 1,1,512, 0,0,0,0,0,0, cb_k, nullptr);

    mgemm<1,false,false,half_t><<<dim3(24,2,32), blk, 0, stream>>>(qbuf, kbuf2, p16, 256,3000, 128, 1024,1024,3000, 4,1,128,
        262144,128, 3072000,128, 3072000,768000, nullptr, rvec);

    // FUSED: scan (0-31) + u GEMM (32-415) + vT shells (416-1167)
    fused_mid<<<dim3(1168), blk, 0, stream>>>(p16, alpha_out,
        qbuf + 512, kbuf2 + 512, 1024, 1024, 262144, 3072000,
        u_buf, key, wt_v, vtbuf, b_value);

    beta_kernel<<<dim3(2048), blk, 0, stream>>>(u_buf, alpha_out, beta_out);

    mgemm<3,false,true,float><<<dim3(1,2,256), blk, 0, stream>>>(beta_out, vtbuf, cv_out, 256,128,3000, 3000,24000,512, 4,8,384,
        3072000,768000, 3000,3072000, 131072,128, nullptr, nullptr);
  } else {
    // v1 fallback: kbuf | qbuf | u | 5x wt. 55.97MB.
    if (ws_size < (size_t)55967744) return;
    half_t* kbuf   = (half_t*)d_ws;
    float*  qbuf   = (float*)((char*)d_ws + 24576000);
    float*  u_buf  = (float*)((char*)d_ws + 28770304);
    half_t* wt_qma = (half_t*)((char*)d_ws + 53346304);
    half_t* wt_kma = (half_t*)((char*)d_ws + 53870592);
    half_t* wt_qca = (half_t*)((char*)d_ws + 54394880);
    half_t* wt_kca = (half_t*)((char*)d_ws + 54919168);
    half_t* wt_v   = (half_t*)((char*)d_ws + 55443456);

    wtrans_all<<<dim3(16,16,5), blk, 0, stream>>>(
        w_query_ma, wt_qma, w_query_ca, wt_qca,
        w_key_ma,   wt_kma, w_key_ca,   wt_kca,
        w_value,    wt_v);

    mgemm<0,false,false,float ><<<dim3(4,16,1),  blk, 0, stream>>>(query, wt_qma, qbuf, 2048, 512, 512, 512,512,512, 1,1,512, 0,0,0,0,0,0, b_query_ma, nullptr);
    mgemm<0,false,false,half_t><<<dim3(4,188,1), blk, 0, stream>>>(key,   wt_kma, kbuf, 24000,512, 512, 512,512,512, 1,1,512, 0,0,0,0,0,0, b_key_ma,   nullptr);
    mgemm<1,false,false,half_t><<<dim3(24,2,32), blk, 0, stream>>>(qbuf,  kbuf, p16, 256,3000, 128, 512,512,3000, 4,1,128,
        131072,128, 1536000,128, 3072000,768000, nullptr, rvec);

    mgemm<0,false,false,float ><<<dim3(4,16,1),  blk, 0, stream>>>(query, wt_qca, qbuf, 2048, 512, 512, 512,512,512, 1,1,512, 0,0,0,0,0,0, b_query_ca, nullptr);
    mgemm<0,false,false,half_t><<<dim3(4,188,1), blk, 0, stream>>>(key,   wt_kca, kbuf, 24000,512, 512, 512,512,512, 1,1,512, 0,0,0,0,0,0, b_key_ca,   nullptr);

    // FUSED: scan (0-31) + u GEMM (32-415); vT serial after (into kbuf)
    fused_mid<<<dim3(416), blk, 0, stream>>>(p16, alpha_out,
        qbuf, kbuf, 512, 512, 131072, 1536000,
        u_buf, key, wt_v, kbuf, b_value);

    mgemm<0,true,false,half_t><<<dim3(4,188,1), blk, 0, stream>>>(key, wt_v, kbuf, 24000,512, 512, 512,512,24000, 1,1,512, 0,0,0,0,0,0, b_value, nullptr);

    beta_kernel<<<dim3(2048), blk, 0, stream>>>(u_buf, alpha_out, beta_out);

    mgemm<3,false,true,float><<<dim3(1,2,256), blk, 0, stream>>>(beta_out, kbuf, cv_out, 256,128,3000, 3000,24000,512, 4,8,384,
        3072000,768000, 3000,3072000, 131072,128, nullptr, nullptr);
  }
}

// Round 18
// 497.873 us; speedup vs baseline: 5.2086x; 1.0935x over previous
//
#include <hip/hip_runtime.h>
#include <hip/hip_bf16.h>
#include <math.h>

#define EPSV 1e-6f
#define INV_SCALE 0.04419417382415922f   // 1/sqrt(512)

typedef _Float16 half_t;
typedef __attribute__((ext_vector_type(8))) _Float16 half8;
typedef __attribute__((ext_vector_type(4))) _Float16 half4v;
typedef __attribute__((ext_vector_type(4))) float    f32x4;

__device__ __forceinline__ float ldf(const float* p)  { return *p; }
__device__ __forceinline__ float ldf(const half_t* p) { return (float)*p; }
__device__ __forceinline__ void  stf(float* p, float v)  { *p = v; }
__device__ __forceinline__ void  stf(half_t* p, float v) { *p = (half_t)v; }
__device__ __forceinline__ float frcp(float x) { return __builtin_amdgcn_rcpf(x); }
__device__ __forceinline__ half8 hz8() {
  half8 v = {(_Float16)0,(_Float16)0,(_Float16)0,(_Float16)0,
             (_Float16)0,(_Float16)0,(_Float16)0,(_Float16)0};
  return v;
}

// ---------------------------------------------------------------------------
// DPP wave-64 inclusive scans (validated rounds 11-17).
// ---------------------------------------------------------------------------
template<int CTRL, int RMASK>
__device__ __forceinline__ float dpp_add_step(float x) {
  int t = __builtin_amdgcn_update_dpp(0, __float_as_int(x), CTRL, RMASK, 0xf, true);
  return x + __int_as_float(t);
}
template<int CTRL, int RMASK>
__device__ __forceinline__ float dpp_mul_step(float x) {
  int t = __builtin_amdgcn_update_dpp(0x3f800000, __float_as_int(x), CTRL, RMASK, 0xf, false);
  return x * __int_as_float(t);
}
__device__ __forceinline__ float wave_iscan_add(float x) {
  x = dpp_add_step<0x111,0xf>(x);
  x = dpp_add_step<0x112,0xf>(x);
  x = dpp_add_step<0x114,0xf>(x);
  x = dpp_add_step<0x118,0xf>(x);
  x = dpp_add_step<0x142,0xa>(x);
  x = dpp_add_step<0x143,0xc>(x);
  return x;
}
__device__ __forceinline__ float wave_iscan_mul(float x) {
  x = dpp_mul_step<0x111,0xf>(x);
  x = dpp_mul_step<0x112,0xf>(x);
  x = dpp_mul_step<0x114,0xf>(x);
  x = dpp_mul_step<0x118,0xf>(x);
  x = dpp_mul_step<0x142,0xa>(x);
  x = dpp_mul_step<0x143,0xc>(x);
  return x;
}

// LDS-only barrier (skips the vmcnt(0) drain __syncthreads emits).
__device__ __forceinline__ void block_sync_lds() {
  asm volatile("s_waitcnt lgkmcnt(0)" ::: "memory");
  __builtin_amdgcn_s_barrier();
  asm volatile("" ::: "memory");
}

// Cross-wave prefix helpers over 4 wave-sums.
__device__ __forceinline__ float cross_sum4(const float* ws, int wid) {
  f32x4 a = *(const f32x4*)ws;
  float s = 0.f;
  #pragma unroll
  for (int j = 0; j < 4; j++) s += (wid > j) ? a[j] : 0.f;
  return s;
}
__device__ __forceinline__ float cross_prod4(const float* ws, int wid) {
  f32x4 a = *(const f32x4*)ws;
  float p = 1.f;
  #pragma unroll
  for (int j = 0; j < 4; j++) p *= (wid > j) ? a[j] : 1.f;
  return p;
}

// ---------------------------------------------------------------------------
// All five weight transposes in ONE dispatch: grid (16,16,5).
// ---------------------------------------------------------------------------
__global__ __launch_bounds__(256)
void wtrans_all(const float* __restrict__ s0, half_t* __restrict__ d0,
                const float* __restrict__ s1, half_t* __restrict__ d1,
                const float* __restrict__ s2, half_t* __restrict__ d2,
                const float* __restrict__ s3, half_t* __restrict__ d3,
                const float* __restrict__ s4, half_t* __restrict__ d4)
{
  __shared__ float t[32][33];
  const float* W; half_t* WT;
  switch (blockIdx.z) {
    case 0: W = s0; WT = d0; break;
    case 1: W = s1; WT = d1; break;
    case 2: W = s2; WT = d2; break;
    case 3: W = s3; WT = d3; break;
    default: W = s4; WT = d4; break;
  }
  int bx = blockIdx.x, by = blockIdx.y;
  int tid = threadIdx.x;
  int r = tid >> 3, cq = tid & 7;
  float4 v = *(const float4*)&W[(size_t)(bx * 32 + r) * 512 + by * 32 + cq * 4];
  t[r][cq * 4 + 0] = v.x; t[r][cq * 4 + 1] = v.y;
  t[r][cq * 4 + 2] = v.z; t[r][cq * 4 + 3] = v.w;
  __syncthreads();
  half4v o;
  o[0] = (half_t)t[cq * 4 + 0][r];
  o[1] = (half_t)t[cq * 4 + 1][r];
  o[2] = (half_t)t[cq * 4 + 2][r];
  o[3] = (half_t)t[cq * 4 + 3][r];
  *(half4v*)&WT[(size_t)(by * 32 + r) * 512 + bx * 32 + cq * 4] = o;
}

// key -> f16 copy (12,288,000 elems = 3,072,000 f32x4 chunks).
__global__ __launch_bounds__(256)
void key2h(const float* __restrict__ in, half_t* __restrict__ out)
{
  int i = blockIdx.x * 256 + threadIdx.x;
  if (i < 3072000) {
    f32x4 v = *(const f32x4*)&in[(size_t)i * 4];
    half4v h;
    h[0] = (half_t)v[0]; h[1] = (half_t)v[1]; h[2] = (half_t)v[2]; h[3] = (half_t)v[3];
    *(half4v*)&out[(size_t)i * 4] = h;
  }
}

// Concatenated biases for the merged N=1024 projections (v3 only).
__global__ __launch_bounds__(256)
void catbias(const float* __restrict__ a, const float* __restrict__ b,
             const float* __restrict__ c, const float* __restrict__ d,
             float* __restrict__ cbq, float* __restrict__ cbk)
{
  int t = threadIdx.x;
  for (int i = t; i < 512; i += 256) {
    cbq[i] = a[i]; cbq[512 + i] = b[i];
    cbk[i] = c[i]; cbk[512 + i] = d[i];
  }
}

// ---------------------------------------------------------------------------
// MFMA GEMM body. A operand fp32 (staged+cast) or f16 (direct 16B chunks).
// ---------------------------------------------------------------------------
struct GemmLds { half_t As[4][128][8]; half_t Bs[4][128][8]; };
struct __align__(16) ScanLds { float wsA[2][4]; float wsB[2][4]; };

__device__ __forceinline__
void stage_a(GemmLds& L, int tid, const float* __restrict__ A,
             int M, int Ke, int lda, int m0, int k0)
{
  #pragma unroll
  for (int i = 0; i < 4; i++) {
    int ch = tid + i * 256;
    int m = ch >> 3, cq = ch & 7, k = cq * 4;
    float4 v = make_float4(0.f, 0.f, 0.f, 0.f);
    if (m0 + m < M && k0 + k < Ke) v = *(const float4*)&A[(size_t)(m0 + m) * lda + k0 + k];
    half4v h;
    h[0] = (half_t)v.x; h[1] = (half_t)v.y; h[2] = (half_t)v.z; h[3] = (half_t)v.w;
    *(half4v*)&L.As[cq >> 1][m][(cq & 1) * 4] = h;
  }
}
__device__ __forceinline__
void stage_a(GemmLds& L, int tid, const half_t* __restrict__ A,
             int M, int Ke, int lda, int m0, int k0)
{
  #pragma unroll
  for (int i = 0; i < 2; i++) {
    int ch = tid + i * 256;
    int m = ch >> 2, kb = ch & 3;
    half8 v = hz8();
    if (m0 + m < M && k0 + kb * 8 < Ke)
      v = *(const half8*)&A[(size_t)(m0 + m) * lda + k0 + kb * 8];
    *(half8*)&L.As[kb][m][0] = v;
  }
}

template<int MODE, bool CT, bool ATOM, typename TA, typename TC>
__device__ __forceinline__
void mgemm_body(GemmLds& L, int tid, int bxx, int byy, int bzz,
                const TA* __restrict__ A, const half_t* __restrict__ BT,
                TC* __restrict__ C, int M, int N, int Kd,
                int lda, int ldb, int ldc, int hdiv, int kdiv, int kc,
                long long sAb, long long sAh, long long sBb, long long sBh,
                long long sCb, long long sCh,
                const float* __restrict__ bias, const float* __restrict__ rvec)
{
  int ks = bzz % kdiv; int zz = bzz / kdiv;
  int bz = zz / hdiv, hz = zz - bz * hdiv;
  A  += (size_t)bz * sAb + (size_t)hz * sAh + (size_t)ks * kc;
  BT += (size_t)bz * sBb + (size_t)hz * sBh + (size_t)ks * kc;
  C  += (size_t)bz * sCb + (size_t)hz * sCh;
  int Ke = Kd - ks * kc; if (Ke > kc) Ke = kc;

  int lane = tid & 63, wid = tid >> 6;
  int wm = wid >> 1, wn = wid & 1;
  int m0 = byy * 128, n0 = bxx * 128;

  f32x4 acc[4][4] = {};

  for (int k0 = 0; k0 < Ke; k0 += 32) {
    stage_a(L, tid, A, M, Ke, lda, m0, k0);
    #pragma unroll
    for (int i = 0; i < 2; i++) {            // B: 128x32 f16
      int ch = tid + i * 256;
      int n = ch >> 2, kb = ch & 3;
      half8 v = hz8();
      if (n0 + n < N && k0 + kb * 8 < Ke)
        v = *(const half8*)&BT[(size_t)(n0 + n) * ldb + k0 + kb * 8];
      *(half8*)&L.Bs[kb][n][0] = v;
    }
    __syncthreads();
    int kb = lane >> 4, r = lane & 15;
    half8 af[4], bfv[4];
    #pragma unroll
    for (int mi = 0; mi < 4; mi++) af[mi]  = *(const half8*)&L.As[kb][wm * 64 + mi * 16 + r][0];
    #pragma unroll
    for (int ni = 0; ni < 4; ni++) bfv[ni] = *(const half8*)&L.Bs[kb][wn * 64 + ni * 16 + r][0];
    #pragma unroll
    for (int mi = 0; mi < 4; mi++)
      #pragma unroll
      for (int ni = 0; ni < 4; ni++)
        acc[mi][ni] = __builtin_amdgcn_mfma_f32_16x16x32_f16(af[mi], bfv[ni], acc[mi][ni], 0, 0, 0);
    __syncthreads();
  }

  float radd = (MODE == 1) ? rvec[hz] : 0.f;
  int r = lane & 15, g = lane >> 4;
  #pragma unroll
  for (int mi = 0; mi < 4; mi++) {
    #pragma unroll
    for (int ni = 0; ni < 4; ni++) {
      int col = n0 + wn * 64 + ni * 16 + r;
      if (col >= N) continue;
      float bv = (MODE == 0) ? bias[col] : 0.f;
      if (CT) {
        int row0 = m0 + wm * 64 + mi * 16 + g * 4;
        if (row0 + 3 < M) {
          half4v o;
          #pragma unroll
          for (int j = 0; j < 4; j++) o[j] = (half_t)(acc[mi][ni][j] + bv);
          *(half4v*)&((half_t*)C)[(size_t)col * ldc + row0] = o;
        }
      } else {
        #pragma unroll
        for (int j = 0; j < 4; j++) {
          int row = m0 + wm * 64 + mi * 16 + g * 4 + j;
          if (row >= M) continue;
          float v = acc[mi][ni][j];
          if (MODE == 0)      v += bv;
          else if (MODE == 1) v = frcp(1.f + expf(-(v * INV_SCALE + radd)));
          else if (MODE == 2) v *= INV_SCALE;
          if (ATOM) atomicAdd((float*)&C[(size_t)row * ldc + col], v);
          else      stf(&C[(size_t)row * ldc + col], v);
        }
      }
    }
  }
}

template<int MODE, bool CT, bool ATOM, typename TA, typename TC>
__global__ __launch_bounds__(256)
void mgemm(const TA* __restrict__ A, const half_t* __restrict__ BT,
           TC* __restrict__ C, int M, int N, int Kd,
           int lda, int ldb, int ldc, int hdiv, int kdiv, int kc,
           long long sAb, long long sAh, long long sBb, long long sBh,
           long long sCb, long long sCh,
           const float* __restrict__ bias, const float* __restrict__ rvec)
{
  __shared__ GemmLds L;
  mgemm_body<MODE,CT,ATOM,TA,TC>(L, threadIdx.x, blockIdx.x, blockIdx.y, blockIdx.z,
                                 A, BT, C, M, N, Kd, lda, ldb, ldc, hdiv, kdiv, kc,
                                 sAb, sAh, sBb, sBh, sCb, sCh, bias, rvec);
}

// ---------------------------------------------------------------------------
// FUSED (256 threads, launch_bounds(256,1)):
//  blocks 0-31   : cp+alpha scan — 8-deep software-pipelined p prefetch
//  blocks 32-415 : u GEMM (384 virtual blocks), A = q_ca f16
//  blocks 416+   : vT projection (752 blocks), A = keyh f16
// ---------------------------------------------------------------------------
union MidLds { GemmLds g; ScanLds s; };

__global__ __launch_bounds__(256, 1)
void fused_mid(const half_t* __restrict__ p16, float* __restrict__ alpha_slot,
               const half_t* __restrict__ qa, const half_t* __restrict__ kb,
               int lda_u, int ldb_u, long long sAb_u, long long sBb_u,
               float* __restrict__ u_buf,
               const half_t* __restrict__ keyh, const half_t* __restrict__ wt_v,
               half_t* __restrict__ vtbuf, const float* __restrict__ b_value)
{
  __shared__ MidLds lds;
  int blk = blockIdx.x;
  int tid = threadIdx.x;

  if (blk >= 32) {
    if (blk < 416) {                     // ---- u GEMM: vb in [0,384) ----
      int vb = blk - 32;
      int bx = vb % 24; int t = vb / 24;
      int by = t & 1;   int bz = t >> 1;
      mgemm_body<2,false,false,half_t,float>(lds.g, tid, bx, by, bz, qa, kb, u_buf,
          256, 3000, 512, lda_u, ldb_u, 3000, 1, 1, 512,
          sAb_u, 0, sBb_u, 0, 768000, 0, nullptr, nullptr);
    } else {                             // ---- vT proj: vb in [0,752) ----
      int vb = blk - 416;
      int bx = vb & 3; int by = vb >> 2;
      mgemm_body<0,true,false,half_t,half_t>(lds.g, tid, bx, by, 0, keyh, wt_v, vtbuf,
          24000, 512, 512, 512, 512, 24000, 1, 1, 512,
          0, 0, 0, 0, 0, 0, b_value, nullptr);
    }
    return;
  }

  // ---- scan for chain blk: 256 thr x 12 elems (3000 = 250x12) ----
  __builtin_amdgcn_s_setprio(1);
  float (&wsA)[2][4] = lds.s.wsA;
  float (&wsB)[2][4] = lds.s.wsB;
  int lane = tid & 63, wid = tid >> 6;
  int k0 = tid * 12;
  size_t zbase = (size_t)blk * 768000;   // 256*3000
  const half_t* prow = p16 + zbase;

  half4v ph0[3], pb0[3], pb1[3], pb2[3], pb3[3], pb4[3], pb5[3], pb6[3], pb7[3];
  #pragma unroll
  for (int j = 0; j < 3; j++) {
    int k = k0 + j * 4;
    half4v z = {(_Float16)0,(_Float16)0,(_Float16)0,(_Float16)0};
    bool ok = (k + 4 <= 3000);
    ph0[j] = ok ? *(const half4v*)&prow[k]         : z;   // row 0
    pb0[j] = ok ? *(const half4v*)&prow[3000 + k]  : z;   // row 1
    pb1[j] = ok ? *(const half4v*)&prow[6000 + k]  : z;   // row 2
    pb2[j] = ok ? *(const half4v*)&prow[9000 + k]  : z;   // row 3
    pb3[j] = ok ? *(const half4v*)&prow[12000 + k] : z;   // row 4
    pb4[j] = ok ? *(const half4v*)&prow[15000 + k] : z;   // row 5
    pb5[j] = ok ? *(const half4v*)&prow[18000 + k] : z;   // row 6
    pb6[j] = ok ? *(const half4v*)&prow[21000 + k] : z;   // row 7
    pb7[j] = ok ? *(const half4v*)&prow[24000 + k] : z;   // row 8
  }

  float a_prev[12];
  #pragma unroll
  for (int c = 0; c < 12; c++) a_prev[c] = 0.f;
  if (tid == 0) a_prev[0] = 1.f;

  float cpv[12], w[12];
  { // prologue: cp row 0 (multiplicative DPP scan), w = p0*cp0
    float l[12], m = 1.f;
    float p0f[12];
    #pragma unroll
    for (int c = 0; c < 12; c++) {
      p0f[c] = (float)ph0[c >> 2][c & 3];
      l[c] = m;
      m *= fmaxf(1.f - p0f[c], EPSV);
    }
    float incl = wave_iscan_mul(m);
    if (lane == 63) wsA[1][wid] = incl;
    float exclw = incl * frcp(fmaxf(m, 1e-30f));
    block_sync_lds();
    float base = exclw * cross_prod4(&wsA[1][0], wid);
    #pragma unroll
    for (int c = 0; c < 12; c++) { cpv[c] = base * l[c]; w[c] = p0f[c] * cpv[c]; }
  }

#define SCAN_STEP(I, BUF)                                                     \
  {                                                                           \
    int par = (I) & 1;                                                        \
    float t_[12], s2 = 0.f;                                                   \
    _Pragma("unroll")                                                         \
    for (int c = 0; c < 12; c++) {                                            \
      s2 = fmaf(a_prev[c], frcp(fmaxf(cpv[c], EPSV)), s2);                    \
      t_[c] = s2;                                                             \
    }                                                                         \
    float incl2 = wave_iscan_add(s2);                                         \
    if (lane == 63) wsB[par][wid] = incl2;                                    \
    float excl2 = incl2 - s2;                                                 \
    float pnf[12], l_[12], m_ = 1.f;                                          \
    _Pragma("unroll")                                                         \
    for (int c = 0; c < 12; c++) {                                            \
      pnf[c] = (float)BUF[c >> 2][c & 3];                                     \
      l_[c] = m_;                                                             \
      m_ *= fmaxf(1.f - pnf[c], EPSV);                                        \
    }                                                                         \
    float incl1 = wave_iscan_mul(m_);                                         \
    if (lane == 63) wsA[par][wid] = incl1;                                    \
    float excl1 = incl1 * frcp(fmaxf(m_, 1e-30f));                            \
    block_sync_lds();                                                         \
    if ((I) + 9 <= 255) {                                                     \
      const half_t* nrow = prow + (size_t)((I) + 9) * 3000;                   \
      _Pragma("unroll")                                                       \
      for (int j = 0; j < 3; j++) {                                           \
        int k = k0 + j * 4;                                                   \
        if (k + 4 <= 3000) BUF[j] = *(const half4v*)&nrow[k];                 \
      }                                                                       \
    }                                                                         \
    __builtin_amdgcn_sched_barrier(0);                                        \
    float off = excl2 + cross_sum4(&wsB[par][0], wid);                        \
    size_t rbase = zbase + (size_t)(I) * 3000;                                \
    _Pragma("unroll")                                                         \
    for (int q4 = 0; q4 < 3; q4++) {                                          \
      f32x4 o;                                                                \
      _Pragma("unroll")                                                       \
      for (int j = 0; j < 4; j++) {                                           \
        int c = q4 * 4 + j;                                                   \
        float an = w[c] * (off + t_[c]);                                      \
        a_prev[c] = an;                                                       \
        o[j] = an;                                                            \
      }                                                                       \
      int k = k0 + q4 * 4;                                                    \
      if (k + 4 <= 3000) *(f32x4*)&alpha_slot[rbase + k] = o;                 \
    }                                                                         \
    float base1 = excl1 * cross_prod4(&wsA[par][0], wid);                     \
    _Pragma("unroll")                                                         \
    for (int c = 0; c < 12; c++) { cpv[c] = base1 * l_[c]; w[c] = pnf[c] * cpv[c]; } \
  }

  for (int i = 0; i < 256; i += 8) {
    SCAN_STEP(i,     pb0);
    SCAN_STEP(i + 1, pb1);
    SCAN_STEP(i + 2, pb2);
    SCAN_STEP(i + 3, pb3);
    SCAN_STEP(i + 4, pb4);
    SCAN_STEP(i + 5, pb5);
    SCAN_STEP(i + 6, pb6);
    SCAN_STEP(i + 7, pb7);
  }
#undef SCAN_STEP
}

// ---------------------------------------------------------------------------
// Chunkwise beta — streaming passes vectorized to f32x4.
// ---------------------------------------------------------------------------
__global__ __launch_bounds__(256)
void beta_kernel(const float* __restrict__ ubuf, const float* __restrict__ alpha_slot,
                 float* __restrict__ beta_slot)
{
  __shared__ __align__(16) float se[3008];
  __shared__ __align__(16) float dn[3008];
  __shared__ __align__(16) float tt[3024];
  __shared__ float red[4];
  int bq = blockIdx.x;
  int b = bq >> 8, q = bq & 255;
  int tid = threadIdx.x;
  int lane = tid & 63, wid = tid >> 6;
  const float* urow = ubuf + (size_t)bq * 3000;
  float lmax = -3.0e38f;
  for (int c = tid; c < 750; c += 256) {
    f32x4 v = *(const f32x4*)&urow[c * 4];
    *(f32x4*)&se[c * 4] = v;
    lmax = fmaxf(lmax, fmaxf(fmaxf(v[0], v[1]), fmaxf(v[2], v[3])));
  }
  #pragma unroll
  for (int d = 32; d > 0; d >>= 1) lmax = fmaxf(lmax, __shfl_xor(lmax, d));
  if (lane == 0) red[wid] = lmax;
  __syncthreads();
  float umax = fmaxf(fmaxf(red[0], red[1]), fmaxf(red[2], red[3]));
  for (int c = tid; c < 750; c += 256) {
    f32x4 v = *(const f32x4*)&se[c * 4];
    #pragma unroll
    for (int j = 0; j < 4; j++) v[j] = fmaxf(expf(v[j] - umax), 1e-5f);
    *(f32x4*)&se[c * 4] = v;
  }
  if (tid < 24) tt[3000 + tid] = 0.f;              // forward-window zero pad
  __syncthreads();
  for (int k = tid; k < 3000; k += 256) {
    int lo = k - 15; if (lo < 0) lo = 0;
    float s = 0.f;
    for (int j = lo; j <= k; j++) s += se[j];
    dn[k] = s;
  }
  __syncthreads();
  for (int h = 0; h < 4; h++) {
    const float* arow = alpha_slot + ((size_t)((b * 4 + h) * 256 + q)) * 3000;
    for (int c = tid; c < 750; c += 256) {
      f32x4 a = *(const f32x4*)&arow[c * 4];
      f32x4 d = *(const f32x4*)&dn[c * 4];
      f32x4 o;
      #pragma unroll
      for (int j = 0; j < 4; j++) o[j] = a[j] * frcp(d[j]);
      *(f32x4*)&tt[c * 4] = o;
    }
    __syncthreads();
    float* brow = beta_slot + ((size_t)((b * 4 + h) * 256 + q)) * 3000;
    for (int c = tid; c < 750; c += 256) {
      f32x4 o;
      #pragma unroll
      for (int j = 0; j < 4; j++) {
        int k = c * 4 + j;
        float s = 0.f;
        #pragma unroll
        for (int w = 0; w < 16; w++) s += tt[k + w];
        o[j] = se[k] * s;
      }
      *(f32x4*)&brow[c * 4] = o;
    }
    __syncthreads();
  }
}

// ---------------------------------------------------------------------------
extern "C" void kernel_launch(void* const* d_in, const int* in_sizes, int n_in,
                              void* d_out, int out_size, void* d_ws, size_t ws_size,
                              hipStream_t stream)
{
  const float* key        = (const float*)d_in[0];
  const float* query      = (const float*)d_in[1];
  const float* w_key_ma   = (const float*)d_in[2];
  const float* b_key_ma   = (const float*)d_in[3];
  const float* w_query_ma = (const float*)d_in[4];
  const float* b_query_ma = (const float*)d_in[5];
  const float* rvec       = (const float*)d_in[6];
  const float* w_key_ca   = (const float*)d_in[7];
  const float* b_key_ca   = (const float*)d_in[8];
  const float* w_query_ca = (const float*)d_in[9];
  const float* b_query_ca = (const float*)d_in[10];
  const float* w_value    = (const float*)d_in[11];
  const float* b_value    = (const float*)d_in[12];

  // Outputs FP32: cv | alpha | beta, flat.
  float* out       = (float*)d_out;
  float* cv_out    = out;                                  // (8,256,512)
  float* alpha_out = out + (size_t)1048576;                // (8,4,256,3000)
  float* beta_out  = alpha_out + (size_t)24576000;         // (8,4,256,3000)
  half_t* p16      = (half_t*)beta_out;                    // p_choose fp16 (first half)
  half_t* keyh     = (half_t*)(beta_out + 12288000);       // key f16 (second half; dead before beta)

  dim3 blk(256);
  bool v3 = ws_size >= (size_t)109322240;

  hipMemsetAsync(cv_out, 0, (size_t)1048576 * sizeof(float), stream);  // cv K-split atomics

  if (v3) {
    // v3 layout: kbuf2[24000][1024] f16 | qbuf[2048][1024] f16 | u f32 | vtbuf | wts | catbias
    half_t* kbuf2 = (half_t*)d_ws;
    half_t* qbuf  = (half_t*)((char*)d_ws + 49152000);
    float*  u_buf = (float*)((char*)d_ws + 57540608);
    half_t* vtbuf = (half_t*)((char*)d_ws + 82116608);
    half_t* wt_q  = (half_t*)((char*)d_ws + 106692608);   // [1024][512]
    half_t* wt_k  = (half_t*)((char*)d_ws + 107741184);   // [1024][512]
    half_t* wt_v  = (half_t*)((char*)d_ws + 108789760);
    float*  cb_q  = (float*)((char*)d_ws + 109314048);
    float*  cb_k  = (float*)((char*)d_ws + 109318144);

    wtrans_all<<<dim3(16,16,5), blk, 0, stream>>>(
        w_query_ma, wt_q, w_query_ca, wt_q + 262144,
        w_key_ma,   wt_k, w_key_ca,   wt_k + 262144,
        w_value,    wt_v);
    catbias<<<dim3(1), blk, 0, stream>>>(b_query_ma, b_query_ca, b_key_ma, b_key_ca, cb_q, cb_k);
    key2h<<<dim3(12000), blk, 0, stream>>>(key, keyh);

    // merged projections: qall (2048x1024, A fp32), kall (24000x1024, A f16)
    mgemm<0,false,false,float ,half_t><<<dim3(8,16,1),  blk, 0, stream>>>(query, wt_q, qbuf, 2048, 1024, 512, 512,512,1024, 1,1,512, 0,0,0,0,0,0, cb_q, nullptr);
    mgemm<0,false,false,half_t,half_t><<<dim3(8,188,1), blk, 0, stream>>>(keyh,  wt_k, kbuf2, 24000,1024, 512, 512,512,1024, 1,1,512, 0,0,0,0,0,0, cb_k, nullptr);

    // e_ma -> p16 (A = q_ma cols of qbuf f16)
    mgemm<1,false,false,half_t,half_t><<<dim3(24,2,32), blk, 0, stream>>>(qbuf, kbuf2, p16, 256,3000, 128, 1024,1024,3000, 4,1,128,
        262144,128, 3072000,128, 3072000,768000, nullptr, rvec);

    // FUSED: scan (0-31) + u GEMM (32-415) + vT shells (416-1167)
    fused_mid<<<dim3(1168), blk, 0, stream>>>(p16, alpha_out,
        qbuf + 512, kbuf2 + 512, 1024, 1024, 262144, 3072000,
        u_buf, keyh, wt_v, vtbuf, b_value);

    beta_kernel<<<dim3(2048), blk, 0, stream>>>(u_buf, alpha_out, beta_out);

    mgemm<3,false,true,float,float><<<dim3(1,2,256), blk, 0, stream>>>(beta_out, vtbuf, cv_out, 256,128,3000, 3000,24000,512, 4,8,384,
        3072000,768000, 3000,3072000, 131072,128, nullptr, nullptr);
  } else {
    // v1 fallback: kbuf | qbuf | u | 5x wt. 55.97MB.
    if (ws_size < (size_t)55967744) return;
    half_t* kbuf   = (half_t*)d_ws;
    half_t* qbuf   = (half_t*)((char*)d_ws + 24576000);
    float*  u_buf  = (float*)((char*)d_ws + 28770304);
    half_t* wt_qma = (half_t*)((char*)d_ws + 53346304);
    half_t* wt_kma = (half_t*)((char*)d_ws + 53870592);
    half_t* wt_qca = (half_t*)((char*)d_ws + 54394880);
    half_t* wt_kca = (half_t*)((char*)d_ws + 54919168);
    half_t* wt_v   = (half_t*)((char*)d_ws + 55443456);

    wtrans_all<<<dim3(16,16,5), blk, 0, stream>>>(
        w_query_ma, wt_qma, w_query_ca, wt_qca,
        w_key_ma,   wt_kma, w_key_ca,   wt_kca,
        w_value,    wt_v);
    key2h<<<dim3(12000), blk, 0, stream>>>(key, keyh);

    mgemm<0,false,false,float ,half_t><<<dim3(4,16,1),  blk, 0, stream>>>(query, wt_qma, qbuf, 2048, 512, 512, 512,512,512, 1,1,512, 0,0,0,0,0,0, b_query_ma, nullptr);
    mgemm<0,false,false,half_t,half_t><<<dim3(4,188,1), blk, 0, stream>>>(keyh,  wt_kma, kbuf, 24000,512, 512, 512,512,512, 1,1,512, 0,0,0,0,0,0, b_key_ma,   nullptr);
    mgemm<1,false,false,half_t,half_t><<<dim3(24,2,32), blk, 0, stream>>>(qbuf,  kbuf, p16, 256,3000, 128, 512,512,3000, 4,1,128,
        131072,128, 1536000,128, 3072000,768000, nullptr, rvec);

    mgemm<0,false,false,float ,half_t><<<dim3(4,16,1),  blk, 0, stream>>>(query, wt_qca, qbuf, 2048, 512, 512, 512,512,512, 1,1,512, 0,0,0,0,0,0, b_query_ca, nullptr);
    mgemm<0,false,false,half_t,half_t><<<dim3(4,188,1), blk, 0, stream>>>(keyh,  wt_kca, kbuf, 24000,512, 512, 512,512,512, 1,1,512, 0,0,0,0,0,0, b_key_ca,   nullptr);

    // FUSED: scan (0-31) + u GEMM (32-415); vT serial after (into kbuf)
    fused_mid<<<dim3(416), blk, 0, stream>>>(p16, alpha_out,
        qbuf, kbuf, 512, 512, 131072, 1536000,
        u_buf, keyh, wt_v, kbuf, b_value);

    mgemm<0,true,false,half_t,half_t><<<dim3(4,188,1), blk, 0, stream>>>(keyh, wt_v, kbuf, 24000,512, 512, 512,512,24000, 1,1,512, 0,0,0,0,0,0, b_value, nullptr);

    beta_kernel<<<dim3(2048), blk, 0, stream>>>(u_buf, alpha_out, beta_out);

    mgemm<3,false,true,float,float><<<dim3(1,2,256), blk, 0, stream>>>(beta_out, kbuf, cv_out, 256,128,3000, 3000,24000,512, 4,8,384,
        3072000,768000, 3000,3072000, 131072,128, nullptr, nullptr);
  }
}

// Round 19
// 429.091 us; speedup vs baseline: 6.0436x; 1.1603x over previous
//
#include <hip/hip_runtime.h>
#include <hip/hip_bf16.h>
#include <math.h>

#define EPSV 1e-6f
#define INV_SCALE 0.04419417382415922f   // 1/sqrt(512)

typedef _Float16 half_t;
typedef __attribute__((ext_vector_type(8))) _Float16 half8;
typedef __attribute__((ext_vector_type(4))) _Float16 half4v;
typedef __attribute__((ext_vector_type(4))) float    f32x4;

__device__ __forceinline__ float ldf(const float* p)  { return *p; }
__device__ __forceinline__ float ldf(const half_t* p) { return (float)*p; }
__device__ __forceinline__ void  stf(float* p, float v)  { *p = v; }
__device__ __forceinline__ void  stf(half_t* p, float v) { *p = (half_t)v; }
__device__ __forceinline__ float frcp(float x) { return __builtin_amdgcn_rcpf(x); }
__device__ __forceinline__ half8 hz8() {
  half8 v = {(_Float16)0,(_Float16)0,(_Float16)0,(_Float16)0,
             (_Float16)0,(_Float16)0,(_Float16)0,(_Float16)0};
  return v;
}

// ---------------------------------------------------------------------------
// DPP wave-64 inclusive scans (validated rounds 11-18).
// ---------------------------------------------------------------------------
template<int CTRL, int RMASK>
__device__ __forceinline__ float dpp_add_step(float x) {
  int t = __builtin_amdgcn_update_dpp(0, __float_as_int(x), CTRL, RMASK, 0xf, true);
  return x + __int_as_float(t);
}
template<int CTRL, int RMASK>
__device__ __forceinline__ float dpp_mul_step(float x) {
  int t = __builtin_amdgcn_update_dpp(0x3f800000, __float_as_int(x), CTRL, RMASK, 0xf, false);
  return x * __int_as_float(t);
}
__device__ __forceinline__ float wave_iscan_add(float x) {
  x = dpp_add_step<0x111,0xf>(x);
  x = dpp_add_step<0x112,0xf>(x);
  x = dpp_add_step<0x114,0xf>(x);
  x = dpp_add_step<0x118,0xf>(x);
  x = dpp_add_step<0x142,0xa>(x);
  x = dpp_add_step<0x143,0xc>(x);
  return x;
}
__device__ __forceinline__ float wave_iscan_mul(float x) {
  x = dpp_mul_step<0x111,0xf>(x);
  x = dpp_mul_step<0x112,0xf>(x);
  x = dpp_mul_step<0x114,0xf>(x);
  x = dpp_mul_step<0x118,0xf>(x);
  x = dpp_mul_step<0x142,0xa>(x);
  x = dpp_mul_step<0x143,0xc>(x);
  return x;
}

// LDS-only barrier (skips the vmcnt(0) drain __syncthreads emits).
__device__ __forceinline__ void block_sync_lds() {
  asm volatile("s_waitcnt lgkmcnt(0)" ::: "memory");
  __builtin_amdgcn_s_barrier();
  asm volatile("" ::: "memory");
}

// Cross-wave prefix helpers over 4 wave-sums.
__device__ __forceinline__ float cross_sum4(const float* ws, int wid) {
  f32x4 a = *(const f32x4*)ws;
  float s = 0.f;
  #pragma unroll
  for (int j = 0; j < 4; j++) s += (wid > j) ? a[j] : 0.f;
  return s;
}
__device__ __forceinline__ float cross_prod4(const float* ws, int wid) {
  f32x4 a = *(const f32x4*)ws;
  float p = 1.f;
  #pragma unroll
  for (int j = 0; j < 4; j++) p *= (wid > j) ? a[j] : 1.f;
  return p;
}

// ---------------------------------------------------------------------------
// PREP (one dispatch): blocks 0-1279 = five 512x512 weight transposes (f32 ->
// f16 [N][K]); blocks 1280-13279 = key->f16 copy; block 13280 = catbias.
// ---------------------------------------------------------------------------
__global__ __launch_bounds__(256)
void prep(const float* __restrict__ s0, half_t* __restrict__ d0,
          const float* __restrict__ s1, half_t* __restrict__ d1,
          const float* __restrict__ s2, half_t* __restrict__ d2,
          const float* __restrict__ s3, half_t* __restrict__ d3,
          const float* __restrict__ s4, half_t* __restrict__ d4,
          const float* __restrict__ key, half_t* __restrict__ keyh,
          const float* __restrict__ ba, const float* __restrict__ bb,
          const float* __restrict__ bc, const float* __restrict__ bd,
          float* __restrict__ cbq, float* __restrict__ cbk)
{
  __shared__ float t[32][33];
  int blk = blockIdx.x;
  int tid = threadIdx.x;
  if (blk < 1280) {
    const float* W; half_t* WT;
    switch (blk >> 8) {
      case 0: W = s0; WT = d0; break;
      case 1: W = s1; WT = d1; break;
      case 2: W = s2; WT = d2; break;
      case 3: W = s3; WT = d3; break;
      default: W = s4; WT = d4; break;
    }
    int tile = blk & 255;
    int bx = tile & 15, by = tile >> 4;
    int r = tid >> 3, cq = tid & 7;
    float4 v = *(const float4*)&W[(size_t)(bx * 32 + r) * 512 + by * 32 + cq * 4];
    t[r][cq * 4 + 0] = v.x; t[r][cq * 4 + 1] = v.y;
    t[r][cq * 4 + 2] = v.z; t[r][cq * 4 + 3] = v.w;
    __syncthreads();
    half4v o;
    o[0] = (half_t)t[cq * 4 + 0][r];
    o[1] = (half_t)t[cq * 4 + 1][r];
    o[2] = (half_t)t[cq * 4 + 2][r];
    o[3] = (half_t)t[cq * 4 + 3][r];
    *(half4v*)&WT[(size_t)(by * 32 + r) * 512 + bx * 32 + cq * 4] = o;
  } else if (blk < 13280) {
    int i = (blk - 1280) * 256 + tid;
    if (i < 3072000) {
      f32x4 v = *(const f32x4*)&key[(size_t)i * 4];
      half4v h;
      h[0] = (half_t)v[0]; h[1] = (half_t)v[1]; h[2] = (half_t)v[2]; h[3] = (half_t)v[3];
      *(half4v*)&keyh[(size_t)i * 4] = h;
    }
  } else {
    if (cbq != nullptr) {
      for (int i = tid; i < 512; i += 256) {
        cbq[i] = ba[i]; cbq[512 + i] = bb[i];
        cbk[i] = bc[i]; cbk[512 + i] = bd[i];
      }
    }
  }
}

// ---------------------------------------------------------------------------
// MFMA GEMM body. A operand fp32 (staged+cast) or f16 (direct 16B chunks).
// ---------------------------------------------------------------------------
struct GemmLds { half_t As[4][128][8]; half_t Bs[4][128][8]; };
struct __align__(16) ScanLds { float wsA[2][4]; float wsB[2][4]; };

__device__ __forceinline__
void stage_a(GemmLds& L, int tid, const float* __restrict__ A,
             int M, int Ke, int lda, int m0, int k0)
{
  #pragma unroll
  for (int i = 0; i < 4; i++) {
    int ch = tid + i * 256;
    int m = ch >> 3, cq = ch & 7, k = cq * 4;
    float4 v = make_float4(0.f, 0.f, 0.f, 0.f);
    if (m0 + m < M && k0 + k < Ke) v = *(const float4*)&A[(size_t)(m0 + m) * lda + k0 + k];
    half4v h;
    h[0] = (half_t)v.x; h[1] = (half_t)v.y; h[2] = (half_t)v.z; h[3] = (half_t)v.w;
    *(half4v*)&L.As[cq >> 1][m][(cq & 1) * 4] = h;
  }
}
__device__ __forceinline__
void stage_a(GemmLds& L, int tid, const half_t* __restrict__ A,
             int M, int Ke, int lda, int m0, int k0)
{
  #pragma unroll
  for (int i = 0; i < 2; i++) {
    int ch = tid + i * 256;
    int m = ch >> 2, kb = ch & 3;
    half8 v = hz8();
    if (m0 + m < M && k0 + kb * 8 < Ke)
      v = *(const half8*)&A[(size_t)(m0 + m) * lda + k0 + kb * 8];
    *(half8*)&L.As[kb][m][0] = v;
  }
}

template<int MODE, bool CT, bool ATOM, typename TA, typename TC>
__device__ __forceinline__
void mgemm_body(GemmLds& L, int tid, int bxx, int byy, int bzz,
                const TA* __restrict__ A, const half_t* __restrict__ BT,
                TC* __restrict__ C, int M, int N, int Kd,
                int lda, int ldb, int ldc, int hdiv, int kdiv, int kc,
                long long sAb, long long sAh, long long sBb, long long sBh,
                long long sCb, long long sCh,
                const float* __restrict__ bias, const float* __restrict__ rvec)
{
  int ks = bzz % kdiv; int zz = bzz / kdiv;
  int bz = zz / hdiv, hz = zz - bz * hdiv;
  A  += (size_t)bz * sAb + (size_t)hz * sAh + (size_t)ks * kc;
  BT += (size_t)bz * sBb + (size_t)hz * sBh + (size_t)ks * kc;
  C  += (size_t)bz * sCb + (size_t)hz * sCh;
  int Ke = Kd - ks * kc; if (Ke > kc) Ke = kc;

  int lane = tid & 63, wid = tid >> 6;
  int wm = wid >> 1, wn = wid & 1;
  int m0 = byy * 128, n0 = bxx * 128;

  f32x4 acc[4][4] = {};

  for (int k0 = 0; k0 < Ke; k0 += 32) {
    stage_a(L, tid, A, M, Ke, lda, m0, k0);
    #pragma unroll
    for (int i = 0; i < 2; i++) {            // B: 128x32 f16
      int ch = tid + i * 256;
      int n = ch >> 2, kb = ch & 3;
      half8 v = hz8();
      if (n0 + n < N && k0 + kb * 8 < Ke)
        v = *(const half8*)&BT[(size_t)(n0 + n) * ldb + k0 + kb * 8];
      *(half8*)&L.Bs[kb][n][0] = v;
    }
    __syncthreads();
    int kb = lane >> 4, r = lane & 15;
    half8 af[4], bfv[4];
    #pragma unroll
    for (int mi = 0; mi < 4; mi++) af[mi]  = *(const half8*)&L.As[kb][wm * 64 + mi * 16 + r][0];
    #pragma unroll
    for (int ni = 0; ni < 4; ni++) bfv[ni] = *(const half8*)&L.Bs[kb][wn * 64 + ni * 16 + r][0];
    #pragma unroll
    for (int mi = 0; mi < 4; mi++)
      #pragma unroll
      for (int ni = 0; ni < 4; ni++)
        acc[mi][ni] = __builtin_amdgcn_mfma_f32_16x16x32_f16(af[mi], bfv[ni], acc[mi][ni], 0, 0, 0);
    __syncthreads();
  }

  float radd = (MODE == 1) ? rvec[hz] : 0.f;
  int r = lane & 15, g = lane >> 4;
  #pragma unroll
  for (int mi = 0; mi < 4; mi++) {
    #pragma unroll
    for (int ni = 0; ni < 4; ni++) {
      int col = n0 + wn * 64 + ni * 16 + r;
      if (col >= N) continue;
      float bv = (MODE == 0) ? bias[col] : 0.f;
      if (CT) {
        int row0 = m0 + wm * 64 + mi * 16 + g * 4;
        if (row0 + 3 < M) {
          half4v o;
          #pragma unroll
          for (int j = 0; j < 4; j++) o[j] = (half_t)(acc[mi][ni][j] + bv);
          *(half4v*)&((half_t*)C)[(size_t)col * ldc + row0] = o;
        }
      } else {
        #pragma unroll
        for (int j = 0; j < 4; j++) {
          int row = m0 + wm * 64 + mi * 16 + g * 4 + j;
          if (row >= M) continue;
          float v = acc[mi][ni][j];
          if (MODE == 0)      v += bv;
          else if (MODE == 1) v = frcp(1.f + expf(-(v * INV_SCALE + radd)));
          else if (MODE == 2) v *= INV_SCALE;
          if (ATOM) atomicAdd((float*)&C[(size_t)row * ldc + col], v);
          else      stf(&C[(size_t)row * ldc + col], v);
        }
      }
    }
  }
}

template<int MODE, bool CT, bool ATOM, typename TA, typename TC>
__global__ __launch_bounds__(256)
void mgemm(const TA* __restrict__ A, const half_t* __restrict__ BT,
           TC* __restrict__ C, int M, int N, int Kd,
           int lda, int ldb, int ldc, int hdiv, int kdiv, int kc,
           long long sAb, long long sAh, long long sBb, long long sBh,
           long long sCb, long long sCh,
           const float* __restrict__ bias, const float* __restrict__ rvec)
{
  __shared__ GemmLds L;
  mgemm_body<MODE,CT,ATOM,TA,TC>(L, threadIdx.x, blockIdx.x, blockIdx.y, blockIdx.z,
                                 A, BT, C, M, N, Kd, lda, ldb, ldc, hdiv, kdiv, kc,
                                 sAb, sAh, sBb, sBh, sCb, sCh, bias, rvec);
}

// ---------------------------------------------------------------------------
// qall + kall merged (v3): blocks 0-127 = qall (2048x1024, A fp32),
// blocks 128-1631 = kall (24000x1024, A f16).
// ---------------------------------------------------------------------------
__global__ __launch_bounds__(256)
void qk_fused(const float* __restrict__ query, const half_t* __restrict__ keyh,
              const half_t* __restrict__ wt_q, const half_t* __restrict__ wt_k,
              half_t* __restrict__ qbuf, half_t* __restrict__ kbuf2,
              const float* __restrict__ cb_q, const float* __restrict__ cb_k)
{
  __shared__ GemmLds L;
  int blk = blockIdx.x;
  if (blk < 128) {
    mgemm_body<0,false,false,float,half_t>(L, threadIdx.x, blk & 7, blk >> 3, 0,
        query, wt_q, qbuf, 2048, 1024, 512, 512, 512, 1024, 1, 1, 512,
        0, 0, 0, 0, 0, 0, cb_q, nullptr);
  } else {
    int vb = blk - 128;
    mgemm_body<0,false,false,half_t,half_t>(L, threadIdx.x, vb % 8, vb / 8, 0,
        keyh, wt_k, kbuf2, 24000, 1024, 512, 512, 512, 1024, 1, 1, 512,
        0, 0, 0, 0, 0, 0, cb_k, nullptr);
  }
}

// ---------------------------------------------------------------------------
// FUSED (256 threads, launch_bounds(256,1)) — identical to round 18:
//  blocks 0-31   : cp+alpha scan — 8-deep software-pipelined p prefetch
//  blocks 32-415 : u GEMM (384 virtual blocks), A = q_ca f16
//  blocks 416+   : vT projection (752 blocks), A = keyh f16
// ---------------------------------------------------------------------------
union MidLds { GemmLds g; ScanLds s; };

__global__ __launch_bounds__(256, 1)
void fused_mid(const half_t* __restrict__ p16, float* __restrict__ alpha_slot,
               const half_t* __restrict__ qa, const half_t* __restrict__ kb,
               int lda_u, int ldb_u, long long sAb_u, long long sBb_u,
               float* __restrict__ u_buf,
               const half_t* __restrict__ keyh, const half_t* __restrict__ wt_v,
               half_t* __restrict__ vtbuf, const float* __restrict__ b_value)
{
  __shared__ MidLds lds;
  int blk = blockIdx.x;
  int tid = threadIdx.x;

  if (blk >= 32) {
    if (blk < 416) {                     // ---- u GEMM: vb in [0,384) ----
      int vb = blk - 32;
      int bx = vb % 24; int t = vb / 24;
      int by = t & 1;   int bz = t >> 1;
      mgemm_body<2,false,false,half_t,float>(lds.g, tid, bx, by, bz, qa, kb, u_buf,
          256, 3000, 512, lda_u, ldb_u, 3000, 1, 1, 512,
          sAb_u, 0, sBb_u, 0, 768000, 0, nullptr, nullptr);
    } else {                             // ---- vT proj: vb in [0,752) ----
      int vb = blk - 416;
      int bx = vb & 3; int by = vb >> 2;
      mgemm_body<0,true,false,half_t,half_t>(lds.g, tid, bx, by, 0, keyh, wt_v, vtbuf,
          24000, 512, 512, 512, 512, 24000, 1, 1, 512,
          0, 0, 0, 0, 0, 0, b_value, nullptr);
    }
    return;
  }

  // ---- scan for chain blk: 256 thr x 12 elems (3000 = 250x12) ----
  __builtin_amdgcn_s_setprio(1);
  float (&wsA)[2][4] = lds.s.wsA;
  float (&wsB)[2][4] = lds.s.wsB;
  int lane = tid & 63, wid = tid >> 6;
  int k0 = tid * 12;
  size_t zbase = (size_t)blk * 768000;   // 256*3000
  const half_t* prow = p16 + zbase;

  half4v ph0[3], pb0[3], pb1[3], pb2[3], pb3[3], pb4[3], pb5[3], pb6[3], pb7[3];
  #pragma unroll
  for (int j = 0; j < 3; j++) {
    int k = k0 + j * 4;
    half4v z = {(_Float16)0,(_Float16)0,(_Float16)0,(_Float16)0};
    bool ok = (k + 4 <= 3000);
    ph0[j] = ok ? *(const half4v*)&prow[k]         : z;
    pb0[j] = ok ? *(const half4v*)&prow[3000 + k]  : z;
    pb1[j] = ok ? *(const half4v*)&prow[6000 + k]  : z;
    pb2[j] = ok ? *(const half4v*)&prow[9000 + k]  : z;
    pb3[j] = ok ? *(const half4v*)&prow[12000 + k] : z;
    pb4[j] = ok ? *(const half4v*)&prow[15000 + k] : z;
    pb5[j] = ok ? *(const half4v*)&prow[18000 + k] : z;
    pb6[j] = ok ? *(const half4v*)&prow[21000 + k] : z;
    pb7[j] = ok ? *(const half4v*)&prow[24000 + k] : z;
  }

  float a_prev[12];
  #pragma unroll
  for (int c = 0; c < 12; c++) a_prev[c] = 0.f;
  if (tid == 0) a_prev[0] = 1.f;

  float cpv[12], w[12];
  { // prologue: cp row 0 (multiplicative DPP scan), w = p0*cp0
    float l[12], m = 1.f;
    float p0f[12];
    #pragma unroll
    for (int c = 0; c < 12; c++) {
      p0f[c] = (float)ph0[c >> 2][c & 3];
      l[c] = m;
      m *= fmaxf(1.f - p0f[c], EPSV);
    }
    float incl = wave_iscan_mul(m);
    if (lane == 63) wsA[1][wid] = incl;
    float exclw = incl * frcp(fmaxf(m, 1e-30f));
    block_sync_lds();
    float base = exclw * cross_prod4(&wsA[1][0], wid);
    #pragma unroll
    for (int c = 0; c < 12; c++) { cpv[c] = base * l[c]; w[c] = p0f[c] * cpv[c]; }
  }

#define SCAN_STEP(I, BUF)                                                     \
  {                                                                           \
    int par = (I) & 1;                                                        \
    float t_[12], s2 = 0.f;                                                   \
    _Pragma("unroll")                                                         \
    for (int c = 0; c < 12; c++) {                                            \
      s2 = fmaf(a_prev[c], frcp(fmaxf(cpv[c], EPSV)), s2);                    \
      t_[c] = s2;                                                             \
    }                                                                         \
    float incl2 = wave_iscan_add(s2);                                         \
    if (lane == 63) wsB[par][wid] = incl2;                                    \
    float excl2 = incl2 - s2;                                                 \
    float pnf[12], l_[12], m_ = 1.f;                                          \
    _Pragma("unroll")                                                         \
    for (int c = 0; c < 12; c++) {                                            \
      pnf[c] = (float)BUF[c >> 2][c & 3];                                     \
      l_[c] = m_;                                                             \
      m_ *= fmaxf(1.f - pnf[c], EPSV);                                        \
    }                                                                         \
    float incl1 = wave_iscan_mul(m_);                                         \
    if (lane == 63) wsA[par][wid] = incl1;                                    \
    float excl1 = incl1 * frcp(fmaxf(m_, 1e-30f));                            \
    block_sync_lds();                                                         \
    if ((I) + 9 <= 255) {                                                     \
      const half_t* nrow = prow + (size_t)((I) + 9) * 3000;                   \
      _Pragma("unroll")                                                       \
      for (int j = 0; j < 3; j++) {                                           \
        int k = k0 + j * 4;                                                   \
        if (k + 4 <= 3000) BUF[j] = *(const half4v*)&nrow[k];                 \
      }                                                                       \
    }                                                                         \
    __builtin_amdgcn_sched_barrier(0);                                        \
    float off = excl2 + cross_sum4(&wsB[par][0], wid);                        \
    size_t rbase = zbase + (size_t)(I) * 3000;                                \
    _Pragma("unroll")                                                         \
    for (int q4 = 0; q4 < 3; q4++) {                                          \
      f32x4 o;                                                                \
      _Pragma("unroll")                                                       \
      for (int j = 0; j < 4; j++) {                                           \
        int c = q4 * 4 + j;                                                   \
        float an = w[c] * (off + t_[c]);                                      \
        a_prev[c] = an;                                                       \
        o[j] = an;                                                            \
      }                                                                       \
      int k = k0 + q4 * 4;                                                    \
      if (k + 4 <= 3000) *(f32x4*)&alpha_slot[rbase + k] = o;                 \
    }                                                                         \
    float base1 = excl1 * cross_prod4(&wsA[par][0], wid);                     \
    _Pragma("unroll")                                                         \
    for (int c = 0; c < 12; c++) { cpv[c] = base1 * l_[c]; w[c] = pnf[c] * cpv[c]; } \
  }

  for (int i = 0; i < 256; i += 8) {
    SCAN_STEP(i,     pb0);
    SCAN_STEP(i + 1, pb1);
    SCAN_STEP(i + 2, pb2);
    SCAN_STEP(i + 3, pb3);
    SCAN_STEP(i + 4, pb4);
    SCAN_STEP(i + 5, pb5);
    SCAN_STEP(i + 6, pb6);
    SCAN_STEP(i + 7, pb7);
  }
#undef SCAN_STEP
}

// ---------------------------------------------------------------------------
// Chunkwise beta — sliding-window form. Each thread owns 12 consecutive k:
// dn (16-back) and the beta window (16-forward) use register-resident
// contiguous LDS slices + running sums (2 adds/elem after the first window)
// instead of 16 LDS-reads per element.
// ---------------------------------------------------------------------------
__global__ __launch_bounds__(256)
void beta_kernel(const float* __restrict__ ubuf, const float* __restrict__ alpha_slot,
                 float* __restrict__ beta_slot)
{
  __shared__ __align__(16) float se[3008];
  __shared__ __align__(16) float dn[3008];
  __shared__ __align__(16) float tt[3040];
  __shared__ float red[4];
  int bq = blockIdx.x;
  int b = bq >> 8, q = bq & 255;
  int tid = threadIdx.x;
  int lane = tid & 63, wid = tid >> 6;
  int k0 = tid * 12;
  bool act = (k0 < 3000);
  const float* urow = ubuf + (size_t)bq * 3000;
  float lmax = -3.0e38f;
  for (int c = tid; c < 750; c += 256) {
    f32x4 v = *(const f32x4*)&urow[c * 4];
    *(f32x4*)&se[c * 4] = v;
    lmax = fmaxf(lmax, fmaxf(fmaxf(v[0], v[1]), fmaxf(v[2], v[3])));
  }
  #pragma unroll
  for (int d = 32; d > 0; d >>= 1) lmax = fmaxf(lmax, __shfl_xor(lmax, d));
  if (lane == 0) red[wid] = lmax;
  __syncthreads();
  float umax = fmaxf(fmaxf(red[0], red[1]), fmaxf(red[2], red[3]));
  for (int c = tid; c < 750; c += 256) {
    f32x4 v = *(const f32x4*)&se[c * 4];
    #pragma unroll
    for (int j = 0; j < 4; j++) v[j] = fmaxf(expf(v[j] - umax), 1e-5f);
    *(f32x4*)&se[c * 4] = v;
  }
  if (tid < 40) tt[3000 + tid] = 0.f;              // forward-window zero pad
  __syncthreads();
  // dn[k] = sum_{j=max(0,k-15)}^{k} se[j] via sliding window
  if (act) {
    float sb[27];
    #pragma unroll
    for (int j = 0; j < 27; j++) {
      int idx = k0 - 15 + j;
      sb[j] = (idx >= 0) ? se[idx] : 0.f;
    }
    float wsum = 0.f;
    #pragma unroll
    for (int j = 0; j < 16; j++) wsum += sb[j];
    dn[k0] = wsum;
    #pragma unroll
    for (int j = 1; j < 12; j++) {
      wsum += sb[15 + j] - sb[j - 1];
      dn[k0 + j] = wsum;
    }
  }
  __syncthreads();
  for (int h = 0; h < 4; h++) {
    const float* arow = alpha_slot + ((size_t)((b * 4 + h) * 256 + q)) * 3000;
    for (int c = tid; c < 750; c += 256) {
      f32x4 a = *(const f32x4*)&arow[c * 4];
      f32x4 d = *(const f32x4*)&dn[c * 4];
      f32x4 o;
      #pragma unroll
      for (int j = 0; j < 4; j++) o[j] = a[j] * frcp(d[j]);
      *(f32x4*)&tt[c * 4] = o;
    }
    __syncthreads();
    float* brow = beta_slot + ((size_t)((b * 4 + h) * 256 + q)) * 3000;
    if (act) {
      float tb[28];
      #pragma unroll
      for (int j = 0; j < 28; j++) tb[j] = tt[k0 + j];
      float wv = 0.f;
      #pragma unroll
      for (int j = 0; j < 16; j++) wv += tb[j];
      float outv[12];
      outv[0] = se[k0] * wv;
      #pragma unroll
      for (int j = 1; j < 12; j++) {
        wv += tb[15 + j] - tb[j - 1];
        outv[j] = se[k0 + j] * wv;
      }
      #pragma unroll
      for (int q4 = 0; q4 < 3; q4++) {
        f32x4 o;
        #pragma unroll
        for (int j = 0; j < 4; j++) o[j] = outv[q4 * 4 + j];
        *(f32x4*)&brow[k0 + q4 * 4] = o;
      }
    }
    __syncthreads();
  }
}

// ---------------------------------------------------------------------------
extern "C" void kernel_launch(void* const* d_in, const int* in_sizes, int n_in,
                              void* d_out, int out_size, void* d_ws, size_t ws_size,
                              hipStream_t stream)
{
  const float* key        = (const float*)d_in[0];
  const float* query      = (const float*)d_in[1];
  const float* w_key_ma   = (const float*)d_in[2];
  const float* b_key_ma   = (const float*)d_in[3];
  const float* w_query_ma = (const float*)d_in[4];
  const float* b_query_ma = (const float*)d_in[5];
  const float* rvec       = (const float*)d_in[6];
  const float* w_key_ca   = (const float*)d_in[7];
  const float* b_key_ca   = (const float*)d_in[8];
  const float* w_query_ca = (const float*)d_in[9];
  const float* b_query_ca = (const float*)d_in[10];
  const float* w_value    = (const float*)d_in[11];
  const float* b_value    = (const float*)d_in[12];

  // Outputs FP32: cv | alpha | beta, flat.
  float* out       = (float*)d_out;
  float* cv_out    = out;                                  // (8,256,512)
  float* alpha_out = out + (size_t)1048576;                // (8,4,256,3000)
  float* beta_out  = alpha_out + (size_t)24576000;         // (8,4,256,3000)
  half_t* p16      = (half_t*)beta_out;                    // p_choose fp16 (first half)
  half_t* keyh     = (half_t*)(beta_out + 12288000);       // key f16 (second half; dead before beta)

  dim3 blk(256);
  bool v3 = ws_size >= (size_t)109322240;

  hipMemsetAsync(cv_out, 0, (size_t)1048576 * sizeof(float), stream);  // cv K-split atomics

  if (v3) {
    // v3 layout: kbuf2[24000][1024] f16 | qbuf[2048][1024] f16 | u f32 | vtbuf | wts | catbias
    half_t* kbuf2 = (half_t*)d_ws;
    half_t* qbuf  = (half_t*)((char*)d_ws + 49152000);
    float*  u_buf = (float*)((char*)d_ws + 57540608);
    half_t* vtbuf = (half_t*)((char*)d_ws + 82116608);
    half_t* wt_q  = (half_t*)((char*)d_ws + 106692608);   // [1024][512]
    half_t* wt_k  = (half_t*)((char*)d_ws + 107741184);   // [1024][512]
    half_t* wt_v  = (half_t*)((char*)d_ws + 108789760);
    float*  cb_q  = (float*)((char*)d_ws + 109314048);
    float*  cb_k  = (float*)((char*)d_ws + 109318144);

    prep<<<dim3(13281), blk, 0, stream>>>(
        w_query_ma, wt_q, w_query_ca, wt_q + 262144,
        w_key_ma,   wt_k, w_key_ca,   wt_k + 262144,
        w_value,    wt_v, key, keyh,
        b_query_ma, b_query_ca, b_key_ma, b_key_ca, cb_q, cb_k);

    qk_fused<<<dim3(1632), blk, 0, stream>>>(query, keyh, wt_q, wt_k, qbuf, kbuf2, cb_q, cb_k);

    // e_ma -> p16 (A = q_ma cols of qbuf f16)
    mgemm<1,false,false,half_t,half_t><<<dim3(24,2,32), blk, 0, stream>>>(qbuf, kbuf2, p16, 256,3000, 128, 1024,1024,3000, 4,1,128,
        262144,128, 3072000,128, 3072000,768000, nullptr, rvec);

    // FUSED: scan (0-31) + u GEMM (32-415) + vT shells (416-1167)
    fused_mid<<<dim3(1168), blk, 0, stream>>>(p16, alpha_out,
        qbuf + 512, kbuf2 + 512, 1024, 1024, 262144, 3072000,
        u_buf, keyh, wt_v, vtbuf, b_value);

    beta_kernel<<<dim3(2048), blk, 0, stream>>>(u_buf, alpha_out, beta_out);

    mgemm<3,false,true,float,float><<<dim3(1,2,256), blk, 0, stream>>>(beta_out, vtbuf, cv_out, 256,128,3000, 3000,24000,512, 4,8,384,
        3072000,768000, 3000,3072000, 131072,128, nullptr, nullptr);
  } else {
    // v1 fallback: kbuf | qbuf | u | 5x wt. 55.97MB.
    if (ws_size < (size_t)55967744) return;
    half_t* kbuf   = (half_t*)d_ws;
    half_t* qbuf   = (half_t*)((char*)d_ws + 24576000);
    float*  u_buf  = (float*)((char*)d_ws + 28770304);
    half_t* wt_qma = (half_t*)((char*)d_ws + 53346304);
    half_t* wt_kma = (half_t*)((char*)d_ws + 53870592);
    half_t* wt_qca = (half_t*)((char*)d_ws + 54394880);
    half_t* wt_kca = (half_t*)((char*)d_ws + 54919168);
    half_t* wt_v   = (half_t*)((char*)d_ws + 55443456);

    prep<<<dim3(13281), blk, 0, stream>>>(
        w_query_ma, wt_qma, w_query_ca, wt_qca,
        w_key_ma,   wt_kma, w_key_ca,   wt_kca,
        w_value,    wt_v, key, keyh,
        nullptr, nullptr, nullptr, nullptr, nullptr, nullptr);

    mgemm<0,false,false,float ,half_t><<<dim3(4,16,1),  blk, 0, stream>>>(query, wt_qma, qbuf, 2048, 512, 512, 512,512,512, 1,1,512, 0,0,0,0,0,0, b_query_ma, nullptr);
    mgemm<0,false,false,half_t,half_t><<<dim3(4,188,1), blk, 0, stream>>>(keyh,  wt_kma, kbuf, 24000,512, 512, 512,512,512, 1,1,512, 0,0,0,0,0,0, b_key_ma,   nullptr);
    mgemm<1,false,false,half_t,half_t><<<dim3(24,2,32), blk, 0, stream>>>(qbuf,  kbuf, p16, 256,3000, 128, 512,512,3000, 4,1,128,
        131072,128, 1536000,128, 3072000,768000, nullptr, rvec);

    mgemm<0,false,false,float ,half_t><<<dim3(4,16,1),  blk, 0, stream>>>(query, wt_qca, qbuf, 2048, 512, 512, 512,512,512, 1,1,512, 0,0,0,0,0,0, b_query_ca, nullptr);
    mgemm<0,false,false,half_t,half_t><<<dim3(4,188,1), blk, 0, stream>>>(keyh,  wt_kca, kbuf, 24000,512, 512, 512,512,512, 1,1,512, 0,0,0,0,0,0, b_key_ca,   nullptr);

    // FUSED: scan (0-31) + u GEMM (32-415); vT serial after (into kbuf)
    fused_mid<<<dim3(416), blk, 0, stream>>>(p16, alpha_out,
        qbuf, kbuf, 512, 512, 131072, 1536000,
        u_buf, keyh, wt_v, kbuf, b_value);

    mgemm<0,true,false,half_t,half_t><<<dim3(4,188,1), blk, 0, stream>>>(keyh, wt_v, kbuf, 24000,512, 512, 512,512,24000, 1,1,512, 0,0,0,0,0,0, b_value, nullptr);

    beta_kernel<<<dim3(2048), blk, 0, stream>>>(u_buf, alpha_out, beta_out);

    mgemm<3,false,true,float,float><<<dim3(1,2,256), blk, 0, stream>>>(beta_out, kbuf, cv_out, 256,128,3000, 3000,24000,512, 4,8,384,
        3072000,768000, 3000,3072000, 131072,128, nullptr, nullptr);
  }
}